// Round 6
// baseline (206.656 us; speedup 1.0000x reference)
//
#include <hip/hip_runtime.h>
#include <math.h>

#define TOTAL_G 17064
#define BATCHN  16
#define ALLF    0xFFFFFFFFFFFFFFFFull
// valid <=> score > 0.01f <=> scorebits > 0x3C23D70A <=> (key>>15) < 0xC3DC28F5
#define INVALID_HI 0xC3DC28F5u

typedef unsigned long long u64;
typedef unsigned int u32;
typedef unsigned short u16;

// ---- ws layout (bytes), total 4,470,400 ----
#define KEYS0_OFF   0          // u64[16][12800]  1,638,400
#define KEYS1_OFF   1638400    // u64[16][3200]     409,600
#define KEYS234_OFF 2048000    // u64[16][1088]     139,264
#define CLSI_OFF    2187264    // u16[16][17064]    546,048
#define NC_OFF      2733312    // int[16] (+pad)        256
#define T512_OFF    2733568    // u64[16]               128
#define CK_OFF      2733696    // u64[16][3072]     393,216
#define IDX_OFF     3126912    // u16[16][512]       16,384
#define BR_OFF      3143296    // u16[16][512]       16,384
#define MSK_OFF     3159680    // u64[16][512*8]    524,288
#define FB_OFF      3683968    // f4 [16][3072]     786,432  (fallback only)

struct Ptrs {
  const float *cls0,*cls1,*cls2,*cls3,*cls4;
  const float *reg0,*reg1,*reg2,*reg3,*reg4;
  const float *ctr0,*ctr1,*ctr2,*ctr3,*ctr4;
  const float *pos0,*pos1,*pos2,*pos3,*pos4;
  char *ws;
};

__device__ __forceinline__ float sigd(float x) {
  return (float)(1.0 / (1.0 + exp(-(double)x)));
}
__device__ __forceinline__ float dexp(float x) {
  return (float)exp((double)x);
}
__device__ __forceinline__ void levinfo(int gid, int& lev, int& idx, int& nl) {
  if      (gid < 12800) { lev=0; idx=gid;        nl=12800; }
  else if (gid < 16000) { lev=1; idx=gid-12800;  nl=3200;  }
  else if (gid < 16800) { lev=2; idx=gid-16000;  nl=800;   }
  else if (gid < 17008) { lev=3; idx=gid-16800;  nl=208;   }
  else                  { lev=4; idx=gid-17008;  nl=56;    }
}

__device__ __forceinline__ u64* ckeys_of(char* ws, int b) {
  return (u64*)(ws + CK_OFF + (size_t)b * 24576);
}
__device__ __forceinline__ u16* idx512_of(char* ws, int b) {
  return (u16*)(ws + IDX_OFF + (size_t)b * 1024);
}
__device__ __forceinline__ u16* byrank_of(char* ws, int b) {
  return (u16*)(ws + BR_OFF + (size_t)b * 1024);
}
__device__ __forceinline__ u64* msk_of(char* ws, int b) {
  return (u64*)(ws + MSK_OFF + (size_t)b * 32768);
}
__device__ __forceinline__ float4* fb_of(char* ws, int b) {
  return (float4*)(ws + FB_OFF + (size_t)b * 49152);
}

// exact box decode (identical everywhere -> deterministic)
__device__ __forceinline__ float4 decode_box(const Ptrs& P, int b, int gid) {
  int lev, idx, nl; levinfo(gid, lev, idx, nl);
  const float *rp, *pp;
  if      (lev == 0) { rp = P.reg0; pp = P.pos0; }
  else if (lev == 1) { rp = P.reg1; pp = P.pos1; }
  else if (lev == 2) { rp = P.reg2; pp = P.pos2; }
  else if (lev == 3) { rp = P.reg3; pp = P.pos3; }
  else               { rp = P.reg4; pp = P.pos4; }
  float4 rv = *(const float4*)(rp + (size_t)(b * nl + idx) * 4);
  float2 pv = *(const float2*)(pp + (size_t)(b * nl + idx) * 2);
  float e0 = dexp(rv.x), e1 = dexp(rv.y), e2 = dexp(rv.z), e3 = dexp(rv.w);
  float x1 = truncf(pv.x - e0), y1 = truncf(pv.y - e1);
  float x2 = truncf(pv.x + e2), y2 = truncf(pv.y + e3);
  x1 = fmaxf(x1, 0.0f); y1 = fmaxf(y1, 0.0f);
  x2 = fminf(x2, 1023.0f); y2 = fminf(y2, 799.0f);
  return make_float4(x1, y1, x2, y2);
}

// ---------------- K1: 4-threads-per-position score / argmax / key ----------------
__global__ __launch_bounds__(256) void k_score(Ptrs P) {
  int t = blockIdx.x * 256 + threadIdx.x;
  int g = t >> 2, q = t & 3;
  if (g >= TOTAL_G) return;
  int b = blockIdx.y;

  int lev, idx, nl;
  levinfo(g, lev, idx, nl);
  const float *clsb, *ctrb;
  if      (lev == 0) { clsb = P.cls0; ctrb = P.ctr0; }
  else if (lev == 1) { clsb = P.cls1; ctrb = P.ctr1; }
  else if (lev == 2) { clsb = P.cls2; ctrb = P.ctr2; }
  else if (lev == 3) { clsb = P.cls3; ctrb = P.ctr3; }
  else               { clsb = P.cls4; ctrb = P.ctr4; }

  const float4* cp4 = (const float4*)(clsb + (size_t)(b * nl + idx) * 80) + q * 5;
  float m = -INFINITY, m2 = -INFINITY; int mi = 0;
  #pragma unroll
  for (int k = 0; k < 5; ++k) {
    float4 v = cp4[k];
    int base = q * 20 + 4 * k;
    if (v.x > m) { m2 = m; m = v.x; mi = base+0; } else if (v.x > m2) m2 = v.x;
    if (v.y > m) { m2 = m; m = v.y; mi = base+1; } else if (v.y > m2) m2 = v.y;
    if (v.z > m) { m2 = m; m = v.z; mi = base+2; } else if (v.z > m2) m2 = v.z;
    if (v.w > m) { m2 = m; m = v.w; mi = base+3; } else if (v.w > m2) m2 = v.w;
  }
  #pragma unroll
  for (int xw = 1; xw <= 2; xw <<= 1) {
    float om  = __shfl_xor(m,  xw);
    float om2 = __shfl_xor(m2, xw);
    int   omi = __shfl_xor(mi, xw);
    bool take = (om > m) || (om == m && omi < mi);
    float lm  = take ? m : om;
    float wm2 = take ? om2 : m2;
    if (take) { m = om; mi = omi; }
    m2 = fmaxf(lm, wm2);
  }

  float thr = fminf(m - 1e-3f, 9.0f);
  float pmax; int ci;
  if (m2 >= thr) {
    float pv = -1.0f; int pi = 0x7fffffff;
    #pragma unroll 1
    for (int k = 0; k < 5; ++k) {
      float4 v = cp4[k];
      float xs[4] = {v.x, v.y, v.z, v.w};
      #pragma unroll
      for (int e = 0; e < 4; ++e) {
        if (xs[e] >= thr) {
          float p = sigd(xs[e]);
          if (p > pv) { pv = p; pi = q * 20 + 4 * k + e; }
        }
      }
    }
    #pragma unroll
    for (int xw = 1; xw <= 2; xw <<= 1) {
      float ov = __shfl_xor(pv, xw);
      int   oi = __shfl_xor(pi, xw);
      if (ov > pv || (ov == pv && oi < pi)) { pv = ov; pi = oi; }
    }
    pmax = pv; ci = pi;
  } else {
    pmax = sigd(m); ci = mi;
  }

  if (q == 0) {
    float tc = ctrb[(size_t)b * nl + idx];
    float csig = sigd(tc);
    float prod = pmax * csig;
    float s = (float)sqrt((double)prod);
    ((u16*)(P.ws + CLSI_OFF))[(size_t)b * TOTAL_G + g] = (u16)ci;
    unsigned hi = ~__float_as_uint(s);
    u64 key = ((u64)hi << 15) | (unsigned)g;
    if      (lev == 0) ((u64*)(P.ws + KEYS0_OFF))  [(size_t)b * 12800 + idx] = key;
    else if (lev == 1) ((u64*)(P.ws + KEYS1_OFF))  [(size_t)b * 3200  + idx] = key;
    else               ((u64*)(P.ws + KEYS234_OFF))[(size_t)b * 1088  + (g - 16000)] = key;
  }
}

// ---------------- radix-select: exact t0-th smallest 47-bit key ----------------
__device__ u64 radix_select(const u64* keys, int n, int t0,
                            u32 (*hist)[4096], u64* bcastP, int* bcastT) {
  int tid = threadIdx.x, wid = tid >> 6, lane = tid & 63;
  int rep = wid & 7;
  u64 Pfx = 0; int t = t0;
  const int S[4] = {35, 23, 11, 0};
  const int W[4] = {12, 12, 12, 11};
  #pragma unroll 1
  for (int p = 0; p < 4; ++p) {
    int s = S[p], wb = W[p];
    u32 dmask = (1u << wb) - 1u;
    for (int i = tid; i < 8 * 4096; i += 1024) (&hist[0][0])[i] = 0;
    __syncthreads();
    for (int i = tid; i < n; i += 1024) {
      u64 k = keys[i];
      if ((k >> (s + wb)) == Pfx) {
        u32 d = (u32)(k >> s) & dmask;
        atomicAdd(&hist[rep][d], 1u);
      }
    }
    __syncthreads();
    for (int i = tid; i < 4096; i += 1024) {
      u32 v = hist[0][i];
      #pragma unroll
      for (int r = 1; r < 8; ++r) v += hist[r][i];
      hist[0][i] = v;
    }
    __syncthreads();
    if (wid == 0) {
      u32 ssum = 0;
      #pragma unroll 8
      for (int i = 0; i < 64; ++i) {
        int ii = (i + lane) & 63;
        ssum += hist[0][(lane << 6) + ii];
      }
      u32 inc = ssum;
      for (int o = 1; o < 64; o <<= 1) {
        u32 v = __shfl_up(inc, o);
        if (lane >= o) inc += v;
      }
      u64 ball = __ballot(inc >= (u32)t);
      int Ws = __ffsll(ball) - 1;
      u32 cumBefore = __shfl(inc - ssum, Ws);
      u32 v2 = hist[0][(Ws << 6) + lane];
      u32 inc2 = v2;
      for (int o = 1; o < 64; o <<= 1) {
        u32 x = __shfl_up(inc2, o);
        if (lane >= o) inc2 += x;
      }
      u64 ball2 = __ballot(cumBefore + inc2 >= (u32)t);
      int l2 = __ffsll(ball2) - 1;
      u32 cumB2 = __shfl(cumBefore + inc2 - v2, l2);
      if (lane == 0) {
        int d = (Ws << 6) + l2;
        *bcastP = (Pfx << wb) | (u32)d;
        *bcastT = t - (int)cumB2;
      }
    }
    __syncthreads();
    Pfx = *bcastP; t = *bcastT;
    __syncthreads();
  }
  return Pfx;
}

__device__ __forceinline__ u64 loadkey(const Ptrs& P, int b, int u) {
  if (u < 12800) return ((const u64*)(P.ws + KEYS0_OFF))  [(size_t)b * 12800 + u];
  if (u < 16000) return ((const u64*)(P.ws + KEYS1_OFF))  [(size_t)b * 3200  + (u - 12800)];
  return               ((const u64*)(P.ws + KEYS234_OFF))[(size_t)b * 1088  + (u - 16000)];
}

__device__ __forceinline__ bool keep_pred(u64 k, int u, u64 T0, u64 T1) {
  bool valid = (u32)(k >> 15) < INVALID_HI;
  bool sel = (u < 12800) ? (k <= T0) : ((u < 16000) ? (k <= T1) : true);
  return valid && sel;
}

// filtered radix-select over the union candidate set
__device__ u64 radix_select_pred(const Ptrs& P, int b, u64 T0, u64 T1, int t0,
                                 u32 (*hist)[4096], u64* bcastP, int* bcastT) {
  int tid = threadIdx.x, wid = tid >> 6, lane = tid & 63;
  int rep = wid & 7;
  u64 Pfx = 0; int t = t0;
  const int S[4] = {35, 23, 11, 0};
  const int W[4] = {12, 12, 12, 11};
  #pragma unroll 1
  for (int p = 0; p < 4; ++p) {
    int s = S[p], wb = W[p];
    u32 dmask = (1u << wb) - 1u;
    for (int i = tid; i < 8 * 4096; i += 1024) (&hist[0][0])[i] = 0;
    __syncthreads();
    for (int u = tid; u < TOTAL_G; u += 1024) {
      u64 k = loadkey(P, b, u);
      if (keep_pred(k, u, T0, T1) && (k >> (s + wb)) == Pfx) {
        u32 d = (u32)(k >> s) & dmask;
        atomicAdd(&hist[rep][d], 1u);
      }
    }
    __syncthreads();
    for (int i = tid; i < 4096; i += 1024) {
      u32 v = hist[0][i];
      #pragma unroll
      for (int r = 1; r < 8; ++r) v += hist[r][i];
      hist[0][i] = v;
    }
    __syncthreads();
    if (wid == 0) {
      u32 ssum = 0;
      #pragma unroll 8
      for (int i = 0; i < 64; ++i) {
        int ii = (i + lane) & 63;
        ssum += hist[0][(lane << 6) + ii];
      }
      u32 inc = ssum;
      for (int o = 1; o < 64; o <<= 1) {
        u32 v = __shfl_up(inc, o);
        if (lane >= o) inc += v;
      }
      u64 ball = __ballot(inc >= (u32)t);
      int Ws = __ffsll(ball) - 1;
      u32 cumBefore = __shfl(inc - ssum, Ws);
      u32 v2 = hist[0][(Ws << 6) + lane];
      u32 inc2 = v2;
      for (int o = 1; o < 64; o <<= 1) {
        u32 x = __shfl_up(inc2, o);
        if (lane >= o) inc2 += x;
      }
      u64 ball2 = __ballot(cumBefore + inc2 >= (u32)t);
      int l2 = __ffsll(ball2) - 1;
      u32 cumB2 = __shfl(cumBefore + inc2 - v2, l2);
      if (lane == 0) {
        int d = (Ws << 6) + l2;
        *bcastP = (Pfx << wb) | (u32)d;
        *bcastT = t - (int)cumB2;
      }
    }
    __syncthreads();
    Pfx = *bcastP; t = *bcastT;
    __syncthreads();
  }
  return Pfx;
}

// ---------------- K2: thresholds + T512 + compaction + idx512 (16 blocks) ----------------
__global__ __launch_bounds__(1024) void k_selcomp(Ptrs P) {
  __shared__ u32 hist[8][4096];       // 128 KB
  __shared__ u64 bcastP;
  __shared__ int bcastT;
  __shared__ int wbase[272], wbase2[272];
  __shared__ int sNc;
  int b = blockIdx.x;
  int tid = threadIdx.x, wid = tid >> 6, lane = tid & 63;

  u64 T0 = radix_select((const u64*)(P.ws + KEYS0_OFF) + (size_t)b * 12800, 12800, 1000,
                        hist, &bcastP, &bcastT);
  u64 T1 = radix_select((const u64*)(P.ws + KEYS1_OFF) + (size_t)b * 3200, 3200, 1000,
                        hist, &bcastP, &bcastT);

  // count survivors
  for (int it = 0; it < 17; ++it) {
    int u = it * 1024 + tid;
    bool keep = false;
    if (u < TOTAL_G) keep = keep_pred(loadkey(P, b, u), u, T0, T1);
    u64 bal = __ballot(keep);
    if (lane == 0) wbase[it * 16 + wid] = __popcll(bal);
  }
  __syncthreads();
  if (tid == 0) {
    int run = 0;
    for (int i = 0; i < 272; ++i) { int c = wbase[i]; wbase[i] = run; run += c; }
    sNc = run;
    ((int*)(P.ws + NC_OFF))[b] = run;
  }
  __syncthreads();
  int Nc = sNc;

  // exact global 512th key (over the filtered union)
  u64 T512;
  if (Nc > 512) T512 = radix_select_pred(P, b, T0, T1, 512, hist, &bcastP, &bcastT);
  else          T512 = ALLF;
  if (tid == 0) ((u64*)(P.ws + T512_OFF))[b] = T512;

  // count top-512 members (for idx512 scatter bases)
  for (int it = 0; it < 17; ++it) {
    int u = it * 1024 + tid;
    bool keep5 = false;
    if (u < TOTAL_G) {
      u64 k = loadkey(P, b, u);
      keep5 = keep_pred(k, u, T0, T1) && (k <= T512);
    }
    u64 bal = __ballot(keep5);
    if (lane == 0) wbase2[it * 16 + wid] = __popcll(bal);
  }
  __syncthreads();
  if (tid == 0) {
    int run = 0;
    for (int i = 0; i < 272; ++i) { int c = wbase2[i]; wbase2[i] = run; run += c; }
  }
  __syncthreads();

  // write ck (compact order) + idx512 (compact indices of top-512 set)
  u64* ck = ckeys_of(P.ws, b);
  u16* ix = idx512_of(P.ws, b);
  for (int it = 0; it < 17; ++it) {
    int u = it * 1024 + tid;
    bool keep = false; u64 k = 0;
    if (u < TOTAL_G) {
      k = loadkey(P, b, u);
      keep = keep_pred(k, u, T0, T1);
    }
    bool keep5 = keep && (k <= T512);
    u64 bal  = __ballot(keep);
    u64 bal5 = __ballot(keep5);
    u64 lm = (1ull << lane) - 1ull;
    int pos  = wbase [it * 16 + wid] + __popcll(bal  & lm);
    int pos5 = wbase2[it * 16 + wid] + __popcll(bal5 & lm);
    if (keep)  ck[pos] = k;
    if (keep5) ix[pos5] = (u16)pos;
  }
}

// ---------------- K3: decode512 + key-directed mask + free rank (4 x 16 blocks) ----------------
__global__ __launch_bounds__(1024) void k_mask(Ptrs P) {
  __shared__ float4 sbox[512];
  __shared__ u64 skey[512];
  __shared__ u32 srank[512];
  int qi = blockIdx.x, b = blockIdx.y;
  int tid = threadIdx.x;
  char* ws = P.ws;
  int Nc = ((int*)(ws + NC_OFF))[b];
  int n512 = Nc < 512 ? Nc : 512;
  const u64* ck = ckeys_of(ws, b);
  const u16* ix = idx512_of(ws, b);

  if (tid < 512) {
    srank[tid] = 0;
    if (tid < n512) {
      u64 k = ck[ix[tid]];
      skey[tid] = k;
      sbox[tid] = decode_box(P, b, (int)(k & 0x7FFF));
    } else {
      skey[tid] = (ALLF - 511) + (u64)tid;       // distinct, > any real key
      sbox[tid] = make_float4(-1e30f, -1e30f, -1e30f, -1e30f);
    }
  }
  __syncthreads();

  int i = qi * 128 + (tid >> 3);
  int w = tid & 7;
  float4 bi = sbox[i];
  u64 ki = skey[i];
  float ia = (bi.z - bi.x) * (bi.w - bi.y);
  u64 mword = 0; u32 cnt = 0;
  #pragma unroll 8
  for (int bj = 0; bj < 64; ++bj) {
    int jj = (bj + w) & 63;
    int j = (w << 6) | jj;
    u64 kj = skey[j];
    cnt += (kj < ki) ? 1u : 0u;
    if (ki < kj) {
      float4 bj4 = sbox[j];
      float ja  = (bj4.z - bj4.x) * (bj4.w - bj4.y);
      float ltx = fmaxf(bi.x, bj4.x), lty = fmaxf(bi.y, bj4.y);
      float rbx = fminf(bi.z, bj4.z), rby = fminf(bi.w, bj4.w);
      float wv = fmaxf(rbx - ltx, 0.0f), hv = fmaxf(rby - lty, 0.0f);
      float inter = wv * hv;
      float iou = inter / (ia + ja - inter);     // exact: integer-valued fp32
      if (iou > 0.6f) mword |= (1ull << jj);
    }
  }
  msk_of(ws, b)[i * 8 + w] = mword;
  atomicAdd(&srank[i], cnt);
  __syncthreads();
  if (tid < 128) {
    int ii = qi * 128 + tid;
    if (ii < n512) byrank_of(ws, b)[srank[ii]] = (u16)ii;
  }
}

// ---------------- K4: greedy reduce + fallback + outputs (16 blocks, 256 thr) ----------------
__global__ __launch_bounds__(256) void k_reduce(Ptrs P, float* out) {
  __shared__ u64 smask[4096];       // 32 KB
  __shared__ u16 sbr[512];
  __shared__ u32 keeplist[100];     // <512: top-512 index; 0x8000|c: compact index
  __shared__ int slotgid[100];
  __shared__ int keptS;
  // fallback scratch
  __shared__ u64 liveC[48];
  __shared__ u64 pk[256];
  __shared__ int pc[256];
  __shared__ float4 fkb[100];
  __shared__ u64 bk; __shared__ int bc2;

  int b = blockIdx.x;
  int tid = threadIdx.x;
  char* ws = P.ws;
  int Nc = ((int*)(ws + NC_OFF))[b];
  int n512 = Nc < 512 ? Nc : 512;
  const u64* ck = ckeys_of(ws, b);
  const u16* ix = idx512_of(ws, b);

  const u64* gmask = msk_of(ws, b);
  for (int t = tid; t < 4096; t += 256) smask[t] = gmask[t];
  { const u16* gbr = byrank_of(ws, b);
    for (int t = tid; t < 512; t += 256) sbr[t] = (t < n512) ? gbr[t] : (u16)0xFFFF; }
  __syncthreads();

  // single-wave greedy: walk byrank with 64-wide probes; live bits replicated in regs
  if (tid < 64) {
    int lane = tid;
    u64 lw[8];
    #pragma unroll
    for (int r = 0; r < 8; ++r) {
      int lo = r << 6;
      int c = n512 - lo; if (c < 0) c = 0; if (c > 64) c = 64;
      lw[r] = (c >= 64) ? ALLF : ((c > 0) ? ((1ull << c) - 1ull) : 0ull);
    }
    int cursor = 0, kept = 0;
    while (cursor < n512 && kept < 100) {
      int idxp = cursor + lane;
      int t = (idxp < n512) ? (int)sbr[idxp] : 0;
      int wsel = t >> 6;
      u64 lv = lw[0];
      #pragma unroll
      for (int r = 1; r < 8; ++r) lv = (wsel == r) ? lw[r] : lv;
      bool alive = (idxp < n512) && ((lv >> (t & 63)) & 1ull);
      u64 bal = __ballot(alive);
      if (!bal) { cursor += 64; continue; }
      int l = __ffsll(bal) - 1;
      int tk = __shfl(t, l);
      cursor += l + 1;
      if (lane == 0) keeplist[kept] = (u32)tk;
      kept++;
      if (kept == 100) break;
      #pragma unroll
      for (int r = 0; r < 8; ++r) {
        u64 rw = smask[tk * 8 + r];
        u64 self = ((tk >> 6) == r) ? (1ull << (tk & 63)) : 0ull;
        lw[r] &= ~(rw | self);
      }
    }
    if (lane == 0) keptS = kept;
  }
  __syncthreads();
  int kept = keptS;

  // fallback: keeps beyond the global top-512 (rare; exact)
  if (kept < 100 && Nc > 512) {
    u64 T512 = ((u64*)(ws + T512_OFF))[b];
    float4* fb = fb_of(ws, b);
    if (tid < 48) {
      int lo = tid << 6;
      u64 m = 0;
      for (int e = 0; e < 64; ++e) {
        int c = lo + e;
        if (c < Nc && ck[c] > T512) m |= (1ull << e);
      }
      liveC[tid] = m;
    }
    for (int c = tid; c < Nc; c += 256)
      if (ck[c] > T512) fb[c] = decode_box(P, b, (int)(ck[c] & 0x7FFF));
    if (tid < kept) fkb[tid] = decode_box(P, b, (int)(ck[ix[keeplist[tid]]] & 0x7FFF));
    __syncthreads();

    // seed suppression from already-kept items
    for (int k2 = 0; k2 < kept; ++k2) {
      float4 bi = fkb[k2];
      float ia = (bi.z - bi.x) * (bi.w - bi.y);
      for (int j = tid; j < Nc; j += 256) {
        if (!((liveC[j >> 6] >> (j & 63)) & 1ull)) continue;
        float4 bj4 = fb[j];
        float ja  = (bj4.z - bj4.x) * (bj4.w - bj4.y);
        float ltx = fmaxf(bi.x, bj4.x), lty = fmaxf(bi.y, bj4.y);
        float rbx = fminf(bi.z, bj4.z), rby = fminf(bi.w, bj4.w);
        float wv = fmaxf(rbx - ltx, 0.0f), hv = fmaxf(rby - lty, 0.0f);
        float inter = wv * hv;
        float iou = inter / (ia + ja - inter);
        if (iou > 0.6f) atomicAnd(&liveC[j >> 6], ~(1ull << (j & 63)));
      }
    }
    __syncthreads();

    // selection-by-min-key loop
    while (kept < 100) {
      u64 mymin = ALLF; int myc = -1;
      for (int c = tid; c < Nc; c += 256) {
        if (!((liveC[c >> 6] >> (c & 63)) & 1ull)) continue;
        u64 k = ck[c];
        if (k < mymin) { mymin = k; myc = c; }
      }
      pk[tid] = mymin; pc[tid] = myc;
      __syncthreads();
      if (tid < 64) {
        u64 m = pk[tid]; int c0 = pc[tid];
        #pragma unroll
        for (int o = 64; o < 256; o += 64)
          if (pk[tid + o] < m) { m = pk[tid + o]; c0 = pc[tid + o]; }
        for (int o = 32; o > 0; o >>= 1) {
          u64 om = __shfl_down(m, o); int oc = __shfl_down(c0, o);
          if (om < m) { m = om; c0 = oc; }
        }
        if (tid == 0) { bk = m; bc2 = c0; }
      }
      __syncthreads();
      if (bk == ALLF) break;
      int cs = bc2;
      if (tid == 0) {
        keeplist[kept] = 0x8000u | (u32)cs;
        atomicAnd(&liveC[cs >> 6], ~(1ull << (cs & 63)));
      }
      __syncthreads();
      kept++;
      if (kept == 100) break;
      float4 bi = fb[cs];
      float ia = (bi.z - bi.x) * (bi.w - bi.y);
      for (int j = tid; j < Nc; j += 256) {
        if (!((liveC[j >> 6] >> (j & 63)) & 1ull)) continue;
        float4 bj4 = fb[j];
        float ja  = (bj4.z - bj4.x) * (bj4.w - bj4.y);
        float ltx = fmaxf(bi.x, bj4.x), lty = fmaxf(bi.y, bj4.y);
        float rbx = fminf(bi.z, bj4.z), rby = fminf(bi.w, bj4.w);
        float wv = fmaxf(rbx - ltx, 0.0f), hv = fmaxf(rby - lty, 0.0f);
        float inter = wv * hv;
        float iou = inter / (ia + ja - inter);
        if (iou > 0.6f) atomicAnd(&liveC[j >> 6], ~(1ull << (j & 63)));
      }
      __syncthreads();
    }
  }

  // outputs: out_s @0 [16,100], out_c @1600, out_b @3200 [16,100,4], out_cp @9600
  if (tid < 100) {
    int s = tid;
    float os = -1.0f, oc = -1.0f;
    float4 bx = make_float4(-1.0f, -1.0f, -1.0f, -1.0f);
    int gid = -1;
    if (s < kept) {
      u32 e = keeplist[s];
      u64 key = (e & 0x8000u) ? ck[e & 0xFFFu] : ck[ix[e]];
      gid = (int)(key & 0x7FFF);
      os = __uint_as_float(~(u32)(key >> 15));
      oc = (float)((u16*)(ws + CLSI_OFF))[(size_t)b * TOTAL_G + gid];
      bx = decode_box(P, b, gid);
    }
    slotgid[s] = gid;
    out[b * 100 + s] = os;
    out[1600 + b * 100 + s] = oc;
    *(float4*)(out + 3200 + (size_t)(b * 100 + s) * 4) = bx;
  }
  __syncthreads();
  for (int t = tid; t < 100 * 80; t += 256) {
    int s = t / 80, k = t - s * 80;
    float val = -1.0f;
    int gid = slotgid[s];
    if (gid >= 0) {
      int lev, idx, nl; levinfo(gid, lev, idx, nl);
      const float* cp;
      if      (lev == 0) cp = P.cls0;
      else if (lev == 1) cp = P.cls1;
      else if (lev == 2) cp = P.cls2;
      else if (lev == 3) cp = P.cls3;
      else               cp = P.cls4;
      val = sigd(cp[(size_t)(b * nl + idx) * 80 + k]);
    }
    out[9600 + (size_t)(b * 100 + s) * 80 + k] = val;
  }
}

extern "C" void kernel_launch(void* const* d_in, const int* in_sizes, int n_in,
                              void* d_out, int out_size, void* d_ws, size_t ws_size,
                              hipStream_t stream) {
  (void)in_sizes; (void)n_in; (void)out_size; (void)ws_size;
  Ptrs P;
  P.cls0 = (const float*)d_in[0];  P.reg0 = (const float*)d_in[1];
  P.ctr0 = (const float*)d_in[2];  P.pos0 = (const float*)d_in[3];
  P.cls1 = (const float*)d_in[4];  P.reg1 = (const float*)d_in[5];
  P.ctr1 = (const float*)d_in[6];  P.pos1 = (const float*)d_in[7];
  P.cls2 = (const float*)d_in[8];  P.reg2 = (const float*)d_in[9];
  P.ctr2 = (const float*)d_in[10]; P.pos2 = (const float*)d_in[11];
  P.cls3 = (const float*)d_in[12]; P.reg3 = (const float*)d_in[13];
  P.ctr3 = (const float*)d_in[14]; P.pos3 = (const float*)d_in[15];
  P.cls4 = (const float*)d_in[16]; P.reg4 = (const float*)d_in[17];
  P.ctr4 = (const float*)d_in[18]; P.pos4 = (const float*)d_in[19];
  P.ws = (char*)d_ws;

  k_score<<<dim3(267, 16), 256, 0, stream>>>(P);
  k_selcomp<<<16, 1024, 0, stream>>>(P);
  k_mask<<<dim3(4, 16), 1024, 0, stream>>>(P);
  k_reduce<<<16, 256, 0, stream>>>(P, (float*)d_out);
}

// Round 7
// 158.517 us; speedup vs baseline: 1.3037x; 1.3037x over previous
//
#include <hip/hip_runtime.h>
#include <math.h>

#define TOTAL_G 17064
#define BATCHN  16
#define ALLF    0xFFFFFFFFFFFFFFFFull
// valid <=> score > 0.01f <=> scorebits > 0x3C23D70A <=> (key>>15) < 0xC3DC28F5
#define INVALID_HI 0xC3DC28F5u

typedef unsigned long long u64;
typedef unsigned int u32;
typedef unsigned short u16;

// ---- ws layout (bytes), total 4,519,808 ----
#define KEYS0_OFF   0          // u64[16][12800]  1,638,400
#define KEYS1_OFF   1638400    // u64[16][3200]     409,600
#define KEYS234_OFF 2048000    // u64[16][1088]     139,264
#define CLSI_OFF    2187264    // u16[16][17064]    546,048
#define NC_OFF      2733312    // int[16] (+pad)        256
#define T01_OFF     2733568    // u64[2][16]            256
#define T512_OFF    2733824    // u64[16]               128
#define CK_OFF      2733952    // u64[16][3072]     393,216
#define IDX_OFF     3127168    // u16[16][512]       16,384
#define KR_OFF      3143552    // u64[16][512]       65,536
#define MSK_OFF     3209088    // u64[16][512*8]    524,288
#define FB_OFF      3733376    // f4 [16][3072]     786,432  (fallback only)

struct Ptrs {
  const float *cls0,*cls1,*cls2,*cls3,*cls4;
  const float *reg0,*reg1,*reg2,*reg3,*reg4;
  const float *ctr0,*ctr1,*ctr2,*ctr3,*ctr4;
  const float *pos0,*pos1,*pos2,*pos3,*pos4;
  char *ws;
};

__device__ __forceinline__ float sigd(float x) {
  return (float)(1.0 / (1.0 + exp(-(double)x)));
}
__device__ __forceinline__ float dexp(float x) {
  return (float)exp((double)x);
}
__device__ __forceinline__ void levinfo(int gid, int& lev, int& idx, int& nl) {
  if      (gid < 12800) { lev=0; idx=gid;        nl=12800; }
  else if (gid < 16000) { lev=1; idx=gid-12800;  nl=3200;  }
  else if (gid < 16800) { lev=2; idx=gid-16000;  nl=800;   }
  else if (gid < 17008) { lev=3; idx=gid-16800;  nl=208;   }
  else                  { lev=4; idx=gid-17008;  nl=56;    }
}

__device__ __forceinline__ u64* ckeys_of(char* ws, int b) {
  return (u64*)(ws + CK_OFF + (size_t)b * 24576);
}
__device__ __forceinline__ u16* idx512_of(char* ws, int b) {
  return (u16*)(ws + IDX_OFF + (size_t)b * 1024);
}
__device__ __forceinline__ u64* krank_of(char* ws, int b) {
  return (u64*)(ws + KR_OFF + (size_t)b * 4096);
}
__device__ __forceinline__ u64* msk_of(char* ws, int b) {
  return (u64*)(ws + MSK_OFF + (size_t)b * 32768);
}
__device__ __forceinline__ float4* fb_of(char* ws, int b) {
  return (float4*)(ws + FB_OFF + (size_t)b * 49152);
}

// exact box decode (identical everywhere -> deterministic)
__device__ __forceinline__ float4 decode_box(const Ptrs& P, int b, int gid) {
  int lev, idx, nl; levinfo(gid, lev, idx, nl);
  const float *rp, *pp;
  if      (lev == 0) { rp = P.reg0; pp = P.pos0; }
  else if (lev == 1) { rp = P.reg1; pp = P.pos1; }
  else if (lev == 2) { rp = P.reg2; pp = P.pos2; }
  else if (lev == 3) { rp = P.reg3; pp = P.pos3; }
  else               { rp = P.reg4; pp = P.pos4; }
  float4 rv = *(const float4*)(rp + (size_t)(b * nl + idx) * 4);
  float2 pv = *(const float2*)(pp + (size_t)(b * nl + idx) * 2);
  float e0 = dexp(rv.x), e1 = dexp(rv.y), e2 = dexp(rv.z), e3 = dexp(rv.w);
  float x1 = truncf(pv.x - e0), y1 = truncf(pv.y - e1);
  float x2 = truncf(pv.x + e2), y2 = truncf(pv.y + e3);
  x1 = fmaxf(x1, 0.0f); y1 = fmaxf(y1, 0.0f);
  x2 = fminf(x2, 1023.0f); y2 = fminf(y2, 799.0f);
  return make_float4(x1, y1, x2, y2);
}

// ---------------- K1: 4-threads-per-position score / argmax / key ----------------
__global__ __launch_bounds__(256) void k_score(Ptrs P) {
  int t = blockIdx.x * 256 + threadIdx.x;
  int g = t >> 2, q = t & 3;
  if (g >= TOTAL_G) return;
  int b = blockIdx.y;

  int lev, idx, nl;
  levinfo(g, lev, idx, nl);
  const float *clsb, *ctrb;
  if      (lev == 0) { clsb = P.cls0; ctrb = P.ctr0; }
  else if (lev == 1) { clsb = P.cls1; ctrb = P.ctr1; }
  else if (lev == 2) { clsb = P.cls2; ctrb = P.ctr2; }
  else if (lev == 3) { clsb = P.cls3; ctrb = P.ctr3; }
  else               { clsb = P.cls4; ctrb = P.ctr4; }

  const float4* cp4 = (const float4*)(clsb + (size_t)(b * nl + idx) * 80) + q * 5;
  float m = -INFINITY, m2 = -INFINITY; int mi = 0;
  #pragma unroll
  for (int k = 0; k < 5; ++k) {
    float4 v = cp4[k];
    int base = q * 20 + 4 * k;
    if (v.x > m) { m2 = m; m = v.x; mi = base+0; } else if (v.x > m2) m2 = v.x;
    if (v.y > m) { m2 = m; m = v.y; mi = base+1; } else if (v.y > m2) m2 = v.y;
    if (v.z > m) { m2 = m; m = v.z; mi = base+2; } else if (v.z > m2) m2 = v.z;
    if (v.w > m) { m2 = m; m = v.w; mi = base+3; } else if (v.w > m2) m2 = v.w;
  }
  #pragma unroll
  for (int xw = 1; xw <= 2; xw <<= 1) {
    float om  = __shfl_xor(m,  xw);
    float om2 = __shfl_xor(m2, xw);
    int   omi = __shfl_xor(mi, xw);
    bool take = (om > m) || (om == m && omi < mi);
    float lm  = take ? m : om;
    float wm2 = take ? om2 : m2;
    if (take) { m = om; mi = omi; }
    m2 = fmaxf(lm, wm2);
  }

  float thr = fminf(m - 1e-3f, 9.0f);
  float pmax; int ci;
  if (m2 >= thr) {
    float pv = -1.0f; int pi = 0x7fffffff;
    #pragma unroll 1
    for (int k = 0; k < 5; ++k) {
      float4 v = cp4[k];
      float xs[4] = {v.x, v.y, v.z, v.w};
      #pragma unroll
      for (int e = 0; e < 4; ++e) {
        if (xs[e] >= thr) {
          float p = sigd(xs[e]);
          if (p > pv) { pv = p; pi = q * 20 + 4 * k + e; }
        }
      }
    }
    #pragma unroll
    for (int xw = 1; xw <= 2; xw <<= 1) {
      float ov = __shfl_xor(pv, xw);
      int   oi = __shfl_xor(pi, xw);
      if (ov > pv || (ov == pv && oi < pi)) { pv = ov; pi = oi; }
    }
    pmax = pv; ci = pi;
  } else {
    pmax = sigd(m); ci = mi;
  }

  if (q == 0) {
    float tc = ctrb[(size_t)b * nl + idx];
    float csig = sigd(tc);
    float prod = pmax * csig;
    float s = (float)sqrt((double)prod);
    ((u16*)(P.ws + CLSI_OFF))[(size_t)b * TOTAL_G + g] = (u16)ci;
    unsigned hi = ~__float_as_uint(s);
    u64 key = ((u64)hi << 15) | (unsigned)g;
    if      (lev == 0) ((u64*)(P.ws + KEYS0_OFF))  [(size_t)b * 12800 + idx] = key;
    else if (lev == 1) ((u64*)(P.ws + KEYS1_OFF))  [(size_t)b * 3200  + idx] = key;
    else               ((u64*)(P.ws + KEYS234_OFF))[(size_t)b * 1088  + (g - 16000)] = key;
  }
}

// ---------------- adaptive radix select ----------------
struct SelSh {
  u32 hist[4][4096];   // 64 KB, 4 replicas
  u64 buf[64];
  u64 res, pfx;
  int t, mode, cnt;
};

__device__ __forceinline__ u64 loadkey(const Ptrs& P, int b, int u) {
  if (u < 12800) return ((const u64*)(P.ws + KEYS0_OFF))  [(size_t)b * 12800 + u];
  if (u < 16000) return ((const u64*)(P.ws + KEYS1_OFF))  [(size_t)b * 3200  + (u - 12800)];
  return               ((const u64*)(P.ws + KEYS234_OFF))[(size_t)b * 1088  + (u - 16000)];
}
__device__ __forceinline__ bool keep_pred(u64 k, int u, u64 T0, u64 T1) {
  bool valid = (u32)(k >> 15) < INVALID_HI;
  bool sel = (u < 12800) ? (k <= T0) : ((u < 16000) ? (k <= T1) : true);
  return valid && sel;
}

// exact t0-th smallest (1-indexed). keys distinct. key[46:45]==0b11 always.
// pred=false: iterate keys[0..n). pred=true: iterate union with keep_pred filter.
__device__ u64 fast_select(const Ptrs& P, int b, const u64* keys, int n,
                           bool pred, u64 T0, u64 T1, int t0, SelSh* S) {
  int tid = threadIdx.x, wid = tid >> 6, lane = tid & 63;
  int rep = wid & 3;
  u64 Pfx = 3; int t = t0;
  const int SS[4] = {33, 21, 9, 0};
  const int WW[4] = {12, 12, 12, 9};
  #pragma unroll 1
  for (int p = 0; p < 4; ++p) {
    int s = SS[p], wb = WW[p];
    u32 dmask = (1u << wb) - 1u;
    for (int i = tid; i < 4 * 4096; i += 1024) (&S->hist[0][0])[i] = 0;
    if (tid == 0) { S->mode = 0; S->cnt = 0; }
    __syncthreads();
    int N = pred ? TOTAL_G : n;
    for (int i = tid; i < N; i += 1024) {
      u64 k = pred ? loadkey(P, b, i) : keys[i];
      if (pred && !keep_pred(k, i, T0, T1)) continue;
      if ((k >> (s + wb)) == Pfx)
        atomicAdd(&S->hist[rep][(u32)(k >> s) & dmask], 1u);
    }
    __syncthreads();
    for (int i = tid; i < 4096; i += 1024) {
      u32 v = S->hist[0][i] + S->hist[1][i] + S->hist[2][i] + S->hist[3][i];
      S->hist[0][i] = v;
    }
    __syncthreads();
    if (wid == 0) {
      u32 ssum = 0;
      #pragma unroll 8
      for (int i = 0; i < 64; ++i) {
        int ii = (i + lane) & 63;
        ssum += S->hist[0][(lane << 6) + ii];
      }
      u32 inc = ssum;
      for (int o = 1; o < 64; o <<= 1) { u32 v = __shfl_up(inc, o); if (lane >= o) inc += v; }
      u64 ball = __ballot(inc >= (u32)t);
      int Wq = __ffsll(ball) - 1;
      u32 cumBefore = __shfl(inc - ssum, Wq);
      u32 v2 = S->hist[0][(Wq << 6) + lane];
      u32 inc2 = v2;
      for (int o = 1; o < 64; o <<= 1) { u32 x = __shfl_up(inc2, o); if (lane >= o) inc2 += x; }
      u64 ball2 = __ballot(cumBefore + inc2 >= (u32)t);
      int l2 = __ffsll(ball2) - 1;
      u32 cumB2 = __shfl(cumBefore + inc2 - v2, l2);
      u32 c = __shfl(v2, l2);
      if (lane == 0) {
        int d = (Wq << 6) + l2;
        u64 np = (Pfx << wb) | (u32)d;
        S->pfx = np; S->t = t - (int)cumB2;
        if (s == 0)       { S->mode = 9; S->res = np; }
        else if (c == 1)  { S->mode = 1; }
        else if (c <= 64) { S->mode = 2; }
      }
    }
    __syncthreads();
    int mode = S->mode; u64 np = S->pfx; int tt = S->t;
    if (mode == 9) return S->res;
    if (mode == 1 || mode == 2) {
      for (int i = tid; i < N; i += 1024) {
        u64 k = pred ? loadkey(P, b, i) : keys[i];
        if (pred && !keep_pred(k, i, T0, T1)) continue;
        if ((k >> s) == np) {
          if (mode == 1) S->res = k;                       // unique match
          else { int pos = atomicAdd(&S->cnt, 1); S->buf[pos] = k; }
        }
      }
      __syncthreads();
      if (mode == 2 && wid == 0) {
        int c2 = S->cnt;
        u64 kl = (lane < c2) ? S->buf[lane] : ALLF;
        int r = 0;
        for (int j = 0; j < c2; ++j) r += (S->buf[j] < kl) ? 1 : 0;
        if (lane < c2 && r == tt - 1) S->res = kl;         // keys distinct -> unique
      }
      __syncthreads();
      return S->res;
    }
    Pfx = np; t = tt;
    __syncthreads();
  }
  return S->pfx;   // unreachable (s==0 pass always exits via mode 9)
}

// ---------------- K2a: per-level top-1000 thresholds (grid 16 x 2) ----------------
__global__ __launch_bounds__(1024) void k_sel(Ptrs P) {
  __shared__ SelSh S;
  int b = blockIdx.x, lev = blockIdx.y;
  const u64* keys = lev ? ((const u64*)(P.ws + KEYS1_OFF) + (size_t)b * 3200)
                        : ((const u64*)(P.ws + KEYS0_OFF) + (size_t)b * 12800);
  int n = lev ? 3200 : 12800;
  u64 T = fast_select(P, b, keys, n, false, 0, 0, 1000, &S);
  if (threadIdx.x == 0) ((u64*)(P.ws + T01_OFF))[lev * 16 + b] = T;
}

// ---------------- K2b: Nc + T512 + compaction + idx512 (grid 16) ----------------
__global__ __launch_bounds__(1024) void k_comp(Ptrs P) {
  __shared__ SelSh S;
  __shared__ int wbase[272], wbase2[272];
  __shared__ int sNc;
  int b = blockIdx.x;
  int tid = threadIdx.x, wid = tid >> 6, lane = tid & 63;
  u64 T0 = ((u64*)(P.ws + T01_OFF))[b];
  u64 T1 = ((u64*)(P.ws + T01_OFF))[16 + b];

  // count survivors
  for (int it = 0; it < 17; ++it) {
    int u = it * 1024 + tid;
    bool keep = false;
    if (u < TOTAL_G) keep = keep_pred(loadkey(P, b, u), u, T0, T1);
    u64 bal = __ballot(keep);
    if (lane == 0) wbase[it * 16 + wid] = __popcll(bal);
  }
  __syncthreads();
  if (tid == 0) {
    int run = 0;
    for (int i = 0; i < 272; ++i) { int c = wbase[i]; wbase[i] = run; run += c; }
    sNc = run;
    ((int*)(P.ws + NC_OFF))[b] = run;
  }
  __syncthreads();
  int Nc = sNc;

  // exact global 512th key over the filtered union
  u64 T512 = ALLF;
  if (Nc > 512) T512 = fast_select(P, b, (const u64*)0, 0, true, T0, T1, 512, &S);
  if (tid == 0) ((u64*)(P.ws + T512_OFF))[b] = T512;

  // top-512 member counts (idx512 scatter bases)
  for (int it = 0; it < 17; ++it) {
    int u = it * 1024 + tid;
    bool keep5 = false;
    if (u < TOTAL_G) {
      u64 k = loadkey(P, b, u);
      keep5 = keep_pred(k, u, T0, T1) && (k <= T512);
    }
    u64 bal = __ballot(keep5);
    if (lane == 0) wbase2[it * 16 + wid] = __popcll(bal);
  }
  __syncthreads();
  if (tid == 0) {
    int run = 0;
    for (int i = 0; i < 272; ++i) { int c = wbase2[i]; wbase2[i] = run; run += c; }
  }
  __syncthreads();

  // scatter ck (compact order) + idx512
  u64* ck = ckeys_of(P.ws, b);
  u16* ix = idx512_of(P.ws, b);
  for (int it = 0; it < 17; ++it) {
    int u = it * 1024 + tid;
    bool keep = false; u64 k = 0;
    if (u < TOTAL_G) {
      k = loadkey(P, b, u);
      keep = keep_pred(k, u, T0, T1);
    }
    bool keep5 = keep && (k <= T512);
    u64 bal  = __ballot(keep);
    u64 bal5 = __ballot(keep5);
    u64 lm = (1ull << lane) - 1ull;
    int pos  = wbase [it * 16 + wid] + __popcll(bal  & lm);
    int pos5 = wbase2[it * 16 + wid] + __popcll(bal5 & lm);
    if (keep)  ck[pos] = k;
    if (keep5) ix[pos5] = (u16)pos;
  }
}

// ---------------- K3: rank-all + decode + rank-space mask (grid 4 x 16) ----------------
__global__ __launch_bounds__(1024) void k_mask(Ptrs P) {
  __shared__ u64 skey[512];
  __shared__ float4 sbox[512];
  __shared__ u16 srank[512];
  __shared__ u16 parts[1024];
  __shared__ u64 smaskR[512 * 8];   // 32 KB, rank-space rows
  int qi = blockIdx.x, b = blockIdx.y;
  int tid = threadIdx.x;
  char* ws = P.ws;
  int Nc = ((int*)(ws + NC_OFF))[b];
  int n512 = Nc < 512 ? Nc : 512;
  const u64* ck = ckeys_of(ws, b);
  const u16* ix = idx512_of(ws, b);

  if (tid < 512) {
    if (tid < n512) {
      u64 k = ck[ix[tid]];
      skey[tid] = k;
      sbox[tid] = decode_box(P, b, (int)(k & 0x7FFF));
    } else {
      skey[tid] = (ALLF - 511) + (u64)tid;   // distinct, > any real key
      sbox[tid] = make_float4(-1e30f, -1e30f, -1e30f, -1e30f);
    }
  }
  for (int i = tid; i < 512 * 8; i += 1024) smaskR[i] = 0ull;
  __syncthreads();

  // rank all 512 by key (split halves across the two 512-thread groups)
  {
    int t2 = tid & 511, half = tid >> 9;
    u64 mykey = skey[t2];
    int jb = half << 8, cnt = 0;
    #pragma unroll 4
    for (int j = jb; j < jb + 256; ++j) cnt += (skey[j] < mykey) ? 1 : 0;
    parts[tid] = (u16)cnt;
  }
  __syncthreads();
  if (tid < 512) srank[tid] = (u16)(parts[tid] + parts[tid + 512]);
  __syncthreads();

  // suppression bits in rank space (rotated j-scan; bits sparse -> atomicOr cheap)
  int i = qi * 128 + (tid >> 3);
  int w = tid & 7;
  float4 bi = sbox[i];
  u64 ki = skey[i];
  int ri = srank[i];
  float ia = (bi.z - bi.x) * (bi.w - bi.y);
  #pragma unroll 8
  for (int bj = 0; bj < 64; ++bj) {
    int jj = (bj + w) & 63;
    int j = (w << 6) | jj;
    u64 kj = skey[j];
    if (ki < kj) {
      float4 bj4 = sbox[j];
      float ja  = (bj4.z - bj4.x) * (bj4.w - bj4.y);
      float ltx = fmaxf(bi.x, bj4.x), lty = fmaxf(bi.y, bj4.y);
      float rbx = fminf(bi.z, bj4.z), rby = fminf(bi.w, bj4.w);
      float wv = fmaxf(rbx - ltx, 0.0f), hv = fmaxf(rby - lty, 0.0f);
      float inter = wv * hv;
      float iou = inter / (ia + ja - inter);   // exact: integer-valued fp32
      if (iou > 0.6f) {
        int rj = srank[j];
        atomicOr(&smaskR[ri * 8 + (rj >> 6)], 1ull << (rj & 63));
      }
    }
  }
  __syncthreads();

  // write this block's 128 rank-rows + krank scatter
  {
    int il = tid >> 3, ww = tid & 7;
    int ig = qi * 128 + il;
    if (ig < n512) {
      int r = srank[ig];
      msk_of(ws, b)[r * 8 + ww] = smaskR[r * 8 + ww];
      if (ww == 0) krank_of(ws, b)[r] = skey[ig];
    }
  }
}

// ---------------- K4: greedy ffs walk + fallback + outputs (grid 16, 256 thr) ----------------
__global__ __launch_bounds__(256) void k_reduce(Ptrs P, float* out) {
  __shared__ u64 smask[4096];       // 32 KB
  __shared__ u32 keeplist[100];     // <512: rank; 0x8000|c: compact index
  __shared__ int slotgid[100];
  __shared__ int keptS;
  // fallback scratch
  __shared__ u64 liveC[48];
  __shared__ u64 pk[256];
  __shared__ int pc[256];
  __shared__ float4 fkb[100];
  __shared__ u64 bk; __shared__ int bc2;

  int b = blockIdx.x;
  int tid = threadIdx.x;
  char* ws = P.ws;
  int Nc = ((int*)(ws + NC_OFF))[b];
  int n512 = Nc < 512 ? Nc : 512;
  const u64* ck = ckeys_of(ws, b);
  const u64* kr = krank_of(ws, b);

  const u64* gmask = msk_of(ws, b);
  for (int t = tid; t < 4096; t += 256) smask[t] = gmask[t];
  __syncthreads();

  // single-wave barrier-free greedy walk over ranks [0, n512)
  if (tid < 64) {
    int lane = tid;
    u64 lw = 0;
    if (lane < 8) {
      int lo = lane << 6;
      int c = n512 - lo; if (c < 0) c = 0; if (c > 64) c = 64;
      lw = (c >= 64) ? ALLF : ((c > 0) ? ((1ull << c) - 1ull) : 0ull);
    }
    int kept = 0;
    while (kept < 100) {
      bool nz = (lane < 8) && (lw != 0ull);
      u64 bal = __ballot(nz);
      if (!bal) break;
      int W = __ffsll(bal) - 1;
      u64 wv = __shfl(lw, W);
      int bit = __ffsll(wv) - 1;
      int i = (W << 6) + bit;
      if (lane == 0) keeplist[kept] = (u32)i;
      kept++;
      if (lane == W) lw &= ~(1ull << bit);
      if (kept == 100) break;
      if (lane < 8) lw &= ~smask[i * 8 + lane];
    }
    if (lane == 0) keptS = kept;
  }
  __syncthreads();
  int kept = keptS;

  // fallback: keeps beyond the global top-512 (rare; exact)
  if (kept < 100 && Nc > 512) {
    u64 T512 = ((u64*)(ws + T512_OFF))[b];
    float4* fb = fb_of(ws, b);
    if (tid < 48) {
      int lo = tid << 6;
      u64 m = 0;
      for (int e = 0; e < 64; ++e) {
        int c = lo + e;
        if (c < Nc && ck[c] > T512) m |= (1ull << e);
      }
      liveC[tid] = m;
    }
    for (int c = tid; c < Nc; c += 256)
      if (ck[c] > T512) fb[c] = decode_box(P, b, (int)(ck[c] & 0x7FFF));
    if (tid < kept) fkb[tid] = decode_box(P, b, (int)(kr[keeplist[tid]] & 0x7FFF));
    __syncthreads();

    for (int k2 = 0; k2 < kept; ++k2) {
      float4 bi = fkb[k2];
      float ia = (bi.z - bi.x) * (bi.w - bi.y);
      for (int j = tid; j < Nc; j += 256) {
        if (!((liveC[j >> 6] >> (j & 63)) & 1ull)) continue;
        float4 bj4 = fb[j];
        float ja  = (bj4.z - bj4.x) * (bj4.w - bj4.y);
        float ltx = fmaxf(bi.x, bj4.x), lty = fmaxf(bi.y, bj4.y);
        float rbx = fminf(bi.z, bj4.z), rby = fminf(bi.w, bj4.w);
        float wv = fmaxf(rbx - ltx, 0.0f), hv = fmaxf(rby - lty, 0.0f);
        float inter = wv * hv;
        float iou = inter / (ia + ja - inter);
        if (iou > 0.6f) atomicAnd(&liveC[j >> 6], ~(1ull << (j & 63)));
      }
    }
    __syncthreads();

    while (kept < 100) {
      u64 mymin = ALLF; int myc = -1;
      for (int c = tid; c < Nc; c += 256) {
        if (!((liveC[c >> 6] >> (c & 63)) & 1ull)) continue;
        u64 k = ck[c];
        if (k < mymin) { mymin = k; myc = c; }
      }
      pk[tid] = mymin; pc[tid] = myc;
      __syncthreads();
      if (tid < 64) {
        u64 m = pk[tid]; int c0 = pc[tid];
        #pragma unroll
        for (int o = 64; o < 256; o += 64)
          if (pk[tid + o] < m) { m = pk[tid + o]; c0 = pc[tid + o]; }
        for (int o = 32; o > 0; o >>= 1) {
          u64 om = __shfl_down(m, o); int oc = __shfl_down(c0, o);
          if (om < m) { m = om; c0 = oc; }
        }
        if (tid == 0) { bk = m; bc2 = c0; }
      }
      __syncthreads();
      if (bk == ALLF) break;
      int cs = bc2;
      if (tid == 0) {
        keeplist[kept] = 0x8000u | (u32)cs;
        atomicAnd(&liveC[cs >> 6], ~(1ull << (cs & 63)));
      }
      __syncthreads();
      kept++;
      if (kept == 100) break;
      float4 bi = fb[cs];
      float ia = (bi.z - bi.x) * (bi.w - bi.y);
      for (int j = tid; j < Nc; j += 256) {
        if (!((liveC[j >> 6] >> (j & 63)) & 1ull)) continue;
        float4 bj4 = fb[j];
        float ja  = (bj4.z - bj4.x) * (bj4.w - bj4.y);
        float ltx = fmaxf(bi.x, bj4.x), lty = fmaxf(bi.y, bj4.y);
        float rbx = fminf(bi.z, bj4.z), rby = fminf(bi.w, bj4.w);
        float wv = fmaxf(rbx - ltx, 0.0f), hv = fmaxf(rby - lty, 0.0f);
        float inter = wv * hv;
        float iou = inter / (ia + ja - inter);
        if (iou > 0.6f) atomicAnd(&liveC[j >> 6], ~(1ull << (j & 63)));
      }
      __syncthreads();
    }
  }

  // outputs: out_s @0 [16,100], out_c @1600, out_b @3200 [16,100,4], out_cp @9600
  if (tid < 100) {
    int s = tid;
    float os = -1.0f, oc = -1.0f;
    float4 bx = make_float4(-1.0f, -1.0f, -1.0f, -1.0f);
    int gid = -1;
    if (s < kept) {
      u32 e = keeplist[s];
      u64 key = (e & 0x8000u) ? ck[e & 0x7FFFu] : kr[e];
      gid = (int)(key & 0x7FFF);
      os = __uint_as_float(~(u32)(key >> 15));
      oc = (float)((u16*)(ws + CLSI_OFF))[(size_t)b * TOTAL_G + gid];
      bx = decode_box(P, b, gid);
    }
    slotgid[s] = gid;
    out[b * 100 + s] = os;
    out[1600 + b * 100 + s] = oc;
    *(float4*)(out + 3200 + (size_t)(b * 100 + s) * 4) = bx;
  }
  __syncthreads();
  for (int t = tid; t < 100 * 80; t += 256) {
    int s = t / 80, k = t - s * 80;
    float val = -1.0f;
    int gid = slotgid[s];
    if (gid >= 0) {
      int lev, idx, nl; levinfo(gid, lev, idx, nl);
      const float* cp;
      if      (lev == 0) cp = P.cls0;
      else if (lev == 1) cp = P.cls1;
      else if (lev == 2) cp = P.cls2;
      else if (lev == 3) cp = P.cls3;
      else               cp = P.cls4;
      val = sigd(cp[(size_t)(b * nl + idx) * 80 + k]);
    }
    out[9600 + (size_t)(b * 100 + s) * 80 + k] = val;
  }
}

extern "C" void kernel_launch(void* const* d_in, const int* in_sizes, int n_in,
                              void* d_out, int out_size, void* d_ws, size_t ws_size,
                              hipStream_t stream) {
  (void)in_sizes; (void)n_in; (void)out_size; (void)ws_size;
  Ptrs P;
  P.cls0 = (const float*)d_in[0];  P.reg0 = (const float*)d_in[1];
  P.ctr0 = (const float*)d_in[2];  P.pos0 = (const float*)d_in[3];
  P.cls1 = (const float*)d_in[4];  P.reg1 = (const float*)d_in[5];
  P.ctr1 = (const float*)d_in[6];  P.pos1 = (const float*)d_in[7];
  P.cls2 = (const float*)d_in[8];  P.reg2 = (const float*)d_in[9];
  P.ctr2 = (const float*)d_in[10]; P.pos2 = (const float*)d_in[11];
  P.cls3 = (const float*)d_in[12]; P.reg3 = (const float*)d_in[13];
  P.ctr3 = (const float*)d_in[14]; P.pos3 = (const float*)d_in[15];
  P.cls4 = (const float*)d_in[16]; P.reg4 = (const float*)d_in[17];
  P.ctr4 = (const float*)d_in[18]; P.pos4 = (const float*)d_in[19];
  P.ws = (char*)d_ws;

  k_score<<<dim3(267, 16), 256, 0, stream>>>(P);
  k_sel<<<dim3(16, 2), 1024, 0, stream>>>(P);
  k_comp<<<16, 1024, 0, stream>>>(P);
  k_mask<<<dim3(4, 16), 1024, 0, stream>>>(P);
  k_reduce<<<16, 256, 0, stream>>>(P, (float*)d_out);
}

// Round 8
// 136.020 us; speedup vs baseline: 1.5193x; 1.1654x over previous
//
#include <hip/hip_runtime.h>
#include <math.h>

#define TOTAL_G 17064
#define BATCHN  16
#define ALLF    0xFFFFFFFFFFFFFFFFull
// valid <=> score > 0.01f <=> scorebits > 0x3C23D70A <=> (key>>15) < 0xC3DC28F5
#define INVALID_HI 0xC3DC28F5u

typedef unsigned long long u64;
typedef unsigned int u32;
typedef unsigned short u16;

// ---- ws layout (bytes), total 4,532,608 ----
#define KEYS0_OFF   0          // u64[16][12800]  1,638,400
#define KEYS1_OFF   1638400    // u64[16][3200]     409,600
#define KEYS234_OFF 2048000    // u64[16][1088]     139,264
#define CLSI_OFF    2187264    // u16[16][17064]    546,048
#define NC_OFF      2733312    // int[16] (+pad)        256
#define T01_OFF     2733568    // u64[2][16]            256
#define T512_OFF    2733824    // u64[16]               128
#define CK_OFF      2733952    // u64[16][3072]     393,216
#define IDX_OFF     3127168    // u16[16][512]       16,384
#define KR_OFF      3143552    // u64[16][512]       65,536
#define MSK_OFF     3209088    // u64[16][512*8]    524,288
#define FB_OFF      3733376    // f4 [16][3072]     786,432  (fallback only)
#define SLOTK_OFF   4519808    // u64[16][100]       12,800

struct Ptrs {
  const float *cls0,*cls1,*cls2,*cls3,*cls4;
  const float *reg0,*reg1,*reg2,*reg3,*reg4;
  const float *ctr0,*ctr1,*ctr2,*ctr3,*ctr4;
  const float *pos0,*pos1,*pos2,*pos3,*pos4;
  char *ws;
};

__device__ __forceinline__ float sigd(float x) {
  return (float)(1.0 / (1.0 + exp(-(double)x)));
}
__device__ __forceinline__ float dexp(float x) {
  return (float)exp((double)x);
}
__device__ __forceinline__ void levinfo(int gid, int& lev, int& idx, int& nl) {
  if      (gid < 12800) { lev=0; idx=gid;        nl=12800; }
  else if (gid < 16000) { lev=1; idx=gid-12800;  nl=3200;  }
  else if (gid < 16800) { lev=2; idx=gid-16000;  nl=800;   }
  else if (gid < 17008) { lev=3; idx=gid-16800;  nl=208;   }
  else                  { lev=4; idx=gid-17008;  nl=56;    }
}

__device__ __forceinline__ u64* ckeys_of(char* ws, int b) {
  return (u64*)(ws + CK_OFF + (size_t)b * 24576);
}
__device__ __forceinline__ u16* idx512_of(char* ws, int b) {
  return (u16*)(ws + IDX_OFF + (size_t)b * 1024);
}
__device__ __forceinline__ u64* krank_of(char* ws, int b) {
  return (u64*)(ws + KR_OFF + (size_t)b * 4096);
}
__device__ __forceinline__ u64* msk_of(char* ws, int b) {
  return (u64*)(ws + MSK_OFF + (size_t)b * 32768);
}
__device__ __forceinline__ float4* fb_of(char* ws, int b) {
  return (float4*)(ws + FB_OFF + (size_t)b * 49152);
}
__device__ __forceinline__ u64* slotkey_of(char* ws, int b) {
  return (u64*)(ws + SLOTK_OFF + (size_t)b * 800);
}

// exact box decode (identical everywhere -> deterministic)
__device__ __forceinline__ float4 decode_box(const Ptrs& P, int b, int gid) {
  int lev, idx, nl; levinfo(gid, lev, idx, nl);
  const float *rp, *pp;
  if      (lev == 0) { rp = P.reg0; pp = P.pos0; }
  else if (lev == 1) { rp = P.reg1; pp = P.pos1; }
  else if (lev == 2) { rp = P.reg2; pp = P.pos2; }
  else if (lev == 3) { rp = P.reg3; pp = P.pos3; }
  else               { rp = P.reg4; pp = P.pos4; }
  float4 rv = *(const float4*)(rp + (size_t)(b * nl + idx) * 4);
  float2 pv = *(const float2*)(pp + (size_t)(b * nl + idx) * 2);
  float e0 = dexp(rv.x), e1 = dexp(rv.y), e2 = dexp(rv.z), e3 = dexp(rv.w);
  float x1 = truncf(pv.x - e0), y1 = truncf(pv.y - e1);
  float x2 = truncf(pv.x + e2), y2 = truncf(pv.y + e3);
  x1 = fmaxf(x1, 0.0f); y1 = fmaxf(y1, 0.0f);
  x2 = fminf(x2, 1023.0f); y2 = fminf(y2, 799.0f);
  return make_float4(x1, y1, x2, y2);
}

// ---------------- K1: LDS-staged, 4-threads-per-position score / argmax / key ----------------
__global__ __launch_bounds__(256) void k_score(Ptrs P) {
  __shared__ float4 sk4[64 * 20];   // 64 positions x 320 B = 20 KB
  int b = blockIdx.y;
  int tid = threadIdx.x;
  int p0 = blockIdx.x * 64;

  // stage: 5 iterations, contiguous within a level (perfectly coalesced)
  #pragma unroll
  for (int it = 0; it < 5; ++it) {
    int t4 = it * 256 + tid;
    int g = p0 + t4 / 20;
    if (g < TOTAL_G) {
      int sub = t4 - (t4 / 20) * 20;
      int lev, idx, nl; levinfo(g, lev, idx, nl);
      const float* clsb;
      if      (lev == 0) clsb = P.cls0;
      else if (lev == 1) clsb = P.cls1;
      else if (lev == 2) clsb = P.cls2;
      else if (lev == 3) clsb = P.cls3;
      else               clsb = P.cls4;
      sk4[t4] = ((const float4*)(clsb + (size_t)(b * nl + idx) * 80))[sub];
    }
  }
  __syncthreads();

  int lp = tid >> 2, q = tid & 3;
  int g = p0 + lp;
  if (g >= TOTAL_G) return;

  const float4* my4 = &sk4[lp * 20 + q * 5];
  float m = -INFINITY, m2 = -INFINITY; int mi = 0;
  #pragma unroll
  for (int k = 0; k < 5; ++k) {
    float4 v = my4[k];
    int base = q * 20 + 4 * k;
    if (v.x > m) { m2 = m; m = v.x; mi = base+0; } else if (v.x > m2) m2 = v.x;
    if (v.y > m) { m2 = m; m = v.y; mi = base+1; } else if (v.y > m2) m2 = v.y;
    if (v.z > m) { m2 = m; m = v.z; mi = base+2; } else if (v.z > m2) m2 = v.z;
    if (v.w > m) { m2 = m; m = v.w; mi = base+3; } else if (v.w > m2) m2 = v.w;
  }
  #pragma unroll
  for (int xw = 1; xw <= 2; xw <<= 1) {
    float om  = __shfl_xor(m,  xw);
    float om2 = __shfl_xor(m2, xw);
    int   omi = __shfl_xor(mi, xw);
    bool take = (om > m) || (om == m && omi < mi);
    float lm  = take ? m : om;
    float wm2 = take ? om2 : m2;
    if (take) { m = om; mi = omi; }
    m2 = fmaxf(lm, wm2);
  }

  float thr = fminf(m - 1e-3f, 9.0f);
  float pmax; int ci;
  if (m2 >= thr) {
    // rare exact path: per-element sigmoid argmax among candidates >= thr
    float pv = -1.0f; int pi = 0x7fffffff;
    #pragma unroll 1
    for (int k = 0; k < 5; ++k) {
      float4 v = my4[k];
      float xs[4] = {v.x, v.y, v.z, v.w};
      #pragma unroll
      for (int e = 0; e < 4; ++e) {
        if (xs[e] >= thr) {
          float p = sigd(xs[e]);
          if (p > pv) { pv = p; pi = q * 20 + 4 * k + e; }
        }
      }
    }
    #pragma unroll
    for (int xw = 1; xw <= 2; xw <<= 1) {
      float ov = __shfl_xor(pv, xw);
      int   oi = __shfl_xor(pi, xw);
      if (ov > pv || (ov == pv && oi < pi)) { pv = ov; pi = oi; }
    }
    pmax = pv; ci = pi;
  } else {
    pmax = sigd(m); ci = mi;
  }

  if (q == 0) {
    int lev, idx, nl; levinfo(g, lev, idx, nl);
    const float* ctrb;
    if      (lev == 0) ctrb = P.ctr0;
    else if (lev == 1) ctrb = P.ctr1;
    else if (lev == 2) ctrb = P.ctr2;
    else if (lev == 3) ctrb = P.ctr3;
    else               ctrb = P.ctr4;
    float tc = ctrb[(size_t)b * nl + idx];
    float csig = sigd(tc);
    float prod = pmax * csig;
    float s = (float)sqrt((double)prod);
    ((u16*)(P.ws + CLSI_OFF))[(size_t)b * TOTAL_G + g] = (u16)ci;
    unsigned hi = ~__float_as_uint(s);
    u64 key = ((u64)hi << 15) | (unsigned)g;
    if      (lev == 0) ((u64*)(P.ws + KEYS0_OFF))  [(size_t)b * 12800 + idx] = key;
    else if (lev == 1) ((u64*)(P.ws + KEYS1_OFF))  [(size_t)b * 3200  + idx] = key;
    else               ((u64*)(P.ws + KEYS234_OFF))[(size_t)b * 1088  + (g - 16000)] = key;
  }
}

// ---------------- adaptive radix select ----------------
struct SelSh {
  u32 hist[4][4096];   // 64 KB, 4 replicas
  u64 buf[64];
  u64 res, pfx;
  int t, mode, cnt;
};

__device__ __forceinline__ u64 loadkey(const Ptrs& P, int b, int u) {
  if (u < 12800) return ((const u64*)(P.ws + KEYS0_OFF))  [(size_t)b * 12800 + u];
  if (u < 16000) return ((const u64*)(P.ws + KEYS1_OFF))  [(size_t)b * 3200  + (u - 12800)];
  return               ((const u64*)(P.ws + KEYS234_OFF))[(size_t)b * 1088  + (u - 16000)];
}
__device__ __forceinline__ bool keep_pred(u64 k, int u, u64 T0, u64 T1) {
  bool valid = (u32)(k >> 15) < INVALID_HI;
  bool sel = (u < 12800) ? (k <= T0) : ((u < 16000) ? (k <= T1) : true);
  return valid && sel;
}

// exact t0-th smallest (1-indexed). keys distinct. key[46:45]==0b11 always.
__device__ u64 fast_select(const Ptrs& P, int b, const u64* keys, int n,
                           bool pred, u64 T0, u64 T1, int t0, SelSh* S) {
  int tid = threadIdx.x, wid = tid >> 6, lane = tid & 63;
  int rep = wid & 3;
  u64 Pfx = 3; int t = t0;
  const int SS[4] = {33, 21, 9, 0};
  const int WW[4] = {12, 12, 12, 9};
  #pragma unroll 1
  for (int p = 0; p < 4; ++p) {
    int s = SS[p], wb = WW[p];
    u32 dmask = (1u << wb) - 1u;
    for (int i = tid; i < 4 * 4096; i += 1024) (&S->hist[0][0])[i] = 0;
    if (tid == 0) { S->mode = 0; S->cnt = 0; }
    __syncthreads();
    int N = pred ? TOTAL_G : n;
    for (int i = tid; i < N; i += 1024) {
      u64 k = pred ? loadkey(P, b, i) : keys[i];
      if (pred && !keep_pred(k, i, T0, T1)) continue;
      if ((k >> (s + wb)) == Pfx)
        atomicAdd(&S->hist[rep][(u32)(k >> s) & dmask], 1u);
    }
    __syncthreads();
    for (int i = tid; i < 4096; i += 1024) {
      u32 v = S->hist[0][i] + S->hist[1][i] + S->hist[2][i] + S->hist[3][i];
      S->hist[0][i] = v;
    }
    __syncthreads();
    if (wid == 0) {
      u32 ssum = 0;
      #pragma unroll 8
      for (int i = 0; i < 64; ++i) {
        int ii = (i + lane) & 63;
        ssum += S->hist[0][(lane << 6) + ii];
      }
      u32 inc = ssum;
      for (int o = 1; o < 64; o <<= 1) { u32 v = __shfl_up(inc, o); if (lane >= o) inc += v; }
      u64 ball = __ballot(inc >= (u32)t);
      int Wq = __ffsll(ball) - 1;
      u32 cumBefore = __shfl(inc - ssum, Wq);
      u32 v2 = S->hist[0][(Wq << 6) + lane];
      u32 inc2 = v2;
      for (int o = 1; o < 64; o <<= 1) { u32 x = __shfl_up(inc2, o); if (lane >= o) inc2 += x; }
      u64 ball2 = __ballot(cumBefore + inc2 >= (u32)t);
      int l2 = __ffsll(ball2) - 1;
      u32 cumB2 = __shfl(cumBefore + inc2 - v2, l2);
      u32 c = __shfl(v2, l2);
      if (lane == 0) {
        int d = (Wq << 6) + l2;
        u64 np = (Pfx << wb) | (u32)d;
        S->pfx = np; S->t = t - (int)cumB2;
        if (s == 0)       { S->mode = 9; S->res = np; }
        else if (c == 1)  { S->mode = 1; }
        else if (c <= 64) { S->mode = 2; }
      }
    }
    __syncthreads();
    int mode = S->mode; u64 np = S->pfx; int tt = S->t;
    if (mode == 9) return S->res;
    if (mode == 1 || mode == 2) {
      for (int i = tid; i < N; i += 1024) {
        u64 k = pred ? loadkey(P, b, i) : keys[i];
        if (pred && !keep_pred(k, i, T0, T1)) continue;
        if ((k >> s) == np) {
          if (mode == 1) S->res = k;
          else { int pos = atomicAdd(&S->cnt, 1); S->buf[pos] = k; }
        }
      }
      __syncthreads();
      if (mode == 2 && wid == 0) {
        int c2 = S->cnt;
        u64 kl = (lane < c2) ? S->buf[lane] : ALLF;
        int r = 0;
        for (int j = 0; j < c2; ++j) r += (S->buf[j] < kl) ? 1 : 0;
        if (lane < c2 && r == tt - 1) S->res = kl;
      }
      __syncthreads();
      return S->res;
    }
    Pfx = np; t = tt;
    __syncthreads();
  }
  return S->pfx;
}

// ---------------- K2a: per-level top-1000 thresholds (grid 16 x 2) ----------------
__global__ __launch_bounds__(1024) void k_sel(Ptrs P) {
  __shared__ SelSh S;
  int b = blockIdx.x, lev = blockIdx.y;
  const u64* keys = lev ? ((const u64*)(P.ws + KEYS1_OFF) + (size_t)b * 3200)
                        : ((const u64*)(P.ws + KEYS0_OFF) + (size_t)b * 12800);
  int n = lev ? 3200 : 12800;
  u64 T = fast_select(P, b, keys, n, false, 0, 0, 1000, &S);
  if (threadIdx.x == 0) ((u64*)(P.ws + T01_OFF))[lev * 16 + b] = T;
}

// ---------------- K2b: Nc + T512 + compaction + idx512 (grid 16) ----------------
__global__ __launch_bounds__(1024) void k_comp(Ptrs P) {
  __shared__ SelSh S;
  __shared__ int wbase[272], wbase2[272];
  __shared__ int sNc;
  int b = blockIdx.x;
  int tid = threadIdx.x, wid = tid >> 6, lane = tid & 63;
  u64 T0 = ((u64*)(P.ws + T01_OFF))[b];
  u64 T1 = ((u64*)(P.ws + T01_OFF))[16 + b];

  for (int it = 0; it < 17; ++it) {
    int u = it * 1024 + tid;
    bool keep = false;
    if (u < TOTAL_G) keep = keep_pred(loadkey(P, b, u), u, T0, T1);
    u64 bal = __ballot(keep);
    if (lane == 0) wbase[it * 16 + wid] = __popcll(bal);
  }
  __syncthreads();
  if (tid == 0) {
    int run = 0;
    for (int i = 0; i < 272; ++i) { int c = wbase[i]; wbase[i] = run; run += c; }
    sNc = run;
    ((int*)(P.ws + NC_OFF))[b] = run;
  }
  __syncthreads();
  int Nc = sNc;

  u64 T512 = ALLF;
  if (Nc > 512) T512 = fast_select(P, b, (const u64*)0, 0, true, T0, T1, 512, &S);
  if (tid == 0) ((u64*)(P.ws + T512_OFF))[b] = T512;

  for (int it = 0; it < 17; ++it) {
    int u = it * 1024 + tid;
    bool keep5 = false;
    if (u < TOTAL_G) {
      u64 k = loadkey(P, b, u);
      keep5 = keep_pred(k, u, T0, T1) && (k <= T512);
    }
    u64 bal = __ballot(keep5);
    if (lane == 0) wbase2[it * 16 + wid] = __popcll(bal);
  }
  __syncthreads();
  if (tid == 0) {
    int run = 0;
    for (int i = 0; i < 272; ++i) { int c = wbase2[i]; wbase2[i] = run; run += c; }
  }
  __syncthreads();

  u64* ck = ckeys_of(P.ws, b);
  u16* ix = idx512_of(P.ws, b);
  for (int it = 0; it < 17; ++it) {
    int u = it * 1024 + tid;
    bool keep = false; u64 k = 0;
    if (u < TOTAL_G) {
      k = loadkey(P, b, u);
      keep = keep_pred(k, u, T0, T1);
    }
    bool keep5 = keep && (k <= T512);
    u64 bal  = __ballot(keep);
    u64 bal5 = __ballot(keep5);
    u64 lm = (1ull << lane) - 1ull;
    int pos  = wbase [it * 16 + wid] + __popcll(bal  & lm);
    int pos5 = wbase2[it * 16 + wid] + __popcll(bal5 & lm);
    if (keep)  ck[pos] = k;
    if (keep5) ix[pos5] = (u16)pos;
  }
}

// ---------------- K3: rank-all + decode + rank-space mask (grid 4 x 16) ----------------
__global__ __launch_bounds__(1024) void k_mask(Ptrs P) {
  __shared__ u64 skey[512];
  __shared__ float4 sbox[512];
  __shared__ u16 srank[512];
  __shared__ u16 parts[1024];
  __shared__ u64 smaskR[512 * 8];   // 32 KB, rank-space rows
  int qi = blockIdx.x, b = blockIdx.y;
  int tid = threadIdx.x;
  char* ws = P.ws;
  int Nc = ((int*)(ws + NC_OFF))[b];
  int n512 = Nc < 512 ? Nc : 512;
  const u64* ck = ckeys_of(ws, b);
  const u16* ix = idx512_of(ws, b);

  if (tid < 512) {
    if (tid < n512) {
      u64 k = ck[ix[tid]];
      skey[tid] = k;
      sbox[tid] = decode_box(P, b, (int)(k & 0x7FFF));
    } else {
      skey[tid] = (ALLF - 511) + (u64)tid;
      sbox[tid] = make_float4(-1e30f, -1e30f, -1e30f, -1e30f);
    }
  }
  for (int i = tid; i < 512 * 8; i += 1024) smaskR[i] = 0ull;
  __syncthreads();

  {
    int t2 = tid & 511, half = tid >> 9;
    u64 mykey = skey[t2];
    int jb = half << 8, cnt = 0;
    #pragma unroll 4
    for (int j = jb; j < jb + 256; ++j) cnt += (skey[j] < mykey) ? 1 : 0;
    parts[tid] = (u16)cnt;
  }
  __syncthreads();
  if (tid < 512) srank[tid] = (u16)(parts[tid] + parts[tid + 512]);
  __syncthreads();

  int i = qi * 128 + (tid >> 3);
  int w = tid & 7;
  float4 bi = sbox[i];
  u64 ki = skey[i];
  int ri = srank[i];
  float ia = (bi.z - bi.x) * (bi.w - bi.y);
  #pragma unroll 8
  for (int bj = 0; bj < 64; ++bj) {
    int jj = (bj + w) & 63;
    int j = (w << 6) | jj;
    u64 kj = skey[j];
    if (ki < kj) {
      float4 bj4 = sbox[j];
      float ja  = (bj4.z - bj4.x) * (bj4.w - bj4.y);
      float ltx = fmaxf(bi.x, bj4.x), lty = fmaxf(bi.y, bj4.y);
      float rbx = fminf(bi.z, bj4.z), rby = fminf(bi.w, bj4.w);
      float wv = fmaxf(rbx - ltx, 0.0f), hv = fmaxf(rby - lty, 0.0f);
      float inter = wv * hv;
      float iou = inter / (ia + ja - inter);   // exact: integer-valued fp32
      if (iou > 0.6f) {
        int rj = srank[j];
        atomicOr(&smaskR[ri * 8 + (rj >> 6)], 1ull << (rj & 63));
      }
    }
  }
  __syncthreads();

  {
    int il = tid >> 3, ww = tid & 7;
    int ig = qi * 128 + il;
    if (ig < n512) {
      int r = srank[ig];
      msk_of(ws, b)[r * 8 + ww] = smaskR[r * 8 + ww];
      if (ww == 0) krank_of(ws, b)[r] = skey[ig];
    }
  }
}

// ---------------- K4: greedy ffs walk + fallback + slotkey (grid 16, 256 thr) ----------------
__global__ __launch_bounds__(256) void k_reduce(Ptrs P) {
  __shared__ u64 smask[4096];       // 32 KB
  __shared__ u32 keeplist[100];     // <512: rank; 0x8000|c: compact index
  __shared__ int keptS;
  __shared__ u64 liveC[48];
  __shared__ u64 pk[256];
  __shared__ int pc[256];
  __shared__ float4 fkb[100];
  __shared__ u64 bk; __shared__ int bc2;

  int b = blockIdx.x;
  int tid = threadIdx.x;
  char* ws = P.ws;
  int Nc = ((int*)(ws + NC_OFF))[b];
  int n512 = Nc < 512 ? Nc : 512;
  const u64* ck = ckeys_of(ws, b);
  const u64* kr = krank_of(ws, b);

  const u64* gmask = msk_of(ws, b);
  for (int t = tid; t < 4096; t += 256) smask[t] = gmask[t];
  __syncthreads();

  if (tid < 64) {
    int lane = tid;
    u64 lw = 0;
    if (lane < 8) {
      int lo = lane << 6;
      int c = n512 - lo; if (c < 0) c = 0; if (c > 64) c = 64;
      lw = (c >= 64) ? ALLF : ((c > 0) ? ((1ull << c) - 1ull) : 0ull);
    }
    int kept = 0;
    while (kept < 100) {
      bool nz = (lane < 8) && (lw != 0ull);
      u64 bal = __ballot(nz);
      if (!bal) break;
      int W = __ffsll(bal) - 1;
      u64 wv = __shfl(lw, W);
      int bit = __ffsll(wv) - 1;
      int i = (W << 6) + bit;
      if (lane == 0) keeplist[kept] = (u32)i;
      kept++;
      if (lane == W) lw &= ~(1ull << bit);
      if (kept == 100) break;
      if (lane < 8) lw &= ~smask[i * 8 + lane];
    }
    if (lane == 0) keptS = kept;
  }
  __syncthreads();
  int kept = keptS;

  // fallback: keeps beyond the global top-512 (rare; exact)
  if (kept < 100 && Nc > 512) {
    u64 T512 = ((u64*)(ws + T512_OFF))[b];
    float4* fb = fb_of(ws, b);
    if (tid < 48) {
      int lo = tid << 6;
      u64 m = 0;
      for (int e = 0; e < 64; ++e) {
        int c = lo + e;
        if (c < Nc && ck[c] > T512) m |= (1ull << e);
      }
      liveC[tid] = m;
    }
    for (int c = tid; c < Nc; c += 256)
      if (ck[c] > T512) fb[c] = decode_box(P, b, (int)(ck[c] & 0x7FFF));
    if (tid < kept) fkb[tid] = decode_box(P, b, (int)(kr[keeplist[tid]] & 0x7FFF));
    __syncthreads();

    for (int k2 = 0; k2 < kept; ++k2) {
      float4 bi = fkb[k2];
      float ia = (bi.z - bi.x) * (bi.w - bi.y);
      for (int j = tid; j < Nc; j += 256) {
        if (!((liveC[j >> 6] >> (j & 63)) & 1ull)) continue;
        float4 bj4 = fb[j];
        float ja  = (bj4.z - bj4.x) * (bj4.w - bj4.y);
        float ltx = fmaxf(bi.x, bj4.x), lty = fmaxf(bi.y, bj4.y);
        float rbx = fminf(bi.z, bj4.z), rby = fminf(bi.w, bj4.w);
        float wv = fmaxf(rbx - ltx, 0.0f), hv = fmaxf(rby - lty, 0.0f);
        float inter = wv * hv;
        float iou = inter / (ia + ja - inter);
        if (iou > 0.6f) atomicAnd(&liveC[j >> 6], ~(1ull << (j & 63)));
      }
    }
    __syncthreads();

    while (kept < 100) {
      u64 mymin = ALLF; int myc = -1;
      for (int c = tid; c < Nc; c += 256) {
        if (!((liveC[c >> 6] >> (c & 63)) & 1ull)) continue;
        u64 k = ck[c];
        if (k < mymin) { mymin = k; myc = c; }
      }
      pk[tid] = mymin; pc[tid] = myc;
      __syncthreads();
      if (tid < 64) {
        u64 m = pk[tid]; int c0 = pc[tid];
        #pragma unroll
        for (int o = 64; o < 256; o += 64)
          if (pk[tid + o] < m) { m = pk[tid + o]; c0 = pc[tid + o]; }
        for (int o = 32; o > 0; o >>= 1) {
          u64 om = __shfl_down(m, o); int oc = __shfl_down(c0, o);
          if (om < m) { m = om; c0 = oc; }
        }
        if (tid == 0) { bk = m; bc2 = c0; }
      }
      __syncthreads();
      if (bk == ALLF) break;
      int cs = bc2;
      if (tid == 0) {
        keeplist[kept] = 0x8000u | (u32)cs;
        atomicAnd(&liveC[cs >> 6], ~(1ull << (cs & 63)));
      }
      __syncthreads();
      kept++;
      if (kept == 100) break;
      float4 bi = fb[cs];
      float ia = (bi.z - bi.x) * (bi.w - bi.y);
      for (int j = tid; j < Nc; j += 256) {
        if (!((liveC[j >> 6] >> (j & 63)) & 1ull)) continue;
        float4 bj4 = fb[j];
        float ja  = (bj4.z - bj4.x) * (bj4.w - bj4.y);
        float ltx = fmaxf(bi.x, bj4.x), lty = fmaxf(bi.y, bj4.y);
        float rbx = fminf(bi.z, bj4.z), rby = fminf(bi.w, bj4.w);
        float wv = fmaxf(rbx - ltx, 0.0f), hv = fmaxf(rby - lty, 0.0f);
        float inter = wv * hv;
        float iou = inter / (ia + ja - inter);
        if (iou > 0.6f) atomicAnd(&liveC[j >> 6], ~(1ull << (j & 63)));
      }
      __syncthreads();
    }
  }

  // resolve slot keys (ALLF = empty slot)
  if (tid < 100) {
    u64 key = ALLF;
    if (tid < kept) {
      u32 e = keeplist[tid];
      key = (e & 0x8000u) ? ck[e & 0x7FFFu] : kr[e];
    }
    slotkey_of(ws, b)[tid] = key;
  }
}

// ---------------- K5: parallel outputs (grid 16 x 10, 256 thr) ----------------
__global__ __launch_bounds__(256) void k_out(Ptrs P, float* out) {
  int b = blockIdx.x, part = blockIdx.y;   // 10 slots per block
  int s0 = part * 10;
  int tid = threadIdx.x;
  const u64* skl = slotkey_of(P.ws, b);

  if (tid < 10) {
    int s = s0 + tid;
    u64 key = skl[s];
    float os = -1.0f, oc = -1.0f;
    float4 bx = make_float4(-1.0f, -1.0f, -1.0f, -1.0f);
    if (key != ALLF) {
      int gid = (int)(key & 0x7FFF);
      os = __uint_as_float(~(u32)(key >> 15));
      oc = (float)((u16*)(P.ws + CLSI_OFF))[(size_t)b * TOTAL_G + gid];
      bx = decode_box(P, b, gid);
    }
    out[b * 100 + s] = os;
    out[1600 + b * 100 + s] = oc;
    *(float4*)(out + 3200 + (size_t)(b * 100 + s) * 4) = bx;
  }

  // class-probability gather: 10 slots x 80 classes
  for (int t = tid; t < 800; t += 256) {
    int sl = t / 80, k = t - sl * 80;
    int s = s0 + sl;
    u64 key = skl[s];
    float val = -1.0f;
    if (key != ALLF) {
      int gid = (int)(key & 0x7FFF);
      int lev, idx, nl; levinfo(gid, lev, idx, nl);
      const float* cp;
      if      (lev == 0) cp = P.cls0;
      else if (lev == 1) cp = P.cls1;
      else if (lev == 2) cp = P.cls2;
      else if (lev == 3) cp = P.cls3;
      else               cp = P.cls4;
      val = sigd(cp[(size_t)(b * nl + idx) * 80 + k]);
    }
    out[9600 + (size_t)(b * 100 + s) * 80 + k] = val;
  }
}

extern "C" void kernel_launch(void* const* d_in, const int* in_sizes, int n_in,
                              void* d_out, int out_size, void* d_ws, size_t ws_size,
                              hipStream_t stream) {
  (void)in_sizes; (void)n_in; (void)out_size; (void)ws_size;
  Ptrs P;
  P.cls0 = (const float*)d_in[0];  P.reg0 = (const float*)d_in[1];
  P.ctr0 = (const float*)d_in[2];  P.pos0 = (const float*)d_in[3];
  P.cls1 = (const float*)d_in[4];  P.reg1 = (const float*)d_in[5];
  P.ctr1 = (const float*)d_in[6];  P.pos1 = (const float*)d_in[7];
  P.cls2 = (const float*)d_in[8];  P.reg2 = (const float*)d_in[9];
  P.ctr2 = (const float*)d_in[10]; P.pos2 = (const float*)d_in[11];
  P.cls3 = (const float*)d_in[12]; P.reg3 = (const float*)d_in[13];
  P.ctr3 = (const float*)d_in[14]; P.pos3 = (const float*)d_in[15];
  P.cls4 = (const float*)d_in[16]; P.reg4 = (const float*)d_in[17];
  P.ctr4 = (const float*)d_in[18]; P.pos4 = (const float*)d_in[19];
  P.ws = (char*)d_ws;

  k_score<<<dim3(267, 16), 256, 0, stream>>>(P);
  k_sel<<<dim3(16, 2), 1024, 0, stream>>>(P);
  k_comp<<<16, 1024, 0, stream>>>(P);
  k_mask<<<dim3(4, 16), 1024, 0, stream>>>(P);
  k_reduce<<<16, 256, 0, stream>>>(P);
  k_out<<<dim3(16, 10), 256, 0, stream>>>(P, (float*)d_out);
}

// Round 9
// 114.146 us; speedup vs baseline: 1.8105x; 1.1916x over previous
//
#include <hip/hip_runtime.h>
#include <math.h>

#define TOTAL_G 17064
#define BATCHN  16
#define ALLF    0xFFFFFFFFFFFFFFFFull
// valid <=> score > 0.01f <=> scorebits > 0x3C23D70A <=> (key>>15) < 0xC3DC28F5
#define INVALID_HI 0xC3DC28F5u

typedef unsigned long long u64;
typedef unsigned int u32;
typedef unsigned short u16;

// ---- ws layout (bytes), total 4,581,760 ----
#define KEYS0_OFF   0          // u64[16][12800]  1,638,400
#define KEYS1_OFF   1638400    // u64[16][3200]     409,600
#define KEYS234_OFF 2048000    // u64[16][1088]     139,264
#define CLSI_OFF    2187264    // u16[16][17064]    546,048
#define NC_OFF      2733312    // int[32]: [0..15]=Nc, [16..31]=n512
#define T01_OFF     2733568    // u64[2][16]            256
#define T512_OFF    2733824    // u64[16]               128
#define CK_OFF      2733952    // u64[16][3072]     393,216
#define K512_OFF    3127168    // u64[16][512]       65,536
#define KR_OFF      3192704    // u64[16][512]       65,536
#define MSK_OFF     3258240    // u64[16][512*8]    524,288
#define FB_OFF      3782528    // f4 [16][3072]     786,432  (fallback only)
#define SLOTK_OFF   4568960    // u64[16][100]       12,800

struct Ptrs {
  const float *cls0,*cls1,*cls2,*cls3,*cls4;
  const float *reg0,*reg1,*reg2,*reg3,*reg4;
  const float *ctr0,*ctr1,*ctr2,*ctr3,*ctr4;
  const float *pos0,*pos1,*pos2,*pos3,*pos4;
  char *ws;
};

__device__ __forceinline__ float sigd(float x) {
  return (float)(1.0 / (1.0 + exp(-(double)x)));
}
__device__ __forceinline__ float dexp(float x) {
  return (float)exp((double)x);
}
__device__ __forceinline__ void levinfo(int gid, int& lev, int& idx, int& nl) {
  if      (gid < 12800) { lev=0; idx=gid;        nl=12800; }
  else if (gid < 16000) { lev=1; idx=gid-12800;  nl=3200;  }
  else if (gid < 16800) { lev=2; idx=gid-16000;  nl=800;   }
  else if (gid < 17008) { lev=3; idx=gid-16800;  nl=208;   }
  else                  { lev=4; idx=gid-17008;  nl=56;    }
}

__device__ __forceinline__ u64* ckeys_of(char* ws, int b) {
  return (u64*)(ws + CK_OFF + (size_t)b * 24576);
}
__device__ __forceinline__ u64* key512_of(char* ws, int b) {
  return (u64*)(ws + K512_OFF + (size_t)b * 4096);
}
__device__ __forceinline__ u64* krank_of(char* ws, int b) {
  return (u64*)(ws + KR_OFF + (size_t)b * 4096);
}
__device__ __forceinline__ u64* msk_of(char* ws, int b) {
  return (u64*)(ws + MSK_OFF + (size_t)b * 32768);
}
__device__ __forceinline__ float4* fb_of(char* ws, int b) {
  return (float4*)(ws + FB_OFF + (size_t)b * 49152);
}
__device__ __forceinline__ u64* slotkey_of(char* ws, int b) {
  return (u64*)(ws + SLOTK_OFF + (size_t)b * 800);
}

// exact box decode (identical everywhere -> deterministic)
__device__ __forceinline__ float4 decode_box(const Ptrs& P, int b, int gid) {
  int lev, idx, nl; levinfo(gid, lev, idx, nl);
  const float *rp, *pp;
  if      (lev == 0) { rp = P.reg0; pp = P.pos0; }
  else if (lev == 1) { rp = P.reg1; pp = P.pos1; }
  else if (lev == 2) { rp = P.reg2; pp = P.pos2; }
  else if (lev == 3) { rp = P.reg3; pp = P.pos3; }
  else               { rp = P.reg4; pp = P.pos4; }
  float4 rv = *(const float4*)(rp + (size_t)(b * nl + idx) * 4);
  float2 pv = *(const float2*)(pp + (size_t)(b * nl + idx) * 2);
  float e0 = dexp(rv.x), e1 = dexp(rv.y), e2 = dexp(rv.z), e3 = dexp(rv.w);
  float x1 = truncf(pv.x - e0), y1 = truncf(pv.y - e1);
  float x2 = truncf(pv.x + e2), y2 = truncf(pv.y + e3);
  x1 = fmaxf(x1, 0.0f); y1 = fmaxf(y1, 0.0f);
  x2 = fminf(x2, 1023.0f); y2 = fminf(y2, 799.0f);
  return make_float4(x1, y1, x2, y2);
}

// ---------------- K1: LDS-staged, 4-threads-per-position score / argmax / key ----------------
__global__ __launch_bounds__(256) void k_score(Ptrs P) {
  __shared__ float4 sk4[64 * 20];   // 64 positions x 320 B = 20 KB
  int b = blockIdx.y;
  int tid = threadIdx.x;
  int p0 = blockIdx.x * 64;

  #pragma unroll
  for (int it = 0; it < 5; ++it) {
    int t4 = it * 256 + tid;
    int g = p0 + t4 / 20;
    if (g < TOTAL_G) {
      int sub = t4 - (t4 / 20) * 20;
      int lev, idx, nl; levinfo(g, lev, idx, nl);
      const float* clsb;
      if      (lev == 0) clsb = P.cls0;
      else if (lev == 1) clsb = P.cls1;
      else if (lev == 2) clsb = P.cls2;
      else if (lev == 3) clsb = P.cls3;
      else               clsb = P.cls4;
      sk4[t4] = ((const float4*)(clsb + (size_t)(b * nl + idx) * 80))[sub];
    }
  }
  __syncthreads();

  int lp = tid >> 2, q = tid & 3;
  int g = p0 + lp;
  if (g >= TOTAL_G) return;

  const float4* my4 = &sk4[lp * 20 + q * 5];
  float m = -INFINITY, m2 = -INFINITY; int mi = 0;
  #pragma unroll
  for (int k = 0; k < 5; ++k) {
    float4 v = my4[k];
    int base = q * 20 + 4 * k;
    if (v.x > m) { m2 = m; m = v.x; mi = base+0; } else if (v.x > m2) m2 = v.x;
    if (v.y > m) { m2 = m; m = v.y; mi = base+1; } else if (v.y > m2) m2 = v.y;
    if (v.z > m) { m2 = m; m = v.z; mi = base+2; } else if (v.z > m2) m2 = v.z;
    if (v.w > m) { m2 = m; m = v.w; mi = base+3; } else if (v.w > m2) m2 = v.w;
  }
  #pragma unroll
  for (int xw = 1; xw <= 2; xw <<= 1) {
    float om  = __shfl_xor(m,  xw);
    float om2 = __shfl_xor(m2, xw);
    int   omi = __shfl_xor(mi, xw);
    bool take = (om > m) || (om == m && omi < mi);
    float lm  = take ? m : om;
    float wm2 = take ? om2 : m2;
    if (take) { m = om; mi = omi; }
    m2 = fmaxf(lm, wm2);
  }

  float thr = fminf(m - 1e-3f, 9.0f);
  float pmax; int ci;
  if (m2 >= thr) {
    // rare exact path: per-element sigmoid argmax among candidates >= thr
    float pv = -1.0f; int pi = 0x7fffffff;
    #pragma unroll 1
    for (int k = 0; k < 5; ++k) {
      float4 v = my4[k];
      float xs[4] = {v.x, v.y, v.z, v.w};
      #pragma unroll
      for (int e = 0; e < 4; ++e) {
        if (xs[e] >= thr) {
          float p = sigd(xs[e]);
          if (p > pv) { pv = p; pi = q * 20 + 4 * k + e; }
        }
      }
    }
    #pragma unroll
    for (int xw = 1; xw <= 2; xw <<= 1) {
      float ov = __shfl_xor(pv, xw);
      int   oi = __shfl_xor(pi, xw);
      if (ov > pv || (ov == pv && oi < pi)) { pv = ov; pi = oi; }
    }
    pmax = pv; ci = pi;
  } else {
    pmax = sigd(m); ci = mi;
  }

  if (q == 0) {
    int lev, idx, nl; levinfo(g, lev, idx, nl);
    const float* ctrb;
    if      (lev == 0) ctrb = P.ctr0;
    else if (lev == 1) ctrb = P.ctr1;
    else if (lev == 2) ctrb = P.ctr2;
    else if (lev == 3) ctrb = P.ctr3;
    else               ctrb = P.ctr4;
    float tc = ctrb[(size_t)b * nl + idx];
    float csig = sigd(tc);
    float prod = pmax * csig;
    float s = (float)sqrt((double)prod);
    ((u16*)(P.ws + CLSI_OFF))[(size_t)b * TOTAL_G + g] = (u16)ci;
    unsigned hi = ~__float_as_uint(s);
    u64 key = ((u64)hi << 15) | (unsigned)g;
    if      (lev == 0) ((u64*)(P.ws + KEYS0_OFF))  [(size_t)b * 12800 + idx] = key;
    else if (lev == 1) ((u64*)(P.ws + KEYS1_OFF))  [(size_t)b * 3200  + idx] = key;
    else               ((u64*)(P.ws + KEYS234_OFF))[(size_t)b * 1088  + (g - 16000)] = key;
  }
}

// ---------------- adaptive radix select ----------------
struct SelSh {
  u32 hist[4][4096];   // 64 KB, 4 replicas
  u64 buf[64];
  u64 res, pfx;
  int t, mode, cnt;
};

__device__ __forceinline__ u64 loadkey(const Ptrs& P, int b, int u) {
  if (u < 12800) return ((const u64*)(P.ws + KEYS0_OFF))  [(size_t)b * 12800 + u];
  if (u < 16000) return ((const u64*)(P.ws + KEYS1_OFF))  [(size_t)b * 3200  + (u - 12800)];
  return               ((const u64*)(P.ws + KEYS234_OFF))[(size_t)b * 1088  + (u - 16000)];
}
__device__ __forceinline__ bool keep_pred(u64 k, int u, u64 T0, u64 T1) {
  bool valid = (u32)(k >> 15) < INVALID_HI;
  bool sel = (u < 12800) ? (k <= T0) : ((u < 16000) ? (k <= T1) : true);
  return valid && sel;
}

// exact t0-th smallest (1-indexed). keys distinct. key[46:45]==0b11 always.
// pred: 0 = plain array keys[0..n); 2 = all TOTAL_G keys, valid-only filter.
// Returns ALLF if fewer than t0 eligible keys exist.
__device__ u64 fast_select(const Ptrs& P, int b, const u64* keys, int n,
                           int pred, int t0, SelSh* S) {
  int tid = threadIdx.x, wid = tid >> 6, lane = tid & 63;
  int rep = wid & 3;
  u64 Pfx = 3; int t = t0;
  const int SS[4] = {33, 21, 9, 0};
  const int WW[4] = {12, 12, 12, 9};
  #pragma unroll 1
  for (int p = 0; p < 4; ++p) {
    int s = SS[p], wb = WW[p];
    u32 dmask = (1u << wb) - 1u;
    for (int i = tid; i < 4 * 4096; i += 1024) (&S->hist[0][0])[i] = 0;
    if (tid == 0) { S->mode = 0; S->cnt = 0; }
    __syncthreads();
    int N = pred ? TOTAL_G : n;
    for (int i = tid; i < N; i += 1024) {
      u64 k = pred ? loadkey(P, b, i) : keys[i];
      if (pred == 2 && !((u32)(k >> 15) < INVALID_HI)) continue;
      if ((k >> (s + wb)) == Pfx)
        atomicAdd(&S->hist[rep][(u32)(k >> s) & dmask], 1u);
    }
    __syncthreads();
    for (int i = tid; i < 4096; i += 1024) {
      u32 v = S->hist[0][i] + S->hist[1][i] + S->hist[2][i] + S->hist[3][i];
      S->hist[0][i] = v;
    }
    __syncthreads();
    if (wid == 0) {
      u32 ssum = 0;
      #pragma unroll 8
      for (int i = 0; i < 64; ++i) {
        int ii = (i + lane) & 63;
        ssum += S->hist[0][(lane << 6) + ii];
      }
      u32 inc = ssum;
      for (int o = 1; o < 64; o <<= 1) { u32 v = __shfl_up(inc, o); if (lane >= o) inc += v; }
      u64 ball = __ballot(inc >= (u32)t);
      if (!ball) {
        if (lane == 0) { S->mode = 9; S->res = ALLF; }   // fewer than t keys
      } else {
        int Wq = __ffsll(ball) - 1;
        u32 cumBefore = __shfl(inc - ssum, Wq);
        u32 v2 = S->hist[0][(Wq << 6) + lane];
        u32 inc2 = v2;
        for (int o = 1; o < 64; o <<= 1) { u32 x = __shfl_up(inc2, o); if (lane >= o) inc2 += x; }
        u64 ball2 = __ballot(cumBefore + inc2 >= (u32)t);
        int l2 = __ffsll(ball2) - 1;
        u32 cumB2 = __shfl(cumBefore + inc2 - v2, l2);
        u32 c = __shfl(v2, l2);
        if (lane == 0) {
          int d = (Wq << 6) + l2;
          u64 np = (Pfx << wb) | (u32)d;
          S->pfx = np; S->t = t - (int)cumB2;
          if (s == 0)       { S->mode = 9; S->res = np; }
          else if (c == 1)  { S->mode = 1; }
          else if (c <= 64) { S->mode = 2; }
        }
      }
    }
    __syncthreads();
    int mode = S->mode; u64 np = S->pfx; int tt = S->t;
    if (mode == 9) return S->res;
    if (mode == 1 || mode == 2) {
      int N2 = pred ? TOTAL_G : n;
      for (int i = tid; i < N2; i += 1024) {
        u64 k = pred ? loadkey(P, b, i) : keys[i];
        if (pred == 2 && !((u32)(k >> 15) < INVALID_HI)) continue;
        if ((k >> s) == np) {
          if (mode == 1) S->res = k;
          else { int pos = atomicAdd(&S->cnt, 1); S->buf[pos] = k; }
        }
      }
      __syncthreads();
      if (mode == 2 && wid == 0) {
        int c2 = S->cnt;
        u64 kl = (lane < c2) ? S->buf[lane] : ALLF;
        int r = 0;
        for (int j = 0; j < c2; ++j) r += (S->buf[j] < kl) ? 1 : 0;
        if (lane < c2 && r == tt - 1) S->res = kl;
      }
      __syncthreads();
      return S->res;
    }
    Pfx = np; t = tt;
    __syncthreads();
  }
  return S->pfx;
}

// ---------------- K2a: T0 / T1 / T512 in parallel (grid 16 x 3) ----------------
// T512 over valid keys == T512 over survivors: any global-valid-top-512 key has
// within-level rank < 512 < 1000 (invalid keys sort below all valid ones).
__global__ __launch_bounds__(1024) void k_sel(Ptrs P) {
  __shared__ SelSh S;
  int b = blockIdx.x, which = blockIdx.y;
  u64 T;
  if (which == 0)
    T = fast_select(P, b, (const u64*)(P.ws + KEYS0_OFF) + (size_t)b * 12800, 12800, 0, 1000, &S);
  else if (which == 1)
    T = fast_select(P, b, (const u64*)(P.ws + KEYS1_OFF) + (size_t)b * 3200, 3200, 0, 1000, &S);
  else
    T = fast_select(P, b, (const u64*)0, 0, 2, 512, &S);
  if (threadIdx.x == 0) {
    if      (which == 0) ((u64*)(P.ws + T01_OFF))[b] = T;
    else if (which == 1) ((u64*)(P.ws + T01_OFF))[16 + b] = T;
    else                 ((u64*)(P.ws + T512_OFF))[b] = T;
  }
}

// ---------------- K2b: 2-pass compaction: ck + key512 + Nc + n512 (grid 16) ----------------
__global__ __launch_bounds__(1024) void k_comp(Ptrs P) {
  __shared__ int wbase[272], wbase2[272];
  __shared__ int sNc, sN5;
  int b = blockIdx.x;
  int tid = threadIdx.x, wid = tid >> 6, lane = tid & 63;
  u64 T0 = ((u64*)(P.ws + T01_OFF))[b];
  u64 T1 = ((u64*)(P.ws + T01_OFF))[16 + b];
  u64 T512 = ((u64*)(P.ws + T512_OFF))[b];

  // pass 1: per-wave counts of keep / keep5
  for (int it = 0; it < 17; ++it) {
    int u = it * 1024 + tid;
    bool keep = false, keep5 = false;
    if (u < TOTAL_G) {
      u64 k = loadkey(P, b, u);
      keep = keep_pred(k, u, T0, T1);
      keep5 = keep && (k <= T512);
    }
    u64 bal  = __ballot(keep);
    u64 bal5 = __ballot(keep5);
    if (lane == 0) { wbase[it * 16 + wid] = __popcll(bal); wbase2[it * 16 + wid] = __popcll(bal5); }
  }
  __syncthreads();
  // parallel exclusive prefix: wave 0 -> wbase, wave 1 -> wbase2
  if (wid < 2) {
    int* arr = wid ? wbase2 : wbase;
    int carry = 0;
    for (int base = 0; base < 272; base += 64) {
      int idx = base + lane;
      int v = (idx < 272) ? arr[idx] : 0;
      int inc = v;
      for (int o = 1; o < 64; o <<= 1) { int x = __shfl_up(inc, o); if (lane >= o) inc += x; }
      if (idx < 272) arr[idx] = inc - v + carry;
      carry += __shfl(inc, 63);
    }
    if (lane == 0) {
      if (wid) { sN5 = carry; ((int*)(P.ws + NC_OFF))[16 + b] = carry; }
      else     { sNc = carry; ((int*)(P.ws + NC_OFF))[b] = carry; }
    }
  }
  __syncthreads();

  // pass 2: scatter ck (survivors) + key512 (global top-512 keys)
  u64* ck  = ckeys_of(P.ws, b);
  u64* k5  = key512_of(P.ws, b);
  for (int it = 0; it < 17; ++it) {
    int u = it * 1024 + tid;
    bool keep = false, keep5 = false; u64 k = 0;
    if (u < TOTAL_G) {
      k = loadkey(P, b, u);
      keep = keep_pred(k, u, T0, T1);
      keep5 = keep && (k <= T512);
    }
    u64 bal  = __ballot(keep);
    u64 bal5 = __ballot(keep5);
    u64 lm = (1ull << lane) - 1ull;
    int pos  = wbase [it * 16 + wid] + __popcll(bal  & lm);
    int pos5 = wbase2[it * 16 + wid] + __popcll(bal5 & lm);
    if (keep)  ck[pos] = k;
    if (keep5) k5[pos5] = k;
  }
}

// ---------------- K3: rank-all + decode + rank-space mask (grid 4 x 16) ----------------
__global__ __launch_bounds__(1024) void k_mask(Ptrs P) {
  __shared__ u64 skey[512];
  __shared__ float4 sbox[512];
  __shared__ u16 srank[512];
  __shared__ u16 parts[1024];
  __shared__ u64 smaskR[512 * 8];   // 32 KB, rank-space rows
  int qi = blockIdx.x, b = blockIdx.y;
  int tid = threadIdx.x;
  char* ws = P.ws;
  int n512 = ((int*)(ws + NC_OFF))[16 + b];
  const u64* k5 = key512_of(ws, b);

  if (tid < 512) {
    if (tid < n512) {
      u64 k = k5[tid];
      skey[tid] = k;
      sbox[tid] = decode_box(P, b, (int)(k & 0x7FFF));
    } else {
      skey[tid] = (ALLF - 511) + (u64)tid;
      sbox[tid] = make_float4(-1e30f, -1e30f, -1e30f, -1e30f);
    }
  }
  for (int i = tid; i < 512 * 8; i += 1024) smaskR[i] = 0ull;
  __syncthreads();

  {
    int t2 = tid & 511, half = tid >> 9;
    u64 mykey = skey[t2];
    int jb = half << 8, cnt = 0;
    #pragma unroll 4
    for (int j = jb; j < jb + 256; ++j) cnt += (skey[j] < mykey) ? 1 : 0;
    parts[tid] = (u16)cnt;
  }
  __syncthreads();
  if (tid < 512) srank[tid] = (u16)(parts[tid] + parts[tid + 512]);
  __syncthreads();

  int i = qi * 128 + (tid >> 3);
  int w = tid & 7;
  float4 bi = sbox[i];
  u64 ki = skey[i];
  int ri = srank[i];
  float ia = (bi.z - bi.x) * (bi.w - bi.y);
  #pragma unroll 8
  for (int bj = 0; bj < 64; ++bj) {
    int jj = (bj + w) & 63;
    int j = (w << 6) | jj;
    u64 kj = skey[j];
    if (ki < kj) {
      float4 bj4 = sbox[j];
      float ja  = (bj4.z - bj4.x) * (bj4.w - bj4.y);
      float ltx = fmaxf(bi.x, bj4.x), lty = fmaxf(bi.y, bj4.y);
      float rbx = fminf(bi.z, bj4.z), rby = fminf(bi.w, bj4.w);
      float wv = fmaxf(rbx - ltx, 0.0f), hv = fmaxf(rby - lty, 0.0f);
      float inter = wv * hv;
      float iou = inter / (ia + ja - inter);   // exact: integer-valued fp32
      if (iou > 0.6f) {
        int rj = srank[j];
        atomicOr(&smaskR[ri * 8 + (rj >> 6)], 1ull << (rj & 63));
      }
    }
  }
  __syncthreads();

  {
    int il = tid >> 3, ww = tid & 7;
    int ig = qi * 128 + il;
    if (ig < n512) {
      int r = srank[ig];
      msk_of(ws, b)[r * 8 + ww] = smaskR[r * 8 + ww];
      if (ww == 0) krank_of(ws, b)[r] = skey[ig];
    }
  }
}

// ---------------- K4: greedy ffs walk + fallback + slotkey (grid 16, 256 thr) ----------------
__global__ __launch_bounds__(256) void k_reduce(Ptrs P) {
  __shared__ u64 smask[4096];       // 32 KB
  __shared__ u32 keeplist[100];     // <512: rank; 0x8000|c: compact index
  __shared__ int keptS;
  __shared__ u64 liveC[48];
  __shared__ u64 pk[256];
  __shared__ int pc[256];
  __shared__ float4 fkb[100];
  __shared__ u64 bk; __shared__ int bc2;

  int b = blockIdx.x;
  int tid = threadIdx.x;
  char* ws = P.ws;
  int Nc   = ((int*)(ws + NC_OFF))[b];
  int n512 = ((int*)(ws + NC_OFF))[16 + b];
  const u64* ck = ckeys_of(ws, b);
  const u64* kr = krank_of(ws, b);

  const u64* gmask = msk_of(ws, b);
  for (int t = tid; t < 4096; t += 256) smask[t] = gmask[t];
  __syncthreads();

  if (tid < 64) {
    int lane = tid;
    u64 lw = 0;
    if (lane < 8) {
      int lo = lane << 6;
      int c = n512 - lo; if (c < 0) c = 0; if (c > 64) c = 64;
      lw = (c >= 64) ? ALLF : ((c > 0) ? ((1ull << c) - 1ull) : 0ull);
    }
    int kept = 0;
    while (kept < 100) {
      bool nz = (lane < 8) && (lw != 0ull);
      u64 bal = __ballot(nz);
      if (!bal) break;
      int W = __ffsll(bal) - 1;
      u64 wv = __shfl(lw, W);
      int bit = __ffsll(wv) - 1;
      int i = (W << 6) + bit;
      if (lane == 0) keeplist[kept] = (u32)i;
      kept++;
      if (lane == W) lw &= ~(1ull << bit);
      if (kept == 100) break;
      if (lane < 8) lw &= ~smask[i * 8 + lane];
    }
    if (lane == 0) keptS = kept;
  }
  __syncthreads();
  int kept = keptS;

  // fallback: keeps beyond the global top-512 (rare; exact)
  if (kept < 100 && Nc > 512) {
    u64 T512 = ((u64*)(ws + T512_OFF))[b];
    float4* fb = fb_of(ws, b);
    if (tid < 48) {
      int lo = tid << 6;
      u64 m = 0;
      for (int e = 0; e < 64; ++e) {
        int c = lo + e;
        if (c < Nc && ck[c] > T512) m |= (1ull << e);
      }
      liveC[tid] = m;
    }
    for (int c = tid; c < Nc; c += 256)
      if (ck[c] > T512) fb[c] = decode_box(P, b, (int)(ck[c] & 0x7FFF));
    if (tid < kept) fkb[tid] = decode_box(P, b, (int)(kr[keeplist[tid]] & 0x7FFF));
    __syncthreads();

    for (int k2 = 0; k2 < kept; ++k2) {
      float4 bi = fkb[k2];
      float ia = (bi.z - bi.x) * (bi.w - bi.y);
      for (int j = tid; j < Nc; j += 256) {
        if (!((liveC[j >> 6] >> (j & 63)) & 1ull)) continue;
        float4 bj4 = fb[j];
        float ja  = (bj4.z - bj4.x) * (bj4.w - bj4.y);
        float ltx = fmaxf(bi.x, bj4.x), lty = fmaxf(bi.y, bj4.y);
        float rbx = fminf(bi.z, bj4.z), rby = fminf(bi.w, bj4.w);
        float wv = fmaxf(rbx - ltx, 0.0f), hv = fmaxf(rby - lty, 0.0f);
        float inter = wv * hv;
        float iou = inter / (ia + ja - inter);
        if (iou > 0.6f) atomicAnd(&liveC[j >> 6], ~(1ull << (j & 63)));
      }
    }
    __syncthreads();

    while (kept < 100) {
      u64 mymin = ALLF; int myc = -1;
      for (int c = tid; c < Nc; c += 256) {
        if (!((liveC[c >> 6] >> (c & 63)) & 1ull)) continue;
        u64 k = ck[c];
        if (k < mymin) { mymin = k; myc = c; }
      }
      pk[tid] = mymin; pc[tid] = myc;
      __syncthreads();
      if (tid < 64) {
        u64 m = pk[tid]; int c0 = pc[tid];
        #pragma unroll
        for (int o = 64; o < 256; o += 64)
          if (pk[tid + o] < m) { m = pk[tid + o]; c0 = pc[tid + o]; }
        for (int o = 32; o > 0; o >>= 1) {
          u64 om = __shfl_down(m, o); int oc = __shfl_down(c0, o);
          if (om < m) { m = om; c0 = oc; }
        }
        if (tid == 0) { bk = m; bc2 = c0; }
      }
      __syncthreads();
      if (bk == ALLF) break;
      int cs = bc2;
      if (tid == 0) {
        keeplist[kept] = 0x8000u | (u32)cs;
        atomicAnd(&liveC[cs >> 6], ~(1ull << (cs & 63)));
      }
      __syncthreads();
      kept++;
      if (kept == 100) break;
      float4 bi = fb[cs];
      float ia = (bi.z - bi.x) * (bi.w - bi.y);
      for (int j = tid; j < Nc; j += 256) {
        if (!((liveC[j >> 6] >> (j & 63)) & 1ull)) continue;
        float4 bj4 = fb[j];
        float ja  = (bj4.z - bj4.x) * (bj4.w - bj4.y);
        float ltx = fmaxf(bi.x, bj4.x), lty = fmaxf(bi.y, bj4.y);
        float rbx = fminf(bi.z, bj4.z), rby = fminf(bi.w, bj4.w);
        float wv = fmaxf(rbx - ltx, 0.0f), hv = fmaxf(rby - lty, 0.0f);
        float inter = wv * hv;
        float iou = inter / (ia + ja - inter);
        if (iou > 0.6f) atomicAnd(&liveC[j >> 6], ~(1ull << (j & 63)));
      }
      __syncthreads();
    }
  }

  // resolve slot keys (ALLF = empty slot)
  if (tid < 100) {
    u64 key = ALLF;
    if (tid < kept) {
      u32 e = keeplist[tid];
      key = (e & 0x8000u) ? ck[e & 0x7FFFu] : kr[e];
    }
    slotkey_of(ws, b)[tid] = key;
  }
}

// ---------------- K5: parallel outputs (grid 16 x 10, 256 thr) ----------------
__global__ __launch_bounds__(256) void k_out(Ptrs P, float* out) {
  int b = blockIdx.x, part = blockIdx.y;   // 10 slots per block
  int s0 = part * 10;
  int tid = threadIdx.x;
  const u64* skl = slotkey_of(P.ws, b);

  if (tid < 10) {
    int s = s0 + tid;
    u64 key = skl[s];
    float os = -1.0f, oc = -1.0f;
    float4 bx = make_float4(-1.0f, -1.0f, -1.0f, -1.0f);
    if (key != ALLF) {
      int gid = (int)(key & 0x7FFF);
      os = __uint_as_float(~(u32)(key >> 15));
      oc = (float)((u16*)(P.ws + CLSI_OFF))[(size_t)b * TOTAL_G + gid];
      bx = decode_box(P, b, gid);
    }
    out[b * 100 + s] = os;
    out[1600 + b * 100 + s] = oc;
    *(float4*)(out + 3200 + (size_t)(b * 100 + s) * 4) = bx;
  }

  for (int t = tid; t < 800; t += 256) {
    int sl = t / 80, k = t - sl * 80;
    int s = s0 + sl;
    u64 key = skl[s];
    float val = -1.0f;
    if (key != ALLF) {
      int gid = (int)(key & 0x7FFF);
      int lev, idx, nl; levinfo(gid, lev, idx, nl);
      const float* cp;
      if      (lev == 0) cp = P.cls0;
      else if (lev == 1) cp = P.cls1;
      else if (lev == 2) cp = P.cls2;
      else if (lev == 3) cp = P.cls3;
      else               cp = P.cls4;
      val = sigd(cp[(size_t)(b * nl + idx) * 80 + k]);
    }
    out[9600 + (size_t)(b * 100 + s) * 80 + k] = val;
  }
}

extern "C" void kernel_launch(void* const* d_in, const int* in_sizes, int n_in,
                              void* d_out, int out_size, void* d_ws, size_t ws_size,
                              hipStream_t stream) {
  (void)in_sizes; (void)n_in; (void)out_size; (void)ws_size;
  Ptrs P;
  P.cls0 = (const float*)d_in[0];  P.reg0 = (const float*)d_in[1];
  P.ctr0 = (const float*)d_in[2];  P.pos0 = (const float*)d_in[3];
  P.cls1 = (const float*)d_in[4];  P.reg1 = (const float*)d_in[5];
  P.ctr1 = (const float*)d_in[6];  P.pos1 = (const float*)d_in[7];
  P.cls2 = (const float*)d_in[8];  P.reg2 = (const float*)d_in[9];
  P.ctr2 = (const float*)d_in[10]; P.pos2 = (const float*)d_in[11];
  P.cls3 = (const float*)d_in[12]; P.reg3 = (const float*)d_in[13];
  P.ctr3 = (const float*)d_in[14]; P.pos3 = (const float*)d_in[15];
  P.cls4 = (const float*)d_in[16]; P.reg4 = (const float*)d_in[17];
  P.ctr4 = (const float*)d_in[18]; P.pos4 = (const float*)d_in[19];
  P.ws = (char*)d_ws;

  k_score<<<dim3(267, 16), 256, 0, stream>>>(P);
  k_sel<<<dim3(16, 3), 1024, 0, stream>>>(P);
  k_comp<<<16, 1024, 0, stream>>>(P);
  k_mask<<<dim3(4, 16), 1024, 0, stream>>>(P);
  k_reduce<<<16, 256, 0, stream>>>(P);
  k_out<<<dim3(16, 10), 256, 0, stream>>>(P, (float*)d_out);
}

// Round 10
// 111.589 us; speedup vs baseline: 1.8519x; 1.0229x over previous
//
#include <hip/hip_runtime.h>
#include <math.h>

#define TOTAL_G 17064
#define BATCHN  16
#define ALLF    0xFFFFFFFFFFFFFFFFull
// valid <=> score > 0.01f <=> scorebits > 0x3C23D70A <=> (key>>15) < 0xC3DC28F5
#define INVALID_HI 0xC3DC28F5u

typedef unsigned long long u64;
typedef unsigned int u32;
typedef unsigned short u16;

// ---- ws layout (bytes), total 3,336,576 ----
#define KEYS0_OFF   0          // u64[16][12800]  1,638,400
#define KEYS1_OFF   1638400    // u64[16][3200]     409,600
#define KEYS234_OFF 2048000    // u64[16][1088]     139,264
#define CLSI_OFF    2187264    // u16[16][17064]    546,048
#define NC_OFF      2733312    // int[32]: [16..31]=n512
#define T01_OFF     2733568    // u64[2][16]            256
#define T512_OFF    2733824    // u64[16]               128
#define KR_OFF      2733952    // u64[16][512]       65,536
#define MSK_OFF     2799488    // u64[16][512*8]    524,288
#define SLOTK_OFF   3323776    // u64[16][100]       12,800

struct Ptrs {
  const float *cls0,*cls1,*cls2,*cls3,*cls4;
  const float *reg0,*reg1,*reg2,*reg3,*reg4;
  const float *ctr0,*ctr1,*ctr2,*ctr3,*ctr4;
  const float *pos0,*pos1,*pos2,*pos3,*pos4;
  char *ws;
};

__device__ __forceinline__ float sigd(float x) {
  return (float)(1.0 / (1.0 + exp(-(double)x)));
}
__device__ __forceinline__ float dexp(float x) {
  return (float)exp((double)x);
}
__device__ __forceinline__ void levinfo(int gid, int& lev, int& idx, int& nl) {
  if      (gid < 12800) { lev=0; idx=gid;        nl=12800; }
  else if (gid < 16000) { lev=1; idx=gid-12800;  nl=3200;  }
  else if (gid < 16800) { lev=2; idx=gid-16000;  nl=800;   }
  else if (gid < 17008) { lev=3; idx=gid-16800;  nl=208;   }
  else                  { lev=4; idx=gid-17008;  nl=56;    }
}

__device__ __forceinline__ u64* krank_of(char* ws, int b) {
  return (u64*)(ws + KR_OFF + (size_t)b * 4096);
}
__device__ __forceinline__ u64* msk_of(char* ws, int b) {
  return (u64*)(ws + MSK_OFF + (size_t)b * 32768);
}
__device__ __forceinline__ u64* slotkey_of(char* ws, int b) {
  return (u64*)(ws + SLOTK_OFF + (size_t)b * 800);
}

// exact box decode (identical everywhere -> deterministic)
__device__ __forceinline__ float4 decode_box(const Ptrs& P, int b, int gid) {
  int lev, idx, nl; levinfo(gid, lev, idx, nl);
  const float *rp, *pp;
  if      (lev == 0) { rp = P.reg0; pp = P.pos0; }
  else if (lev == 1) { rp = P.reg1; pp = P.pos1; }
  else if (lev == 2) { rp = P.reg2; pp = P.pos2; }
  else if (lev == 3) { rp = P.reg3; pp = P.pos3; }
  else               { rp = P.reg4; pp = P.pos4; }
  float4 rv = *(const float4*)(rp + (size_t)(b * nl + idx) * 4);
  float2 pv = *(const float2*)(pp + (size_t)(b * nl + idx) * 2);
  float e0 = dexp(rv.x), e1 = dexp(rv.y), e2 = dexp(rv.z), e3 = dexp(rv.w);
  float x1 = truncf(pv.x - e0), y1 = truncf(pv.y - e1);
  float x2 = truncf(pv.x + e2), y2 = truncf(pv.y + e3);
  x1 = fmaxf(x1, 0.0f); y1 = fmaxf(y1, 0.0f);
  x2 = fminf(x2, 1023.0f); y2 = fminf(y2, 799.0f);
  return make_float4(x1, y1, x2, y2);
}

// ---------------- K1: LDS-staged, 4-threads-per-position score / argmax / key ----------------
__global__ __launch_bounds__(256) void k_score(Ptrs P) {
  __shared__ float4 sk4[64 * 20];   // 64 positions x 320 B = 20 KB
  int b = blockIdx.y;
  int tid = threadIdx.x;
  int p0 = blockIdx.x * 64;

  #pragma unroll
  for (int it = 0; it < 5; ++it) {
    int t4 = it * 256 + tid;
    int g = p0 + t4 / 20;
    if (g < TOTAL_G) {
      int sub = t4 - (t4 / 20) * 20;
      int lev, idx, nl; levinfo(g, lev, idx, nl);
      const float* clsb;
      if      (lev == 0) clsb = P.cls0;
      else if (lev == 1) clsb = P.cls1;
      else if (lev == 2) clsb = P.cls2;
      else if (lev == 3) clsb = P.cls3;
      else               clsb = P.cls4;
      sk4[t4] = ((const float4*)(clsb + (size_t)(b * nl + idx) * 80))[sub];
    }
  }
  __syncthreads();

  int lp = tid >> 2, q = tid & 3;
  int g = p0 + lp;
  if (g >= TOTAL_G) return;

  const float4* my4 = &sk4[lp * 20 + q * 5];
  float m = -INFINITY, m2 = -INFINITY; int mi = 0;
  #pragma unroll
  for (int k = 0; k < 5; ++k) {
    float4 v = my4[k];
    int base = q * 20 + 4 * k;
    if (v.x > m) { m2 = m; m = v.x; mi = base+0; } else if (v.x > m2) m2 = v.x;
    if (v.y > m) { m2 = m; m = v.y; mi = base+1; } else if (v.y > m2) m2 = v.y;
    if (v.z > m) { m2 = m; m = v.z; mi = base+2; } else if (v.z > m2) m2 = v.z;
    if (v.w > m) { m2 = m; m = v.w; mi = base+3; } else if (v.w > m2) m2 = v.w;
  }
  #pragma unroll
  for (int xw = 1; xw <= 2; xw <<= 1) {
    float om  = __shfl_xor(m,  xw);
    float om2 = __shfl_xor(m2, xw);
    int   omi = __shfl_xor(mi, xw);
    bool take = (om > m) || (om == m && omi < mi);
    float lm  = take ? m : om;
    float wm2 = take ? om2 : m2;
    if (take) { m = om; mi = omi; }
    m2 = fmaxf(lm, wm2);
  }

  float thr = fminf(m - 1e-3f, 9.0f);
  float pmax; int ci;
  if (m2 >= thr) {
    // rare exact path: per-element sigmoid argmax among candidates >= thr
    float pv = -1.0f; int pi = 0x7fffffff;
    #pragma unroll 1
    for (int k = 0; k < 5; ++k) {
      float4 v = my4[k];
      float xs[4] = {v.x, v.y, v.z, v.w};
      #pragma unroll
      for (int e = 0; e < 4; ++e) {
        if (xs[e] >= thr) {
          float p = sigd(xs[e]);
          if (p > pv) { pv = p; pi = q * 20 + 4 * k + e; }
        }
      }
    }
    #pragma unroll
    for (int xw = 1; xw <= 2; xw <<= 1) {
      float ov = __shfl_xor(pv, xw);
      int   oi = __shfl_xor(pi, xw);
      if (ov > pv || (ov == pv && oi < pi)) { pv = ov; pi = oi; }
    }
    pmax = pv; ci = pi;
  } else {
    pmax = sigd(m); ci = mi;
  }

  if (q == 0) {
    int lev, idx, nl; levinfo(g, lev, idx, nl);
    const float* ctrb;
    if      (lev == 0) ctrb = P.ctr0;
    else if (lev == 1) ctrb = P.ctr1;
    else if (lev == 2) ctrb = P.ctr2;
    else if (lev == 3) ctrb = P.ctr3;
    else               ctrb = P.ctr4;
    float tc = ctrb[(size_t)b * nl + idx];
    float csig = sigd(tc);
    float prod = pmax * csig;
    float s = (float)sqrt((double)prod);
    ((u16*)(P.ws + CLSI_OFF))[(size_t)b * TOTAL_G + g] = (u16)ci;
    unsigned hi = ~__float_as_uint(s);
    u64 key = ((u64)hi << 15) | (unsigned)g;
    if      (lev == 0) ((u64*)(P.ws + KEYS0_OFF))  [(size_t)b * 12800 + idx] = key;
    else if (lev == 1) ((u64*)(P.ws + KEYS1_OFF))  [(size_t)b * 3200  + idx] = key;
    else               ((u64*)(P.ws + KEYS234_OFF))[(size_t)b * 1088  + (g - 16000)] = key;
  }
}

// ---------------- adaptive radix select ----------------
struct SelSh {
  u32 hist[4][4096];   // 64 KB, 4 replicas
  u64 buf[64];
  u64 res, pfx;
  int t, mode, cnt;
};

__device__ __forceinline__ u64 loadkey(const Ptrs& P, int b, int u) {
  if (u < 12800) return ((const u64*)(P.ws + KEYS0_OFF))  [(size_t)b * 12800 + u];
  if (u < 16000) return ((const u64*)(P.ws + KEYS1_OFF))  [(size_t)b * 3200  + (u - 12800)];
  return               ((const u64*)(P.ws + KEYS234_OFF))[(size_t)b * 1088  + (u - 16000)];
}
__device__ __forceinline__ bool keep_pred(u64 k, int u, u64 T0, u64 T1) {
  bool valid = (u32)(k >> 15) < INVALID_HI;
  bool sel = (u < 12800) ? (k <= T0) : ((u < 16000) ? (k <= T1) : true);
  return valid && sel;
}

// exact t0-th smallest (1-indexed). keys distinct. key[46:45]==0b11 always.
// pred: 0 = plain array keys[0..n); 2 = all TOTAL_G keys, valid-only filter.
// Returns ALLF if fewer than t0 eligible keys exist.
__device__ u64 fast_select(const Ptrs& P, int b, const u64* keys, int n,
                           int pred, int t0, SelSh* S) {
  int tid = threadIdx.x, wid = tid >> 6, lane = tid & 63;
  int rep = wid & 3;
  u64 Pfx = 3; int t = t0;
  const int SS[4] = {33, 21, 9, 0};
  const int WW[4] = {12, 12, 12, 9};
  #pragma unroll 1
  for (int p = 0; p < 4; ++p) {
    int s = SS[p], wb = WW[p];
    u32 dmask = (1u << wb) - 1u;
    for (int i = tid; i < 4 * 4096; i += 1024) (&S->hist[0][0])[i] = 0;
    if (tid == 0) { S->mode = 0; S->cnt = 0; }
    __syncthreads();
    int N = pred ? TOTAL_G : n;
    for (int i = tid; i < N; i += 1024) {
      u64 k = pred ? loadkey(P, b, i) : keys[i];
      if (pred == 2 && !((u32)(k >> 15) < INVALID_HI)) continue;
      if ((k >> (s + wb)) == Pfx)
        atomicAdd(&S->hist[rep][(u32)(k >> s) & dmask], 1u);
    }
    __syncthreads();
    for (int i = tid; i < 4096; i += 1024) {
      u32 v = S->hist[0][i] + S->hist[1][i] + S->hist[2][i] + S->hist[3][i];
      S->hist[0][i] = v;
    }
    __syncthreads();
    if (wid == 0) {
      u32 ssum = 0;
      #pragma unroll 8
      for (int i = 0; i < 64; ++i) {
        int ii = (i + lane) & 63;
        ssum += S->hist[0][(lane << 6) + ii];
      }
      u32 inc = ssum;
      for (int o = 1; o < 64; o <<= 1) { u32 v = __shfl_up(inc, o); if (lane >= o) inc += v; }
      u64 ball = __ballot(inc >= (u32)t);
      if (!ball) {
        if (lane == 0) { S->mode = 9; S->res = ALLF; }   // fewer than t keys
      } else {
        int Wq = __ffsll(ball) - 1;
        u32 cumBefore = __shfl(inc - ssum, Wq);
        u32 v2 = S->hist[0][(Wq << 6) + lane];
        u32 inc2 = v2;
        for (int o = 1; o < 64; o <<= 1) { u32 x = __shfl_up(inc2, o); if (lane >= o) inc2 += x; }
        u64 ball2 = __ballot(cumBefore + inc2 >= (u32)t);
        int l2 = __ffsll(ball2) - 1;
        u32 cumB2 = __shfl(cumBefore + inc2 - v2, l2);
        u32 c = __shfl(v2, l2);
        if (lane == 0) {
          int d = (Wq << 6) + l2;
          u64 np = (Pfx << wb) | (u32)d;
          S->pfx = np; S->t = t - (int)cumB2;
          if (s == 0)       { S->mode = 9; S->res = np; }
          else if (c == 1)  { S->mode = 1; }
          else if (c <= 64) { S->mode = 2; }
        }
      }
    }
    __syncthreads();
    int mode = S->mode; u64 np = S->pfx; int tt = S->t;
    if (mode == 9) return S->res;
    if (mode == 1 || mode == 2) {
      int N2 = pred ? TOTAL_G : n;
      for (int i = tid; i < N2; i += 1024) {
        u64 k = pred ? loadkey(P, b, i) : keys[i];
        if (pred == 2 && !((u32)(k >> 15) < INVALID_HI)) continue;
        if ((k >> s) == np) {
          if (mode == 1) S->res = k;
          else { int pos = atomicAdd(&S->cnt, 1); S->buf[pos] = k; }
        }
      }
      __syncthreads();
      if (mode == 2 && wid == 0) {
        int c2 = S->cnt;
        u64 kl = (lane < c2) ? S->buf[lane] : ALLF;
        int r = 0;
        for (int j = 0; j < c2; ++j) r += (S->buf[j] < kl) ? 1 : 0;
        if (lane < c2 && r == tt - 1) S->res = kl;
      }
      __syncthreads();
      return S->res;
    }
    Pfx = np; t = tt;
    __syncthreads();
  }
  return S->pfx;
}

// ---------------- K2: T0 / T1 / T512 in parallel (grid 16 x 3) ----------------
// T512 over valid keys == T512 over survivors (valid-top-512 key has
// within-level valid-rank < 512 < 1000; invalid keys sort after all valid).
__global__ __launch_bounds__(1024) void k_sel(Ptrs P) {
  __shared__ SelSh S;
  int b = blockIdx.x, which = blockIdx.y;
  u64 T;
  if (which == 0)
    T = fast_select(P, b, (const u64*)(P.ws + KEYS0_OFF) + (size_t)b * 12800, 12800, 0, 1000, &S);
  else if (which == 1)
    T = fast_select(P, b, (const u64*)(P.ws + KEYS1_OFF) + (size_t)b * 3200, 3200, 0, 1000, &S);
  else
    T = fast_select(P, b, (const u64*)0, 0, 2, 512, &S);
  if (threadIdx.x == 0) {
    if      (which == 0) ((u64*)(P.ws + T01_OFF))[b] = T;
    else if (which == 1) ((u64*)(P.ws + T01_OFF))[16 + b] = T;
    else                 ((u64*)(P.ws + T512_OFF))[b] = T;
  }
}

// ---------------- K3: in-LDS compact + rank + decode + rank-space mask (grid 4 x 16) ----------------
// keep5 = valid && key <= T512  (per-level top-1000 filter provably redundant here:
// a valid key <= T512 has within-level valid-rank < 512 < 1000).
__global__ __launch_bounds__(1024) void k_mask(Ptrs P) {
  __shared__ u64 skey[512];
  __shared__ float4 sbox[512];
  __shared__ u16 srank[512];
  __shared__ u16 parts[1024];
  __shared__ u64 smaskR[512 * 8];   // 32 KB, rank-space rows
  __shared__ int wbase[272];
  __shared__ int sN5;
  int qi = blockIdx.x, b = blockIdx.y;
  int tid = threadIdx.x, wid = tid >> 6, lane = tid & 63;
  char* ws = P.ws;
  u64 T512 = ((u64*)(ws + T512_OFF))[b];

  // pass A: per-wave keep5 counts (deterministic order -> identical across 4 blocks)
  for (int it = 0; it < 17; ++it) {
    int u = it * 1024 + tid;
    bool keep5 = false;
    if (u < TOTAL_G) {
      u64 k = loadkey(P, b, u);
      keep5 = ((u32)(k >> 15) < INVALID_HI) && (k <= T512);
    }
    u64 bal = __ballot(keep5);
    if (lane == 0) wbase[it * 16 + wid] = __popcll(bal);
  }
  for (int i = tid; i < 512 * 8; i += 1024) smaskR[i] = 0ull;
  __syncthreads();
  if (wid == 0) {
    int carry = 0;
    for (int base = 0; base < 272; base += 64) {
      int idx = base + lane;
      int v = (idx < 272) ? wbase[idx] : 0;
      int inc = v;
      for (int o = 1; o < 64; o <<= 1) { int x = __shfl_up(inc, o); if (lane >= o) inc += x; }
      if (idx < 272) wbase[idx] = inc - v + carry;
      carry += __shfl(inc, 63);
    }
    if (lane == 0) sN5 = carry;
  }
  __syncthreads();
  int n512 = sN5;                       // <= 512 by construction
  if (qi == 0 && tid == 0) ((int*)(ws + NC_OFF))[16 + b] = n512;

  // pass B: ordered scatter into LDS
  for (int it = 0; it < 17; ++it) {
    int u = it * 1024 + tid;
    bool keep5 = false; u64 k = 0;
    if (u < TOTAL_G) {
      k = loadkey(P, b, u);
      keep5 = ((u32)(k >> 15) < INVALID_HI) && (k <= T512);
    }
    u64 bal = __ballot(keep5);
    int pos = wbase[it * 16 + wid] + __popcll(bal & ((1ull << lane) - 1ull));
    if (keep5) skey[pos] = k;
  }
  __syncthreads();
  if (tid < 512) {
    if (tid < n512) {
      sbox[tid] = decode_box(P, b, (int)(skey[tid] & 0x7FFF));
    } else {
      skey[tid] = (ALLF - 511) + (u64)tid;   // distinct, > any real key
      sbox[tid] = make_float4(-1e30f, -1e30f, -1e30f, -1e30f);
    }
  }
  __syncthreads();

  // rank all 512 by key
  {
    int t2 = tid & 511, half = tid >> 9;
    u64 mykey = skey[t2];
    int jb = half << 8, cnt = 0;
    #pragma unroll 4
    for (int j = jb; j < jb + 256; ++j) cnt += (skey[j] < mykey) ? 1 : 0;
    parts[tid] = (u16)cnt;
  }
  __syncthreads();
  if (tid < 512) srank[tid] = (u16)(parts[tid] + parts[tid + 512]);
  __syncthreads();

  // suppression bits in rank space (rotated j-scan, conflict-free)
  int i = qi * 128 + (tid >> 3);
  int w = tid & 7;
  float4 bi = sbox[i];
  u64 ki = skey[i];
  int ri = srank[i];
  float ia = (bi.z - bi.x) * (bi.w - bi.y);
  #pragma unroll 8
  for (int bj = 0; bj < 64; ++bj) {
    int jj = (bj + w) & 63;
    int j = (w << 6) | jj;
    u64 kj = skey[j];
    if (ki < kj) {
      float4 bj4 = sbox[j];
      float ja  = (bj4.z - bj4.x) * (bj4.w - bj4.y);
      float ltx = fmaxf(bi.x, bj4.x), lty = fmaxf(bi.y, bj4.y);
      float rbx = fminf(bi.z, bj4.z), rby = fminf(bi.w, bj4.w);
      float wv = fmaxf(rbx - ltx, 0.0f), hv = fmaxf(rby - lty, 0.0f);
      float inter = wv * hv;
      float iou = inter / (ia + ja - inter);   // exact: integer-valued fp32
      if (iou > 0.6f) {
        int rj = srank[j];
        atomicOr(&smaskR[ri * 8 + (rj >> 6)], 1ull << (rj & 63));
      }
    }
  }
  __syncthreads();

  {
    int il = tid >> 3, ww = tid & 7;
    int ig = qi * 128 + il;
    if (ig < n512) {
      int r = srank[ig];
      msk_of(ws, b)[r * 8 + ww] = smaskR[r * 8 + ww];
      if (ww == 0) krank_of(ws, b)[r] = skey[ig];
    }
  }
}

// ---------------- K4: greedy ffs walk + fallback + slotkey (grid 16, 256 thr) ----------------
__global__ __launch_bounds__(256) void k_reduce(Ptrs P) {
  __shared__ u64 smask[4096];       // 32 KB
  __shared__ u32 keeplist[100];     // ranks (walk phase only)
  __shared__ int keptS;
  __shared__ u64 liveC[267];        // fallback: live bits over gid space
  __shared__ u64 pk[256];
  __shared__ int pc[256];
  __shared__ float4 fkb[100];
  __shared__ u64 bk; __shared__ int bc2;

  int b = blockIdx.x;
  int tid = threadIdx.x;
  char* ws = P.ws;
  int n512 = ((int*)(ws + NC_OFF))[16 + b];
  const u64* kr = krank_of(ws, b);

  const u64* gmask = msk_of(ws, b);
  for (int t = tid; t < 4096; t += 256) smask[t] = gmask[t];
  __syncthreads();

  // single-wave barrier-free greedy walk over ranks [0, n512)
  if (tid < 64) {
    int lane = tid;
    u64 lw = 0;
    if (lane < 8) {
      int lo = lane << 6;
      int c = n512 - lo; if (c < 0) c = 0; if (c > 64) c = 64;
      lw = (c >= 64) ? ALLF : ((c > 0) ? ((1ull << c) - 1ull) : 0ull);
    }
    int kept = 0;
    while (kept < 100) {
      bool nz = (lane < 8) && (lw != 0ull);
      u64 bal = __ballot(nz);
      if (!bal) break;
      int W = __ffsll(bal) - 1;
      u64 wv = __shfl(lw, W);
      int bit = __ffsll(wv) - 1;
      int i = (W << 6) + bit;
      if (lane == 0) keeplist[kept] = (u32)i;
      kept++;
      if (lane == W) lw &= ~(1ull << bit);
      if (kept == 100) break;
      if (lane < 8) lw &= ~smask[i * 8 + lane];
    }
    if (lane == 0) keptS = kept;
  }
  __syncthreads();
  int kept = keptS;
  int keptW = kept;

  // fallback: keeps beyond the global top-512 (possible only if n512==512; rare; exact)
  if (kept < 100 && n512 == 512) {
    u64 T0   = ((u64*)(ws + T01_OFF))[b];
    u64 T1   = ((u64*)(ws + T01_OFF))[16 + b];
    u64 T512 = ((u64*)(ws + T512_OFF))[b];
    for (int w = tid; w < 267; w += 256) {
      int lo = w << 6;
      u64 m = 0;
      for (int e = 0; e < 64; ++e) {
        int u = lo + e;
        if (u < TOTAL_G) {
          u64 k = loadkey(P, b, u);
          if (keep_pred(k, u, T0, T1) && k > T512) m |= (1ull << e);
        }
      }
      liveC[w] = m;
    }
    if (tid < kept) fkb[tid] = decode_box(P, b, (int)(kr[keeplist[tid]] & 0x7FFF));
    __syncthreads();

    // seed suppression from already-kept items
    for (int k2 = 0; k2 < kept; ++k2) {
      float4 bi = fkb[k2];
      float ia = (bi.z - bi.x) * (bi.w - bi.y);
      for (int u = tid; u < TOTAL_G; u += 256) {
        if (!((liveC[u >> 6] >> (u & 63)) & 1ull)) continue;
        float4 bj4 = decode_box(P, b, u);
        float ja  = (bj4.z - bj4.x) * (bj4.w - bj4.y);
        float ltx = fmaxf(bi.x, bj4.x), lty = fmaxf(bi.y, bj4.y);
        float rbx = fminf(bi.z, bj4.z), rby = fminf(bi.w, bj4.w);
        float wv = fmaxf(rbx - ltx, 0.0f), hv = fmaxf(rby - lty, 0.0f);
        float inter = wv * hv;
        float iou = inter / (ia + ja - inter);
        if (iou > 0.6f) atomicAnd(&liveC[u >> 6], ~(1ull << (u & 63)));
      }
    }
    __syncthreads();

    // selection-by-min-key loop
    while (kept < 100) {
      u64 mymin = ALLF; int myc = -1;
      for (int u = tid; u < TOTAL_G; u += 256) {
        if (!((liveC[u >> 6] >> (u & 63)) & 1ull)) continue;
        u64 k = loadkey(P, b, u);
        if (k < mymin) { mymin = k; myc = u; }
      }
      pk[tid] = mymin; pc[tid] = myc;
      __syncthreads();
      if (tid < 64) {
        u64 m = pk[tid]; int c0 = pc[tid];
        #pragma unroll
        for (int o = 64; o < 256; o += 64)
          if (pk[tid + o] < m) { m = pk[tid + o]; c0 = pc[tid + o]; }
        for (int o = 32; o > 0; o >>= 1) {
          u64 om = __shfl_down(m, o); int oc = __shfl_down(c0, o);
          if (om < m) { m = om; c0 = oc; }
        }
        if (tid == 0) { bk = m; bc2 = c0; }
      }
      __syncthreads();
      if (bk == ALLF) break;
      int cs = bc2;
      if (tid == 0) {
        slotkey_of(ws, b)[kept] = bk;     // fallback keeps write slotkey directly
        atomicAnd(&liveC[cs >> 6], ~(1ull << (cs & 63)));
      }
      __syncthreads();
      kept++;
      if (kept == 100) break;
      float4 bi = decode_box(P, b, cs);
      float ia = (bi.z - bi.x) * (bi.w - bi.y);
      for (int u = tid; u < TOTAL_G; u += 256) {
        if (!((liveC[u >> 6] >> (u & 63)) & 1ull)) continue;
        float4 bj4 = decode_box(P, b, u);
        float ja  = (bj4.z - bj4.x) * (bj4.w - bj4.y);
        float ltx = fmaxf(bi.x, bj4.x), lty = fmaxf(bi.y, bj4.y);
        float rbx = fminf(bi.z, bj4.z), rby = fminf(bi.w, bj4.w);
        float wv = fmaxf(rbx - ltx, 0.0f), hv = fmaxf(rby - lty, 0.0f);
        float inter = wv * hv;
        float iou = inter / (ia + ja - inter);
        if (iou > 0.6f) atomicAnd(&liveC[u >> 6], ~(1ull << (u & 63)));
      }
      __syncthreads();
    }
  }

  // resolve slot keys: walk entries via kr; fallback entries already written; rest = ALLF
  if (tid < 100) {
    if (tid < keptW)     slotkey_of(ws, b)[tid] = kr[keeplist[tid]];
    else if (tid >= kept) slotkey_of(ws, b)[tid] = ALLF;
  }
}

// ---------------- K5: parallel outputs (grid 16 x 10, 256 thr) ----------------
__global__ __launch_bounds__(256) void k_out(Ptrs P, float* out) {
  int b = blockIdx.x, part = blockIdx.y;   // 10 slots per block
  int s0 = part * 10;
  int tid = threadIdx.x;
  const u64* skl = slotkey_of(P.ws, b);

  if (tid < 10) {
    int s = s0 + tid;
    u64 key = skl[s];
    float os = -1.0f, oc = -1.0f;
    float4 bx = make_float4(-1.0f, -1.0f, -1.0f, -1.0f);
    if (key != ALLF) {
      int gid = (int)(key & 0x7FFF);
      os = __uint_as_float(~(u32)(key >> 15));
      oc = (float)((u16*)(P.ws + CLSI_OFF))[(size_t)b * TOTAL_G + gid];
      bx = decode_box(P, b, gid);
    }
    out[b * 100 + s] = os;
    out[1600 + b * 100 + s] = oc;
    *(float4*)(out + 3200 + (size_t)(b * 100 + s) * 4) = bx;
  }

  for (int t = tid; t < 800; t += 256) {
    int sl = t / 80, k = t - sl * 80;
    int s = s0 + sl;
    u64 key = skl[s];
    float val = -1.0f;
    if (key != ALLF) {
      int gid = (int)(key & 0x7FFF);
      int lev, idx, nl; levinfo(gid, lev, idx, nl);
      const float* cp;
      if      (lev == 0) cp = P.cls0;
      else if (lev == 1) cp = P.cls1;
      else if (lev == 2) cp = P.cls2;
      else if (lev == 3) cp = P.cls3;
      else               cp = P.cls4;
      val = sigd(cp[(size_t)(b * nl + idx) * 80 + k]);
    }
    out[9600 + (size_t)(b * 100 + s) * 80 + k] = val;
  }
}

extern "C" void kernel_launch(void* const* d_in, const int* in_sizes, int n_in,
                              void* d_out, int out_size, void* d_ws, size_t ws_size,
                              hipStream_t stream) {
  (void)in_sizes; (void)n_in; (void)out_size; (void)ws_size;
  Ptrs P;
  P.cls0 = (const float*)d_in[0];  P.reg0 = (const float*)d_in[1];
  P.ctr0 = (const float*)d_in[2];  P.pos0 = (const float*)d_in[3];
  P.cls1 = (const float*)d_in[4];  P.reg1 = (const float*)d_in[5];
  P.ctr1 = (const float*)d_in[6];  P.pos1 = (const float*)d_in[7];
  P.cls2 = (const float*)d_in[8];  P.reg2 = (const float*)d_in[9];
  P.ctr2 = (const float*)d_in[10]; P.pos2 = (const float*)d_in[11];
  P.cls3 = (const float*)d_in[12]; P.reg3 = (const float*)d_in[13];
  P.ctr3 = (const float*)d_in[14]; P.pos3 = (const float*)d_in[15];
  P.cls4 = (const float*)d_in[16]; P.reg4 = (const float*)d_in[17];
  P.ctr4 = (const float*)d_in[18]; P.pos4 = (const float*)d_in[19];
  P.ws = (char*)d_ws;

  k_score<<<dim3(267, 16), 256, 0, stream>>>(P);
  k_sel<<<dim3(16, 3), 1024, 0, stream>>>(P);
  k_mask<<<dim3(4, 16), 1024, 0, stream>>>(P);
  k_reduce<<<16, 256, 0, stream>>>(P);
  k_out<<<dim3(16, 10), 256, 0, stream>>>(P, (float*)d_out);
}

// Round 11
// 109.296 us; speedup vs baseline: 1.8908x; 1.0210x over previous
//
#include <hip/hip_runtime.h>
#include <math.h>

#define TOTAL_G 17064
#define BATCHN  16
#define ALLF    0xFFFFFFFFFFFFFFFFull
// valid <=> score > 0.01f <=> scorebits > 0x3C23D70A <=> (key>>15) < 0xC3DC28F5
#define INVALID_HI 0xC3DC28F5u

typedef unsigned long long u64;
typedef unsigned int u32;
typedef unsigned short u16;

// ---- ws layout (bytes), total 3,336,576 ----
#define KEYS0_OFF   0          // u64[16][12800]  1,638,400
#define KEYS1_OFF   1638400    // u64[16][3200]     409,600
#define KEYS234_OFF 2048000    // u64[16][1088]     139,264
#define CLSI_OFF    2187264    // u16[16][17064]    546,048
#define NC_OFF      2733312    // int[32]: [16..31]=n512
#define T512_OFF    2733824    // u64[16]
#define KR_OFF      2733952    // u64[16][512]       65,536
#define MSK_OFF     2799488    // u64[16][512*8]    524,288
#define SLOTK_OFF   3323776    // u64[16][100]       12,800

struct Ptrs {
  const float *cls0,*cls1,*cls2,*cls3,*cls4;
  const float *reg0,*reg1,*reg2,*reg3,*reg4;
  const float *ctr0,*ctr1,*ctr2,*ctr3,*ctr4;
  const float *pos0,*pos1,*pos2,*pos3,*pos4;
  char *ws;
};

__device__ __forceinline__ float sigd(float x) {
  return (float)(1.0 / (1.0 + exp(-(double)x)));
}
__device__ __forceinline__ float dexp(float x) {
  return (float)exp((double)x);
}
__device__ __forceinline__ void levinfo(int gid, int& lev, int& idx, int& nl) {
  if      (gid < 12800) { lev=0; idx=gid;        nl=12800; }
  else if (gid < 16000) { lev=1; idx=gid-12800;  nl=3200;  }
  else if (gid < 16800) { lev=2; idx=gid-16000;  nl=800;   }
  else if (gid < 17008) { lev=3; idx=gid-16800;  nl=208;   }
  else                  { lev=4; idx=gid-17008;  nl=56;    }
}

__device__ __forceinline__ u64* krank_of(char* ws, int b) {
  return (u64*)(ws + KR_OFF + (size_t)b * 4096);
}
__device__ __forceinline__ u64* msk_of(char* ws, int b) {
  return (u64*)(ws + MSK_OFF + (size_t)b * 32768);
}
__device__ __forceinline__ u64* slotkey_of(char* ws, int b) {
  return (u64*)(ws + SLOTK_OFF + (size_t)b * 800);
}

// exact box decode (identical everywhere -> deterministic)
__device__ __forceinline__ float4 decode_box(const Ptrs& P, int b, int gid) {
  int lev, idx, nl; levinfo(gid, lev, idx, nl);
  const float *rp, *pp;
  if      (lev == 0) { rp = P.reg0; pp = P.pos0; }
  else if (lev == 1) { rp = P.reg1; pp = P.pos1; }
  else if (lev == 2) { rp = P.reg2; pp = P.pos2; }
  else if (lev == 3) { rp = P.reg3; pp = P.pos3; }
  else               { rp = P.reg4; pp = P.pos4; }
  float4 rv = *(const float4*)(rp + (size_t)(b * nl + idx) * 4);
  float2 pv = *(const float2*)(pp + (size_t)(b * nl + idx) * 2);
  float e0 = dexp(rv.x), e1 = dexp(rv.y), e2 = dexp(rv.z), e3 = dexp(rv.w);
  float x1 = truncf(pv.x - e0), y1 = truncf(pv.y - e1);
  float x2 = truncf(pv.x + e2), y2 = truncf(pv.y + e3);
  x1 = fmaxf(x1, 0.0f); y1 = fmaxf(y1, 0.0f);
  x2 = fminf(x2, 1023.0f); y2 = fminf(y2, 799.0f);
  return make_float4(x1, y1, x2, y2);
}

// ---------------- K1: LDS-staged, 4-threads-per-position score / argmax / key ----------------
__global__ __launch_bounds__(256) void k_score(Ptrs P) {
  __shared__ float4 sk4[64 * 20];   // 64 positions x 320 B = 20 KB
  int b = blockIdx.y;
  int tid = threadIdx.x;
  int p0 = blockIdx.x * 64;

  #pragma unroll
  for (int it = 0; it < 5; ++it) {
    int t4 = it * 256 + tid;
    int g = p0 + t4 / 20;
    if (g < TOTAL_G) {
      int sub = t4 - (t4 / 20) * 20;
      int lev, idx, nl; levinfo(g, lev, idx, nl);
      const float* clsb;
      if      (lev == 0) clsb = P.cls0;
      else if (lev == 1) clsb = P.cls1;
      else if (lev == 2) clsb = P.cls2;
      else if (lev == 3) clsb = P.cls3;
      else               clsb = P.cls4;
      sk4[t4] = ((const float4*)(clsb + (size_t)(b * nl + idx) * 80))[sub];
    }
  }
  __syncthreads();

  int lp = tid >> 2, q = tid & 3;
  int g = p0 + lp;
  if (g >= TOTAL_G) return;

  const float4* my4 = &sk4[lp * 20 + q * 5];
  float m = -INFINITY, m2 = -INFINITY; int mi = 0;
  #pragma unroll
  for (int k = 0; k < 5; ++k) {
    float4 v = my4[k];
    int base = q * 20 + 4 * k;
    if (v.x > m) { m2 = m; m = v.x; mi = base+0; } else if (v.x > m2) m2 = v.x;
    if (v.y > m) { m2 = m; m = v.y; mi = base+1; } else if (v.y > m2) m2 = v.y;
    if (v.z > m) { m2 = m; m = v.z; mi = base+2; } else if (v.z > m2) m2 = v.z;
    if (v.w > m) { m2 = m; m = v.w; mi = base+3; } else if (v.w > m2) m2 = v.w;
  }
  #pragma unroll
  for (int xw = 1; xw <= 2; xw <<= 1) {
    float om  = __shfl_xor(m,  xw);
    float om2 = __shfl_xor(m2, xw);
    int   omi = __shfl_xor(mi, xw);
    bool take = (om > m) || (om == m && omi < mi);
    float lm  = take ? m : om;
    float wm2 = take ? om2 : m2;
    if (take) { m = om; mi = omi; }
    m2 = fmaxf(lm, wm2);
  }

  float thr = fminf(m - 1e-3f, 9.0f);
  float pmax; int ci;
  if (m2 >= thr) {
    // rare exact path: per-element sigmoid argmax among candidates >= thr
    float pv = -1.0f; int pi = 0x7fffffff;
    #pragma unroll 1
    for (int k = 0; k < 5; ++k) {
      float4 v = my4[k];
      float xs[4] = {v.x, v.y, v.z, v.w};
      #pragma unroll
      for (int e = 0; e < 4; ++e) {
        if (xs[e] >= thr) {
          float p = sigd(xs[e]);
          if (p > pv) { pv = p; pi = q * 20 + 4 * k + e; }
        }
      }
    }
    #pragma unroll
    for (int xw = 1; xw <= 2; xw <<= 1) {
      float ov = __shfl_xor(pv, xw);
      int   oi = __shfl_xor(pi, xw);
      if (ov > pv || (ov == pv && oi < pi)) { pv = ov; pi = oi; }
    }
    pmax = pv; ci = pi;
  } else {
    pmax = sigd(m); ci = mi;
  }

  if (q == 0) {
    int lev, idx, nl; levinfo(g, lev, idx, nl);
    const float* ctrb;
    if      (lev == 0) ctrb = P.ctr0;
    else if (lev == 1) ctrb = P.ctr1;
    else if (lev == 2) ctrb = P.ctr2;
    else if (lev == 3) ctrb = P.ctr3;
    else               ctrb = P.ctr4;
    float tc = ctrb[(size_t)b * nl + idx];
    float csig = sigd(tc);
    float prod = pmax * csig;
    float s = (float)sqrt((double)prod);
    ((u16*)(P.ws + CLSI_OFF))[(size_t)b * TOTAL_G + g] = (u16)ci;
    unsigned hi = ~__float_as_uint(s);
    u64 key = ((u64)hi << 15) | (unsigned)g;
    if      (lev == 0) ((u64*)(P.ws + KEYS0_OFF))  [(size_t)b * 12800 + idx] = key;
    else if (lev == 1) ((u64*)(P.ws + KEYS1_OFF))  [(size_t)b * 3200  + idx] = key;
    else               ((u64*)(P.ws + KEYS234_OFF))[(size_t)b * 1088  + (g - 16000)] = key;
  }
}

// ---------------- adaptive radix select (1024 threads) ----------------
struct SelSh {
  u32 hist[4][4096];   // 64 KB, 4 replicas
  u64 buf[64];
  u64 res, pfx;
  int t, mode, cnt;
};

__device__ __forceinline__ u64 loadkey(const Ptrs& P, int b, int u) {
  if (u < 12800) return ((const u64*)(P.ws + KEYS0_OFF))  [(size_t)b * 12800 + u];
  if (u < 16000) return ((const u64*)(P.ws + KEYS1_OFF))  [(size_t)b * 3200  + (u - 12800)];
  return               ((const u64*)(P.ws + KEYS234_OFF))[(size_t)b * 1088  + (u - 16000)];
}
__device__ __forceinline__ bool keep_pred(u64 k, int u, u64 T0, u64 T1) {
  bool valid = (u32)(k >> 15) < INVALID_HI;
  bool sel = (u < 12800) ? (k <= T0) : ((u < 16000) ? (k <= T1) : true);
  return valid && sel;
}

// exact t0-th smallest (1-indexed). keys distinct. key[46:45]==0b11 always.
// pred: 2 = all TOTAL_G keys, valid-only filter. Returns ALLF if < t0 eligible.
// Deterministic: histogram sums order-independent; collect ranks by value.
__device__ u64 fast_select(const Ptrs& P, int b, int pred, int t0, SelSh* S) {
  int tid = threadIdx.x, wid = tid >> 6, lane = tid & 63;
  int rep = wid & 3;
  u64 Pfx = 3; int t = t0;
  const int SS[4] = {33, 21, 9, 0};
  const int WW[4] = {12, 12, 12, 9};
  #pragma unroll 1
  for (int p = 0; p < 4; ++p) {
    int s = SS[p], wb = WW[p];
    u32 dmask = (1u << wb) - 1u;
    for (int i = tid; i < 4 * 4096; i += 1024) (&S->hist[0][0])[i] = 0;
    if (tid == 0) { S->mode = 0; S->cnt = 0; }
    __syncthreads();
    for (int i = tid; i < TOTAL_G; i += 1024) {
      u64 k = loadkey(P, b, i);
      if (pred == 2 && !((u32)(k >> 15) < INVALID_HI)) continue;
      if ((k >> (s + wb)) == Pfx)
        atomicAdd(&S->hist[rep][(u32)(k >> s) & dmask], 1u);
    }
    __syncthreads();
    for (int i = tid; i < 4096; i += 1024) {
      u32 v = S->hist[0][i] + S->hist[1][i] + S->hist[2][i] + S->hist[3][i];
      S->hist[0][i] = v;
    }
    __syncthreads();
    if (wid == 0) {
      u32 ssum = 0;
      #pragma unroll 8
      for (int i = 0; i < 64; ++i) {
        int ii = (i + lane) & 63;
        ssum += S->hist[0][(lane << 6) + ii];
      }
      u32 inc = ssum;
      for (int o = 1; o < 64; o <<= 1) { u32 v = __shfl_up(inc, o); if (lane >= o) inc += v; }
      u64 ball = __ballot(inc >= (u32)t);
      if (!ball) {
        if (lane == 0) { S->mode = 9; S->res = ALLF; }   // fewer than t keys
      } else {
        int Wq = __ffsll(ball) - 1;
        u32 cumBefore = __shfl(inc - ssum, Wq);
        u32 v2 = S->hist[0][(Wq << 6) + lane];
        u32 inc2 = v2;
        for (int o = 1; o < 64; o <<= 1) { u32 x = __shfl_up(inc2, o); if (lane >= o) inc2 += x; }
        u64 ball2 = __ballot(cumBefore + inc2 >= (u32)t);
        int l2 = __ffsll(ball2) - 1;
        u32 cumB2 = __shfl(cumBefore + inc2 - v2, l2);
        u32 c = __shfl(v2, l2);
        if (lane == 0) {
          int d = (Wq << 6) + l2;
          u64 np = (Pfx << wb) | (u32)d;
          S->pfx = np; S->t = t - (int)cumB2;
          if (s == 0)       { S->mode = 9; S->res = np; }
          else if (c == 1)  { S->mode = 1; }
          else if (c <= 64) { S->mode = 2; }
        }
      }
    }
    __syncthreads();
    int mode = S->mode; u64 np = S->pfx; int tt = S->t;
    if (mode == 9) return S->res;
    if (mode == 1 || mode == 2) {
      for (int i = tid; i < TOTAL_G; i += 1024) {
        u64 k = loadkey(P, b, i);
        if (pred == 2 && !((u32)(k >> 15) < INVALID_HI)) continue;
        if ((k >> s) == np) {
          if (mode == 1) S->res = k;
          else { int pos = atomicAdd(&S->cnt, 1); S->buf[pos] = k; }
        }
      }
      __syncthreads();
      if (mode == 2 && wid == 0) {
        int c2 = S->cnt;
        u64 kl = (lane < c2) ? S->buf[lane] : ALLF;
        int r = 0;
        for (int j = 0; j < c2; ++j) r += (S->buf[j] < kl) ? 1 : 0;
        if (lane < c2 && r == tt - 1) S->res = kl;
      }
      __syncthreads();
      return S->res;
    }
    Pfx = np; t = tt;
    __syncthreads();
  }
  return S->pfx;
}

// ---------------- K2: in-block T512 + compact + rank + decode + mask (grid 4 x 16) ----------------
// keep5 = valid && key <= T512 (per-level top-1000 filter provably redundant here:
// a valid key <= T512 has within-level valid-rank < 512 < 1000).
// T512 computed redundantly per block — fast_select is deterministic, so all 4
// quadrant blocks derive the identical value; redundant copies run on idle CUs.
__global__ __launch_bounds__(1024) void k_mask(Ptrs P) {
  __shared__ union USh {
    SelSh S;                                         // 64.6 KB (select phase)
    struct { float4 sbox[512]; u64 smaskR[4096]; u16 parts[1024]; } M;   // 43 KB
  } U;
  __shared__ u64 skey[512];
  __shared__ u16 srank[512];
  __shared__ int wbase[272];
  __shared__ int sN5;
  int qi = blockIdx.x, b = blockIdx.y;
  int tid = threadIdx.x, wid = tid >> 6, lane = tid & 63;
  char* ws = P.ws;

  u64 T512 = fast_select(P, b, 2, 512, &U.S);
  if (qi == 0 && tid == 0) ((u64*)(ws + T512_OFF))[b] = T512;

  // pass A: per-wave keep5 counts (deterministic order -> identical across blocks)
  for (int it = 0; it < 17; ++it) {
    int u = it * 1024 + tid;
    bool keep5 = false;
    if (u < TOTAL_G) {
      u64 k = loadkey(P, b, u);
      keep5 = ((u32)(k >> 15) < INVALID_HI) && (k <= T512);
    }
    u64 bal = __ballot(keep5);
    if (lane == 0) wbase[it * 16 + wid] = __popcll(bal);
  }
  __syncthreads();   // barrier between select's last union read and later union writes
  if (wid == 0) {
    int carry = 0;
    for (int base = 0; base < 272; base += 64) {
      int idx = base + lane;
      int v = (idx < 272) ? wbase[idx] : 0;
      int inc = v;
      for (int o = 1; o < 64; o <<= 1) { int x = __shfl_up(inc, o); if (lane >= o) inc += x; }
      if (idx < 272) wbase[idx] = inc - v + carry;
      carry += __shfl(inc, 63);
    }
    if (lane == 0) sN5 = carry;
  }
  __syncthreads();
  int n512 = sN5;                       // <= 512 by construction
  if (qi == 0 && tid == 0) ((int*)(ws + NC_OFF))[16 + b] = n512;

  // pass B: ordered scatter into LDS
  for (int it = 0; it < 17; ++it) {
    int u = it * 1024 + tid;
    bool keep5 = false; u64 k = 0;
    if (u < TOTAL_G) {
      k = loadkey(P, b, u);
      keep5 = ((u32)(k >> 15) < INVALID_HI) && (k <= T512);
    }
    u64 bal = __ballot(keep5);
    int pos = wbase[it * 16 + wid] + __popcll(bal & ((1ull << lane) - 1ull));
    if (keep5) skey[pos] = k;
  }
  __syncthreads();

  // decode + pad (first union-M writes — select long finished, multiple barriers ago)
  if (tid < 512) {
    if (tid < n512) {
      U.M.sbox[tid] = decode_box(P, b, (int)(skey[tid] & 0x7FFF));
    } else {
      skey[tid] = (ALLF - 511) + (u64)tid;   // distinct, > any real key
      U.M.sbox[tid] = make_float4(-1e30f, -1e30f, -1e30f, -1e30f);
    }
  }
  for (int i = tid; i < 512 * 8; i += 1024) U.M.smaskR[i] = 0ull;
  __syncthreads();

  // rank all 512 by key
  {
    int t2 = tid & 511, half = tid >> 9;
    u64 mykey = skey[t2];
    int jb = half << 8, cnt = 0;
    #pragma unroll 4
    for (int j = jb; j < jb + 256; ++j) cnt += (skey[j] < mykey) ? 1 : 0;
    U.M.parts[tid] = (u16)cnt;
  }
  __syncthreads();
  if (tid < 512) srank[tid] = (u16)(U.M.parts[tid] + U.M.parts[tid + 512]);
  __syncthreads();

  // suppression bits in rank space (rotated j-scan, conflict-free)
  int i = qi * 128 + (tid >> 3);
  int w = tid & 7;
  float4 bi = U.M.sbox[i];
  u64 ki = skey[i];
  int ri = srank[i];
  float ia = (bi.z - bi.x) * (bi.w - bi.y);
  #pragma unroll 8
  for (int bj = 0; bj < 64; ++bj) {
    int jj = (bj + w) & 63;
    int j = (w << 6) | jj;
    u64 kj = skey[j];
    if (ki < kj) {
      float4 bj4 = U.M.sbox[j];
      float ja  = (bj4.z - bj4.x) * (bj4.w - bj4.y);
      float ltx = fmaxf(bi.x, bj4.x), lty = fmaxf(bi.y, bj4.y);
      float rbx = fminf(bi.z, bj4.z), rby = fminf(bi.w, bj4.w);
      float wv = fmaxf(rbx - ltx, 0.0f), hv = fmaxf(rby - lty, 0.0f);
      float inter = wv * hv;
      float iou = inter / (ia + ja - inter);   // exact: integer-valued fp32
      if (iou > 0.6f) {
        int rj = srank[j];
        atomicOr(&U.M.smaskR[ri * 8 + (rj >> 6)], 1ull << (rj & 63));
      }
    }
  }
  __syncthreads();

  {
    int il = tid >> 3, ww = tid & 7;
    int ig = qi * 128 + il;
    if (ig < n512) {
      int r = srank[ig];
      msk_of(ws, b)[r * 8 + ww] = U.M.smaskR[r * 8 + ww];
      if (ww == 0) krank_of(ws, b)[r] = skey[ig];
    }
  }
}

// ---------------- 256-thread exact radix select (fallback only; no early exits) ----------------
__device__ u64 select256(const u64* keys, int n, int t0, u32* hist, u64* shP, int* shT) {
  u64 Pfx = 3; int t = t0;
  const int SS[4] = {33, 21, 9, 0};
  const int WW[4] = {12, 12, 12, 9};
  for (int p = 0; p < 4; ++p) {
    int s = SS[p], wb = WW[p];
    u32 dmask = (1u << wb) - 1u;
    for (int i = threadIdx.x; i < 4096; i += 256) hist[i] = 0;
    __syncthreads();
    for (int i = threadIdx.x; i < n; i += 256) {
      u64 k = keys[i];
      if ((k >> (s + wb)) == Pfx) atomicAdd(&hist[(u32)(k >> s) & dmask], 1u);
    }
    __syncthreads();
    if (threadIdx.x < 64) {
      int lane = threadIdx.x;
      u32 ssum = 0;
      for (int i = 0; i < 64; ++i) ssum += hist[(lane << 6) + ((i + lane) & 63)];
      u32 inc = ssum;
      for (int o = 1; o < 64; o <<= 1) { u32 v = __shfl_up(inc, o); if (lane >= o) inc += v; }
      u64 ball = __ballot(inc >= (u32)t);
      int Wq = __ffsll(ball) - 1;
      u32 cumBefore = __shfl(inc - ssum, Wq);
      u32 v2 = hist[(Wq << 6) + lane];
      u32 inc2 = v2;
      for (int o = 1; o < 64; o <<= 1) { u32 x = __shfl_up(inc2, o); if (lane >= o) inc2 += x; }
      u64 ball2 = __ballot(cumBefore + inc2 >= (u32)t);
      int l2 = __ffsll(ball2) - 1;
      u32 cumB2 = __shfl(cumBefore + inc2 - v2, l2);
      if (lane == 0) { *shP = (Pfx << wb) | (u32)((Wq << 6) + l2); *shT = t - (int)cumB2; }
    }
    __syncthreads();
    Pfx = *shP; t = *shT;
    __syncthreads();
  }
  return Pfx;   // final pass (s=0) yields the full 47-bit key
}

// ---------------- K3: greedy ffs walk + fallback + slotkey (grid 16, 256 thr) ----------------
__global__ __launch_bounds__(256) void k_reduce(Ptrs P) {
  __shared__ u64 smask[4096];       // 32 KB
  __shared__ u32 keeplist[100];     // ranks (walk phase only)
  __shared__ int keptS;
  __shared__ u64 liveC[267];        // fallback: live bits over gid space
  __shared__ union UF {
    u32 hist[4096];                 // 16 KB (fallback selects)
    struct { u64 pk[256]; int pc[256]; float4 fkb[100]; } F;
  } UF_;
  __shared__ u64 shP; __shared__ int shT;
  __shared__ u64 bk; __shared__ int bc2;

  int b = blockIdx.x;
  int tid = threadIdx.x;
  char* ws = P.ws;
  int n512 = ((int*)(ws + NC_OFF))[16 + b];
  const u64* kr = krank_of(ws, b);

  const u64* gmask = msk_of(ws, b);
  for (int t = tid; t < 4096; t += 256) smask[t] = gmask[t];
  __syncthreads();

  // single-wave barrier-free greedy walk over ranks [0, n512)
  if (tid < 64) {
    int lane = tid;
    u64 lw = 0;
    if (lane < 8) {
      int lo = lane << 6;
      int c = n512 - lo; if (c < 0) c = 0; if (c > 64) c = 64;
      lw = (c >= 64) ? ALLF : ((c > 0) ? ((1ull << c) - 1ull) : 0ull);
    }
    int kept = 0;
    while (kept < 100) {
      bool nz = (lane < 8) && (lw != 0ull);
      u64 bal = __ballot(nz);
      if (!bal) break;
      int W = __ffsll(bal) - 1;
      u64 wv = __shfl(lw, W);
      int bit = __ffsll(wv) - 1;
      int i = (W << 6) + bit;
      if (lane == 0) keeplist[kept] = (u32)i;
      kept++;
      if (lane == W) lw &= ~(1ull << bit);
      if (kept == 100) break;
      if (lane < 8) lw &= ~smask[i * 8 + lane];
    }
    if (lane == 0) keptS = kept;
  }
  __syncthreads();
  int kept = keptS;
  int keptW = kept;

  // fallback: keeps beyond the global top-512 (possible only if n512==512; rare; exact)
  if (kept < 100 && n512 == 512) {
    // lazily compute exact per-level top-1000 thresholds (never-taken path)
    u64 T0 = select256((const u64*)(ws + KEYS0_OFF) + (size_t)b * 12800, 12800, 1000,
                       UF_.hist, &shP, &shT);
    u64 T1 = select256((const u64*)(ws + KEYS1_OFF) + (size_t)b * 3200, 3200, 1000,
                       UF_.hist, &shP, &shT);
    u64 T512 = ((u64*)(ws + T512_OFF))[b];
    for (int w = tid; w < 267; w += 256) {
      int lo = w << 6;
      u64 m = 0;
      for (int e = 0; e < 64; ++e) {
        int u = lo + e;
        if (u < TOTAL_G) {
          u64 k = loadkey(P, b, u);
          if (keep_pred(k, u, T0, T1) && k > T512) m |= (1ull << e);
        }
      }
      liveC[w] = m;
    }
    if (tid < kept) UF_.F.fkb[tid] = decode_box(P, b, (int)(kr[keeplist[tid]] & 0x7FFF));
    __syncthreads();

    // seed suppression from already-kept items
    for (int k2 = 0; k2 < kept; ++k2) {
      float4 bi = UF_.F.fkb[k2];
      float ia = (bi.z - bi.x) * (bi.w - bi.y);
      for (int u = tid; u < TOTAL_G; u += 256) {
        if (!((liveC[u >> 6] >> (u & 63)) & 1ull)) continue;
        float4 bj4 = decode_box(P, b, u);
        float ja  = (bj4.z - bj4.x) * (bj4.w - bj4.y);
        float ltx = fmaxf(bi.x, bj4.x), lty = fmaxf(bi.y, bj4.y);
        float rbx = fminf(bi.z, bj4.z), rby = fminf(bi.w, bj4.w);
        float wv = fmaxf(rbx - ltx, 0.0f), hv = fmaxf(rby - lty, 0.0f);
        float inter = wv * hv;
        float iou = inter / (ia + ja - inter);
        if (iou > 0.6f) atomicAnd(&liveC[u >> 6], ~(1ull << (u & 63)));
      }
    }
    __syncthreads();

    // selection-by-min-key loop
    while (kept < 100) {
      u64 mymin = ALLF; int myc = -1;
      for (int u = tid; u < TOTAL_G; u += 256) {
        if (!((liveC[u >> 6] >> (u & 63)) & 1ull)) continue;
        u64 k = loadkey(P, b, u);
        if (k < mymin) { mymin = k; myc = u; }
      }
      UF_.F.pk[tid] = mymin; UF_.F.pc[tid] = myc;
      __syncthreads();
      if (tid < 64) {
        u64 m = UF_.F.pk[tid]; int c0 = UF_.F.pc[tid];
        #pragma unroll
        for (int o = 64; o < 256; o += 64)
          if (UF_.F.pk[tid + o] < m) { m = UF_.F.pk[tid + o]; c0 = UF_.F.pc[tid + o]; }
        for (int o = 32; o > 0; o >>= 1) {
          u64 om = __shfl_down(m, o); int oc = __shfl_down(c0, o);
          if (om < m) { m = om; c0 = oc; }
        }
        if (tid == 0) { bk = m; bc2 = c0; }
      }
      __syncthreads();
      if (bk == ALLF) break;
      int cs = bc2;
      if (tid == 0) {
        slotkey_of(ws, b)[kept] = bk;     // fallback keeps write slotkey directly
        atomicAnd(&liveC[cs >> 6], ~(1ull << (cs & 63)));
      }
      __syncthreads();
      kept++;
      if (kept == 100) break;
      float4 bi = decode_box(P, b, cs);
      float ia = (bi.z - bi.x) * (bi.w - bi.y);
      for (int u = tid; u < TOTAL_G; u += 256) {
        if (!((liveC[u >> 6] >> (u & 63)) & 1ull)) continue;
        float4 bj4 = decode_box(P, b, u);
        float ja  = (bj4.z - bj4.x) * (bj4.w - bj4.y);
        float ltx = fmaxf(bi.x, bj4.x), lty = fmaxf(bi.y, bj4.y);
        float rbx = fminf(bi.z, bj4.z), rby = fminf(bi.w, bj4.w);
        float wv = fmaxf(rbx - ltx, 0.0f), hv = fmaxf(rby - lty, 0.0f);
        float inter = wv * hv;
        float iou = inter / (ia + ja - inter);
        if (iou > 0.6f) atomicAnd(&liveC[u >> 6], ~(1ull << (u & 63)));
      }
      __syncthreads();
    }
  }

  // resolve slot keys: walk entries via kr; fallback entries already written; rest = ALLF
  if (tid < 100) {
    if (tid < keptW)      slotkey_of(ws, b)[tid] = kr[keeplist[tid]];
    else if (tid >= kept) slotkey_of(ws, b)[tid] = ALLF;
  }
}

// ---------------- K4: parallel outputs (grid 16 x 10, 256 thr) ----------------
__global__ __launch_bounds__(256) void k_out(Ptrs P, float* out) {
  int b = blockIdx.x, part = blockIdx.y;   // 10 slots per block
  int s0 = part * 10;
  int tid = threadIdx.x;
  const u64* skl = slotkey_of(P.ws, b);

  if (tid < 10) {
    int s = s0 + tid;
    u64 key = skl[s];
    float os = -1.0f, oc = -1.0f;
    float4 bx = make_float4(-1.0f, -1.0f, -1.0f, -1.0f);
    if (key != ALLF) {
      int gid = (int)(key & 0x7FFF);
      os = __uint_as_float(~(u32)(key >> 15));
      oc = (float)((u16*)(P.ws + CLSI_OFF))[(size_t)b * TOTAL_G + gid];
      bx = decode_box(P, b, gid);
    }
    out[b * 100 + s] = os;
    out[1600 + b * 100 + s] = oc;
    *(float4*)(out + 3200 + (size_t)(b * 100 + s) * 4) = bx;
  }

  for (int t = tid; t < 800; t += 256) {
    int sl = t / 80, k = t - sl * 80;
    int s = s0 + sl;
    u64 key = skl[s];
    float val = -1.0f;
    if (key != ALLF) {
      int gid = (int)(key & 0x7FFF);
      int lev, idx, nl; levinfo(gid, lev, idx, nl);
      const float* cp;
      if      (lev == 0) cp = P.cls0;
      else if (lev == 1) cp = P.cls1;
      else if (lev == 2) cp = P.cls2;
      else if (lev == 3) cp = P.cls3;
      else               cp = P.cls4;
      val = sigd(cp[(size_t)(b * nl + idx) * 80 + k]);
    }
    out[9600 + (size_t)(b * 100 + s) * 80 + k] = val;
  }
}

extern "C" void kernel_launch(void* const* d_in, const int* in_sizes, int n_in,
                              void* d_out, int out_size, void* d_ws, size_t ws_size,
                              hipStream_t stream) {
  (void)in_sizes; (void)n_in; (void)out_size; (void)ws_size;
  Ptrs P;
  P.cls0 = (const float*)d_in[0];  P.reg0 = (const float*)d_in[1];
  P.ctr0 = (const float*)d_in[2];  P.pos0 = (const float*)d_in[3];
  P.cls1 = (const float*)d_in[4];  P.reg1 = (const float*)d_in[5];
  P.ctr1 = (const float*)d_in[6];  P.pos1 = (const float*)d_in[7];
  P.cls2 = (const float*)d_in[8];  P.reg2 = (const float*)d_in[9];
  P.ctr2 = (const float*)d_in[10]; P.pos2 = (const float*)d_in[11];
  P.cls3 = (const float*)d_in[12]; P.reg3 = (const float*)d_in[13];
  P.ctr3 = (const float*)d_in[14]; P.pos3 = (const float*)d_in[15];
  P.cls4 = (const float*)d_in[16]; P.reg4 = (const float*)d_in[17];
  P.ctr4 = (const float*)d_in[18]; P.pos4 = (const float*)d_in[19];
  P.ws = (char*)d_ws;

  k_score<<<dim3(267, 16), 256, 0, stream>>>(P);
  k_mask<<<dim3(4, 16), 1024, 0, stream>>>(P);
  k_reduce<<<16, 256, 0, stream>>>(P);
  k_out<<<dim3(16, 10), 256, 0, stream>>>(P, (float*)d_out);
}

// Round 12
// 99.126 us; speedup vs baseline: 2.0848x; 1.1026x over previous
//
#include <hip/hip_runtime.h>
#include <math.h>

#define TOTAL_G 17064
#define BATCHN  16
#define ALLF    0xFFFFFFFFFFFFFFFFull
// valid <=> score > 0.01f <=> scorebits > 0x3C23D70A <=> (key>>15) < 0xC3DC28F5
#define INVALID_HI 0xC3DC28F5u

typedef unsigned long long u64;
typedef unsigned int u32;
typedef unsigned short u16;

// ---- ws layout (bytes), total 3,336,576 ----
#define KEYS0_OFF   0          // u64[16][12800]  1,638,400
#define KEYS1_OFF   1638400    // u64[16][3200]     409,600
#define KEYS234_OFF 2048000    // u64[16][1088]     139,264
#define CLSI_OFF    2187264    // u16[16][17064]    546,048
#define NC_OFF      2733312    // int[32]: [16..31]=n512
#define T512_OFF    2733824    // u64[16]  (= Boundary-1; fallback predicate k > T512)
#define KR_OFF      2733952    // u64[16][512]       65,536
#define MSK_OFF     2799488    // u64[16][512*8]    524,288
#define SLOTK_OFF   3323776    // u64[16][100]       12,800

struct Ptrs {
  const float *cls0,*cls1,*cls2,*cls3,*cls4;
  const float *reg0,*reg1,*reg2,*reg3,*reg4;
  const float *ctr0,*ctr1,*ctr2,*ctr3,*ctr4;
  const float *pos0,*pos1,*pos2,*pos3,*pos4;
  char *ws;
};

__device__ __forceinline__ float sigd(float x) {
  return (float)(1.0 / (1.0 + exp(-(double)x)));
}
__device__ __forceinline__ float dexp(float x) {
  return (float)exp((double)x);
}
__device__ __forceinline__ void levinfo(int gid, int& lev, int& idx, int& nl) {
  if      (gid < 12800) { lev=0; idx=gid;        nl=12800; }
  else if (gid < 16000) { lev=1; idx=gid-12800;  nl=3200;  }
  else if (gid < 16800) { lev=2; idx=gid-16000;  nl=800;   }
  else if (gid < 17008) { lev=3; idx=gid-16800;  nl=208;   }
  else                  { lev=4; idx=gid-17008;  nl=56;    }
}

__device__ __forceinline__ u64* krank_of(char* ws, int b) {
  return (u64*)(ws + KR_OFF + (size_t)b * 4096);
}
__device__ __forceinline__ u64* msk_of(char* ws, int b) {
  return (u64*)(ws + MSK_OFF + (size_t)b * 32768);
}
__device__ __forceinline__ u64* slotkey_of(char* ws, int b) {
  return (u64*)(ws + SLOTK_OFF + (size_t)b * 800);
}

// exact box decode (identical everywhere -> deterministic)
__device__ __forceinline__ float4 decode_box(const Ptrs& P, int b, int gid) {
  int lev, idx, nl; levinfo(gid, lev, idx, nl);
  const float *rp, *pp;
  if      (lev == 0) { rp = P.reg0; pp = P.pos0; }
  else if (lev == 1) { rp = P.reg1; pp = P.pos1; }
  else if (lev == 2) { rp = P.reg2; pp = P.pos2; }
  else if (lev == 3) { rp = P.reg3; pp = P.pos3; }
  else               { rp = P.reg4; pp = P.pos4; }
  float4 rv = *(const float4*)(rp + (size_t)(b * nl + idx) * 4);
  float2 pv = *(const float2*)(pp + (size_t)(b * nl + idx) * 2);
  float e0 = dexp(rv.x), e1 = dexp(rv.y), e2 = dexp(rv.z), e3 = dexp(rv.w);
  float x1 = truncf(pv.x - e0), y1 = truncf(pv.y - e1);
  float x2 = truncf(pv.x + e2), y2 = truncf(pv.y + e3);
  x1 = fmaxf(x1, 0.0f); y1 = fmaxf(y1, 0.0f);
  x2 = fminf(x2, 1023.0f); y2 = fminf(y2, 799.0f);
  return make_float4(x1, y1, x2, y2);
}

// ---------------- K1: LDS-staged, 4-threads-per-position score / argmax / key ----------------
__global__ __launch_bounds__(256) void k_score(Ptrs P) {
  __shared__ float4 sk4[64 * 20];   // 64 positions x 320 B = 20 KB
  int b = blockIdx.y;
  int tid = threadIdx.x;
  int p0 = blockIdx.x * 64;

  #pragma unroll
  for (int it = 0; it < 5; ++it) {
    int t4 = it * 256 + tid;
    int g = p0 + t4 / 20;
    if (g < TOTAL_G) {
      int sub = t4 - (t4 / 20) * 20;
      int lev, idx, nl; levinfo(g, lev, idx, nl);
      const float* clsb;
      if      (lev == 0) clsb = P.cls0;
      else if (lev == 1) clsb = P.cls1;
      else if (lev == 2) clsb = P.cls2;
      else if (lev == 3) clsb = P.cls3;
      else               clsb = P.cls4;
      sk4[t4] = ((const float4*)(clsb + (size_t)(b * nl + idx) * 80))[sub];
    }
  }
  __syncthreads();

  int lp = tid >> 2, q = tid & 3;
  int g = p0 + lp;
  if (g >= TOTAL_G) return;

  const float4* my4 = &sk4[lp * 20 + q * 5];
  float m = -INFINITY, m2 = -INFINITY; int mi = 0;
  #pragma unroll
  for (int k = 0; k < 5; ++k) {
    float4 v = my4[k];
    int base = q * 20 + 4 * k;
    if (v.x > m) { m2 = m; m = v.x; mi = base+0; } else if (v.x > m2) m2 = v.x;
    if (v.y > m) { m2 = m; m = v.y; mi = base+1; } else if (v.y > m2) m2 = v.y;
    if (v.z > m) { m2 = m; m = v.z; mi = base+2; } else if (v.z > m2) m2 = v.z;
    if (v.w > m) { m2 = m; m = v.w; mi = base+3; } else if (v.w > m2) m2 = v.w;
  }
  #pragma unroll
  for (int xw = 1; xw <= 2; xw <<= 1) {
    float om  = __shfl_xor(m,  xw);
    float om2 = __shfl_xor(m2, xw);
    int   omi = __shfl_xor(mi, xw);
    bool take = (om > m) || (om == m && omi < mi);
    float lm  = take ? m : om;
    float wm2 = take ? om2 : m2;
    if (take) { m = om; mi = omi; }
    m2 = fmaxf(lm, wm2);
  }

  float thr = fminf(m - 1e-3f, 9.0f);
  float pmax; int ci;
  if (m2 >= thr) {
    // rare exact path: per-element sigmoid argmax among candidates >= thr
    float pv = -1.0f; int pi = 0x7fffffff;
    #pragma unroll 1
    for (int k = 0; k < 5; ++k) {
      float4 v = my4[k];
      float xs[4] = {v.x, v.y, v.z, v.w};
      #pragma unroll
      for (int e = 0; e < 4; ++e) {
        if (xs[e] >= thr) {
          float p = sigd(xs[e]);
          if (p > pv) { pv = p; pi = q * 20 + 4 * k + e; }
        }
      }
    }
    #pragma unroll
    for (int xw = 1; xw <= 2; xw <<= 1) {
      float ov = __shfl_xor(pv, xw);
      int   oi = __shfl_xor(pi, xw);
      if (ov > pv || (ov == pv && oi < pi)) { pv = ov; pi = oi; }
    }
    pmax = pv; ci = pi;
  } else {
    pmax = sigd(m); ci = mi;
  }

  if (q == 0) {
    int lev, idx, nl; levinfo(g, lev, idx, nl);
    const float* ctrb;
    if      (lev == 0) ctrb = P.ctr0;
    else if (lev == 1) ctrb = P.ctr1;
    else if (lev == 2) ctrb = P.ctr2;
    else if (lev == 3) ctrb = P.ctr3;
    else               ctrb = P.ctr4;
    float tc = ctrb[(size_t)b * nl + idx];
    float csig = sigd(tc);
    float prod = pmax * csig;
    float s = (float)sqrt((double)prod);
    ((u16*)(P.ws + CLSI_OFF))[(size_t)b * TOTAL_G + g] = (u16)ci;
    unsigned hi = ~__float_as_uint(s);
    u64 key = ((u64)hi << 15) | (unsigned)g;
    if      (lev == 0) ((u64*)(P.ws + KEYS0_OFF))  [(size_t)b * 12800 + idx] = key;
    else if (lev == 1) ((u64*)(P.ws + KEYS1_OFF))  [(size_t)b * 3200  + idx] = key;
    else               ((u64*)(P.ws + KEYS234_OFF))[(size_t)b * 1088  + (g - 16000)] = key;
  }
}

__device__ __forceinline__ u64 loadkey(const Ptrs& P, int b, int u) {
  if (u < 12800) return ((const u64*)(P.ws + KEYS0_OFF))  [(size_t)b * 12800 + u];
  if (u < 16000) return ((const u64*)(P.ws + KEYS1_OFF))  [(size_t)b * 3200  + (u - 12800)];
  return               ((const u64*)(P.ws + KEYS234_OFF))[(size_t)b * 1088  + (u - 16000)];
}
__device__ __forceinline__ bool keep_pred(u64 k, int u, u64 T0, u64 T1) {
  bool valid = (u32)(k >> 15) < INVALID_HI;
  bool sel = (u < 12800) ? (k <= T0) : ((u < 16000) ? (k <= T1) : true);
  return valid && sel;
}

// ---------------- K2: single-pass prefix boundary + compact + rank + decode + mask ----------------
// Valid keys all have key bits [46:41] == 48 (score in (0.01,1] => hi>>26 == 48),
// so bits [40:29] are the top 12 VARYING bits. One 4096-bin histogram of those
// bits + cumsum finds bin B' where cum >= 512. Working set = valid keys <
// Boundary = (48<<41)|(B'<<29): a TRUE PREFIX of global key order with n512 =
// cumBefore < 512. Walk on a prefix + exact fallback beyond it = exact greedy
// (same argument as the exact-T512 version; fallback predicate k > Boundary-1).
// No-crossing case (fewer than 512 valid keys): Boundary = first invalid key.
// Deterministic across the 4 quadrant blocks (order-independent sums).
__global__ __launch_bounds__(1024) void k_mask(Ptrs P) {
  __shared__ union USh {
    u32 H[4][4096];                                                      // 64 KB
    struct { float4 sbox[512]; u64 smaskR[4096]; u16 parts[1024]; } M;   // 42 KB
  } U;
  __shared__ u64 skey[512];
  __shared__ u16 srank[512];
  __shared__ int wbase[272];
  __shared__ int sN5;
  __shared__ u64 sBoundary;
  int qi = blockIdx.x, b = blockIdx.y;
  int tid = threadIdx.x, wid = tid >> 6, lane = tid & 63;
  char* ws = P.ws;

  // phase 1: histogram of valid keys' bits [40:29]
  for (int i = tid; i < 4 * 4096; i += 1024) (&U.H[0][0])[i] = 0;
  __syncthreads();
  for (int u = tid; u < TOTAL_G; u += 1024) {
    u64 k = loadkey(P, b, u);
    if ((u32)(k >> 15) < INVALID_HI)
      atomicAdd(&U.H[wid & 3][(u32)(k >> 29) & 0xFFF], 1u);
  }
  __syncthreads();
  for (int i = tid; i < 4096; i += 1024) {
    u32 v = U.H[0][i] + U.H[1][i] + U.H[2][i] + U.H[3][i];
    U.H[0][i] = v;
  }
  __syncthreads();
  // phase 2: single-wave two-level cumsum -> first bin where cum >= 512
  if (wid == 0) {
    u32 ssum = 0;
    #pragma unroll 8
    for (int i = 0; i < 64; ++i) {
      int ii = (i + lane) & 63;
      ssum += U.H[0][(lane << 6) + ii];
    }
    u32 inc = ssum;
    for (int o = 1; o < 64; o <<= 1) { u32 v = __shfl_up(inc, o); if (lane >= o) inc += v; }
    u64 ball = __ballot(inc >= 512u);
    if (!ball) {
      if (lane == 0) sBoundary = ((u64)INVALID_HI << 15);   // all valid keys
    } else {
      int Wq = __ffsll(ball) - 1;
      u32 cumBefore = __shfl(inc - ssum, Wq);
      u32 v2 = U.H[0][(Wq << 6) + lane];
      u32 inc2 = v2;
      for (int o = 1; o < 64; o <<= 1) { u32 x = __shfl_up(inc2, o); if (lane >= o) inc2 += x; }
      u64 ball2 = __ballot(cumBefore + inc2 >= 512u);
      int l2 = __ffsll(ball2) - 1;
      if (lane == 0) {
        int d = (Wq << 6) + l2;
        sBoundary = (48ull << 41) | ((u64)d << 29);
      }
    }
  }
  __syncthreads();
  u64 Boundary = sBoundary;
  if (qi == 0 && tid == 0) ((u64*)(ws + T512_OFF))[b] = Boundary - 1;

  // phase 3 pass A: per-wave keep5 counts (deterministic across blocks)
  for (int it = 0; it < 17; ++it) {
    int u = it * 1024 + tid;
    bool keep5 = false;
    if (u < TOTAL_G) {
      u64 k = loadkey(P, b, u);
      keep5 = ((u32)(k >> 15) < INVALID_HI) && (k < Boundary);
    }
    u64 bal = __ballot(keep5);
    if (lane == 0) wbase[it * 16 + wid] = __popcll(bal);
  }
  __syncthreads();
  if (wid == 0) {
    int carry = 0;
    for (int base = 0; base < 272; base += 64) {
      int idx = base + lane;
      int v = (idx < 272) ? wbase[idx] : 0;
      int inc = v;
      for (int o = 1; o < 64; o <<= 1) { int x = __shfl_up(inc, o); if (lane >= o) inc += x; }
      if (idx < 272) wbase[idx] = inc - v + carry;
      carry += __shfl(inc, 63);
    }
    if (lane == 0) sN5 = carry;
  }
  __syncthreads();
  int n512 = sN5;                       // < 512 by construction
  if (qi == 0 && tid == 0) ((int*)(ws + NC_OFF))[16 + b] = n512;

  // phase 3 pass B: ordered scatter into LDS
  for (int it = 0; it < 17; ++it) {
    int u = it * 1024 + tid;
    bool keep5 = false; u64 k = 0;
    if (u < TOTAL_G) {
      k = loadkey(P, b, u);
      keep5 = ((u32)(k >> 15) < INVALID_HI) && (k < Boundary);
    }
    u64 bal = __ballot(keep5);
    int pos = wbase[it * 16 + wid] + __popcll(bal & ((1ull << lane) - 1ull));
    if (keep5) skey[pos] = k;
  }
  __syncthreads();

  // phase 4: decode + pad (first union-M writes — histogram dead for several barriers)
  if (tid < 512) {
    if (tid < n512) {
      U.M.sbox[tid] = decode_box(P, b, (int)(skey[tid] & 0x7FFF));
    } else {
      skey[tid] = (ALLF - 511) + (u64)tid;   // distinct, > any real key
      U.M.sbox[tid] = make_float4(-1e30f, -1e30f, -1e30f, -1e30f);
    }
  }
  for (int i = tid; i < 512 * 8; i += 1024) U.M.smaskR[i] = 0ull;
  __syncthreads();

  // phase 5: rank all 512 by key
  {
    int t2 = tid & 511, half = tid >> 9;
    u64 mykey = skey[t2];
    int jb = half << 8, cnt = 0;
    #pragma unroll 4
    for (int j = jb; j < jb + 256; ++j) cnt += (skey[j] < mykey) ? 1 : 0;
    U.M.parts[tid] = (u16)cnt;
  }
  __syncthreads();
  if (tid < 512) srank[tid] = (u16)(U.M.parts[tid] + U.M.parts[tid + 512]);
  __syncthreads();

  // phase 6: suppression bits in rank space (rotated j-scan, conflict-free)
  int i = qi * 128 + (tid >> 3);
  int w = tid & 7;
  float4 bi = U.M.sbox[i];
  u64 ki = skey[i];
  int ri = srank[i];
  float ia = (bi.z - bi.x) * (bi.w - bi.y);
  #pragma unroll 8
  for (int bj = 0; bj < 64; ++bj) {
    int jj = (bj + w) & 63;
    int j = (w << 6) | jj;
    u64 kj = skey[j];
    if (ki < kj) {
      float4 bj4 = U.M.sbox[j];
      float ja  = (bj4.z - bj4.x) * (bj4.w - bj4.y);
      float ltx = fmaxf(bi.x, bj4.x), lty = fmaxf(bi.y, bj4.y);
      float rbx = fminf(bi.z, bj4.z), rby = fminf(bi.w, bj4.w);
      float wv = fmaxf(rbx - ltx, 0.0f), hv = fmaxf(rby - lty, 0.0f);
      float inter = wv * hv;
      float iou = inter / (ia + ja - inter);   // exact: integer-valued fp32
      if (iou > 0.6f) {
        int rj = srank[j];
        atomicOr(&U.M.smaskR[ri * 8 + (rj >> 6)], 1ull << (rj & 63));
      }
    }
  }
  __syncthreads();

  {
    int il = tid >> 3, ww = tid & 7;
    int ig = qi * 128 + il;
    if (ig < n512) {
      int r = srank[ig];
      msk_of(ws, b)[r * 8 + ww] = U.M.smaskR[r * 8 + ww];
      if (ww == 0) krank_of(ws, b)[r] = skey[ig];
    }
  }
}

// ---------------- 256-thread exact radix select (fallback only; no early exits) ----------------
__device__ u64 select256(const u64* keys, int n, int t0, u32* hist, u64* shP, int* shT) {
  u64 Pfx = 3; int t = t0;
  const int SS[4] = {33, 21, 9, 0};
  const int WW[4] = {12, 12, 12, 9};
  for (int p = 0; p < 4; ++p) {
    int s = SS[p], wb = WW[p];
    u32 dmask = (1u << wb) - 1u;
    for (int i = threadIdx.x; i < 4096; i += 256) hist[i] = 0;
    __syncthreads();
    for (int i = threadIdx.x; i < n; i += 256) {
      u64 k = keys[i];
      if ((k >> (s + wb)) == Pfx) atomicAdd(&hist[(u32)(k >> s) & dmask], 1u);
    }
    __syncthreads();
    if (threadIdx.x < 64) {
      int lane = threadIdx.x;
      u32 ssum = 0;
      for (int i = 0; i < 64; ++i) ssum += hist[(lane << 6) + ((i + lane) & 63)];
      u32 inc = ssum;
      for (int o = 1; o < 64; o <<= 1) { u32 v = __shfl_up(inc, o); if (lane >= o) inc += v; }
      u64 ball = __ballot(inc >= (u32)t);
      int Wq = __ffsll(ball) - 1;
      u32 cumBefore = __shfl(inc - ssum, Wq);
      u32 v2 = hist[(Wq << 6) + lane];
      u32 inc2 = v2;
      for (int o = 1; o < 64; o <<= 1) { u32 x = __shfl_up(inc2, o); if (lane >= o) inc2 += x; }
      u64 ball2 = __ballot(cumBefore + inc2 >= (u32)t);
      int l2 = __ffsll(ball2) - 1;
      u32 cumB2 = __shfl(cumBefore + inc2 - v2, l2);
      if (lane == 0) { *shP = (Pfx << wb) | (u32)((Wq << 6) + l2); *shT = t - (int)cumB2; }
    }
    __syncthreads();
    Pfx = *shP; t = *shT;
    __syncthreads();
  }
  return Pfx;   // final pass (s=0) yields the full 47-bit key
}

// ---------------- K3: greedy ffs walk + fallback + slotkey (grid 16, 256 thr) ----------------
__global__ __launch_bounds__(256) void k_reduce(Ptrs P) {
  __shared__ u64 smask[4096];       // 32 KB
  __shared__ u32 keeplist[100];     // ranks (walk phase only)
  __shared__ int keptS;
  __shared__ u64 liveC[267];        // fallback: live bits over gid space
  __shared__ union UF {
    u32 hist[4096];                 // 16 KB (fallback selects)
    struct { u64 pk[256]; int pc[256]; float4 fkb[100]; } F;
  } UF_;
  __shared__ u64 shP; __shared__ int shT;
  __shared__ u64 bk; __shared__ int bc2;

  int b = blockIdx.x;
  int tid = threadIdx.x;
  char* ws = P.ws;
  int n512 = ((int*)(ws + NC_OFF))[16 + b];
  const u64* kr = krank_of(ws, b);

  const u64* gmask = msk_of(ws, b);
  for (int t = tid; t < 4096; t += 256) smask[t] = gmask[t];
  __syncthreads();

  // single-wave barrier-free greedy walk over ranks [0, n512)
  if (tid < 64) {
    int lane = tid;
    u64 lw = 0;
    if (lane < 8) {
      int lo = lane << 6;
      int c = n512 - lo; if (c < 0) c = 0; if (c > 64) c = 64;
      lw = (c >= 64) ? ALLF : ((c > 0) ? ((1ull << c) - 1ull) : 0ull);
    }
    int kept = 0;
    while (kept < 100) {
      bool nz = (lane < 8) && (lw != 0ull);
      u64 bal = __ballot(nz);
      if (!bal) break;
      int W = __ffsll(bal) - 1;
      u64 wv = __shfl(lw, W);
      int bit = __ffsll(wv) - 1;
      int i = (W << 6) + bit;
      if (lane == 0) keeplist[kept] = (u32)i;
      kept++;
      if (lane == W) lw &= ~(1ull << bit);
      if (kept == 100) break;
      if (lane < 8) lw &= ~smask[i * 8 + lane];
    }
    if (lane == 0) keptS = kept;
  }
  __syncthreads();
  int kept = keptS;
  int keptW = kept;

  // fallback: keeps beyond the prefix (rare; exact). liveC ends empty when the
  // prefix really contained everything, so cost is bounded by the select256s.
  if (kept < 100) {
    // lazily compute exact per-level top-1000 thresholds (never-taken path)
    u64 T0 = select256((const u64*)(ws + KEYS0_OFF) + (size_t)b * 12800, 12800, 1000,
                       UF_.hist, &shP, &shT);
    u64 T1 = select256((const u64*)(ws + KEYS1_OFF) + (size_t)b * 3200, 3200, 1000,
                       UF_.hist, &shP, &shT);
    u64 T512 = ((u64*)(ws + T512_OFF))[b];
    for (int w = tid; w < 267; w += 256) {
      int lo = w << 6;
      u64 m = 0;
      for (int e = 0; e < 64; ++e) {
        int u = lo + e;
        if (u < TOTAL_G) {
          u64 k = loadkey(P, b, u);
          if (keep_pred(k, u, T0, T1) && k > T512) m |= (1ull << e);
        }
      }
      liveC[w] = m;
    }
    if (tid < kept) UF_.F.fkb[tid] = decode_box(P, b, (int)(kr[keeplist[tid]] & 0x7FFF));
    __syncthreads();

    // seed suppression from already-kept items
    for (int k2 = 0; k2 < kept; ++k2) {
      float4 bi = UF_.F.fkb[k2];
      float ia = (bi.z - bi.x) * (bi.w - bi.y);
      for (int u = tid; u < TOTAL_G; u += 256) {
        if (!((liveC[u >> 6] >> (u & 63)) & 1ull)) continue;
        float4 bj4 = decode_box(P, b, u);
        float ja  = (bj4.z - bj4.x) * (bj4.w - bj4.y);
        float ltx = fmaxf(bi.x, bj4.x), lty = fmaxf(bi.y, bj4.y);
        float rbx = fminf(bi.z, bj4.z), rby = fminf(bi.w, bj4.w);
        float wv = fmaxf(rbx - ltx, 0.0f), hv = fmaxf(rby - lty, 0.0f);
        float inter = wv * hv;
        float iou = inter / (ia + ja - inter);
        if (iou > 0.6f) atomicAnd(&liveC[u >> 6], ~(1ull << (u & 63)));
      }
    }
    __syncthreads();

    // selection-by-min-key loop
    while (kept < 100) {
      u64 mymin = ALLF; int myc = -1;
      for (int u = tid; u < TOTAL_G; u += 256) {
        if (!((liveC[u >> 6] >> (u & 63)) & 1ull)) continue;
        u64 k = loadkey(P, b, u);
        if (k < mymin) { mymin = k; myc = u; }
      }
      UF_.F.pk[tid] = mymin; UF_.F.pc[tid] = myc;
      __syncthreads();
      if (tid < 64) {
        u64 m = UF_.F.pk[tid]; int c0 = UF_.F.pc[tid];
        #pragma unroll
        for (int o = 64; o < 256; o += 64)
          if (UF_.F.pk[tid + o] < m) { m = UF_.F.pk[tid + o]; c0 = UF_.F.pc[tid + o]; }
        for (int o = 32; o > 0; o >>= 1) {
          u64 om = __shfl_down(m, o); int oc = __shfl_down(c0, o);
          if (om < m) { m = om; c0 = oc; }
        }
        if (tid == 0) { bk = m; bc2 = c0; }
      }
      __syncthreads();
      if (bk == ALLF) break;
      int cs = bc2;
      if (tid == 0) {
        slotkey_of(ws, b)[kept] = bk;     // fallback keeps write slotkey directly
        atomicAnd(&liveC[cs >> 6], ~(1ull << (cs & 63)));
      }
      __syncthreads();
      kept++;
      if (kept == 100) break;
      float4 bi = decode_box(P, b, cs);
      float ia = (bi.z - bi.x) * (bi.w - bi.y);
      for (int u = tid; u < TOTAL_G; u += 256) {
        if (!((liveC[u >> 6] >> (u & 63)) & 1ull)) continue;
        float4 bj4 = decode_box(P, b, u);
        float ja  = (bj4.z - bj4.x) * (bj4.w - bj4.y);
        float ltx = fmaxf(bi.x, bj4.x), lty = fmaxf(bi.y, bj4.y);
        float rbx = fminf(bi.z, bj4.z), rby = fminf(bi.w, bj4.w);
        float wv = fmaxf(rbx - ltx, 0.0f), hv = fmaxf(rby - lty, 0.0f);
        float inter = wv * hv;
        float iou = inter / (ia + ja - inter);
        if (iou > 0.6f) atomicAnd(&liveC[u >> 6], ~(1ull << (u & 63)));
      }
      __syncthreads();
    }
  }

  // resolve slot keys: walk entries via kr; fallback entries already written; rest = ALLF
  if (tid < 100) {
    if (tid < keptW)      slotkey_of(ws, b)[tid] = kr[keeplist[tid]];
    else if (tid >= kept) slotkey_of(ws, b)[tid] = ALLF;
  }
}

// ---------------- K4: parallel outputs (grid 16 x 10, 256 thr) ----------------
__global__ __launch_bounds__(256) void k_out(Ptrs P, float* out) {
  int b = blockIdx.x, part = blockIdx.y;   // 10 slots per block
  int s0 = part * 10;
  int tid = threadIdx.x;
  const u64* skl = slotkey_of(P.ws, b);

  if (tid < 10) {
    int s = s0 + tid;
    u64 key = skl[s];
    float os = -1.0f, oc = -1.0f;
    float4 bx = make_float4(-1.0f, -1.0f, -1.0f, -1.0f);
    if (key != ALLF) {
      int gid = (int)(key & 0x7FFF);
      os = __uint_as_float(~(u32)(key >> 15));
      oc = (float)((u16*)(P.ws + CLSI_OFF))[(size_t)b * TOTAL_G + gid];
      bx = decode_box(P, b, gid);
    }
    out[b * 100 + s] = os;
    out[1600 + b * 100 + s] = oc;
    *(float4*)(out + 3200 + (size_t)(b * 100 + s) * 4) = bx;
  }

  for (int t = tid; t < 800; t += 256) {
    int sl = t / 80, k = t - sl * 80;
    int s = s0 + sl;
    u64 key = skl[s];
    float val = -1.0f;
    if (key != ALLF) {
      int gid = (int)(key & 0x7FFF);
      int lev, idx, nl; levinfo(gid, lev, idx, nl);
      const float* cp;
      if      (lev == 0) cp = P.cls0;
      else if (lev == 1) cp = P.cls1;
      else if (lev == 2) cp = P.cls2;
      else if (lev == 3) cp = P.cls3;
      else               cp = P.cls4;
      val = sigd(cp[(size_t)(b * nl + idx) * 80 + k]);
    }
    out[9600 + (size_t)(b * 100 + s) * 80 + k] = val;
  }
}

extern "C" void kernel_launch(void* const* d_in, const int* in_sizes, int n_in,
                              void* d_out, int out_size, void* d_ws, size_t ws_size,
                              hipStream_t stream) {
  (void)in_sizes; (void)n_in; (void)out_size; (void)ws_size;
  Ptrs P;
  P.cls0 = (const float*)d_in[0];  P.reg0 = (const float*)d_in[1];
  P.ctr0 = (const float*)d_in[2];  P.pos0 = (const float*)d_in[3];
  P.cls1 = (const float*)d_in[4];  P.reg1 = (const float*)d_in[5];
  P.ctr1 = (const float*)d_in[6];  P.pos1 = (const float*)d_in[7];
  P.cls2 = (const float*)d_in[8];  P.reg2 = (const float*)d_in[9];
  P.ctr2 = (const float*)d_in[10]; P.pos2 = (const float*)d_in[11];
  P.cls3 = (const float*)d_in[12]; P.reg3 = (const float*)d_in[13];
  P.ctr3 = (const float*)d_in[14]; P.pos3 = (const float*)d_in[15];
  P.cls4 = (const float*)d_in[16]; P.reg4 = (const float*)d_in[17];
  P.ctr4 = (const float*)d_in[18]; P.pos4 = (const float*)d_in[19];
  P.ws = (char*)d_ws;

  k_score<<<dim3(267, 16), 256, 0, stream>>>(P);
  k_mask<<<dim3(4, 16), 1024, 0, stream>>>(P);
  k_reduce<<<16, 256, 0, stream>>>(P);
  k_out<<<dim3(16, 10), 256, 0, stream>>>(P, (float*)d_out);
}